// Round 5
// baseline (517.615 us; speedup 1.0000x reference)
//
#include <hip/hip_runtime.h>
#include <hip/hip_bf16.h>
#include <math.h>

#define NEG_SLOPE 0.2f

typedef __attribute__((ext_vector_type(8))) __bf16 bf16x8;
typedef __attribute__((ext_vector_type(4))) float f32x4;

// ---------------- helpers ----------------
__device__ inline float lrelu(float v) { return v > 0.f ? v : NEG_SLOPE * v; }

__device__ inline unsigned short f2bf(float f) {
    __hip_bfloat16 h = __float2bfloat16(f);
    return *reinterpret_cast<unsigned short*>(&h);
}
__device__ inline float bf_lo(unsigned u) { return __uint_as_float(u << 16); }
__device__ inline float bf_hi(unsigned u) { return __uint_as_float(u & 0xffff0000u); }

template <int H>
__device__ inline float sel_h(const float* a, int h) {
    if (H == 1) return a[0];
    return (h & 2) ? ((h & 1) ? a[3] : a[2]) : ((h & 1) ? a[1] : a[0]);
}

// ---------------- CSR build ----------------
__global__ void count_deg_kernel(const int* __restrict__ ei, int E, int N,
                                 int* __restrict__ deg) {
    int e = blockIdx.x * blockDim.x + threadIdx.x;
    if (e >= E + N) return;
    int dst = (e < E) ? ei[E + e] : (e - E);
    atomicAdd(&deg[dst], 1);
}

__global__ void scan_kernel(const int* __restrict__ deg, int* __restrict__ off, int N) {
    __shared__ int sums[1024];
    int tid = threadIdx.x;
    int chunk = (N + 1023) / 1024;
    int start = tid * chunk;
    int end = start + chunk; if (end > N) end = N;
    int s = 0;
    for (int i = start; i < end && i < N; i++) s += deg[i];
    sums[tid] = s;
    __syncthreads();
    for (int d = 1; d < 1024; d <<= 1) {
        int v = 0;
        if (tid >= d) v = sums[tid - d];
        __syncthreads();
        if (tid >= d) sums[tid] += v;
        __syncthreads();
    }
    int prefix = (tid == 0) ? 0 : sums[tid - 1];
    int run = prefix;
    for (int i = start; i < end && i < N; i++) { off[i] = run; run += deg[i]; }
    if (tid == 1023) off[N] = sums[1023];
}

__global__ void scatter_kernel(const int* __restrict__ ei, int E, int N,
                               const int* __restrict__ off, int* __restrict__ cursor,
                               int* __restrict__ csr_src) {
    int e = blockIdx.x * blockDim.x + threadIdx.x;
    if (e >= E + N) return;
    int src, dst;
    if (e < E) { src = ei[e]; dst = ei[E + e]; }
    else       { src = dst = e - E; }
    int pos = off[dst] + atomicAdd(&cursor[dst], 1);
    csr_src[pos] = src;
}

// ---------------- fp32 -> bf16 cast (vectorized), n % 4 == 0 ----------------
__global__ void cast_bf16_kernel(const float* __restrict__ in, unsigned short* __restrict__ out,
                                 size_t n4) {
    size_t i = (size_t)blockIdx.x * blockDim.x + threadIdx.x;
    if (i >= n4) return;
    float4 v = reinterpret_cast<const float4*>(in)[i];
    ushort4 o;
    o.x = f2bf(v.x); o.y = f2bf(v.y); o.z = f2bf(v.z); o.w = f2bf(v.w);
    reinterpret_cast<ushort4*>(out)[i] = o;
}

// ---------------- transpose-cast: out[n*K + k] = bf16(in[k*N + n]) ----------------
__global__ void transpose_cast_kernel(const float* __restrict__ in, unsigned short* __restrict__ out,
                                      int K, int N) {
    int idx = blockIdx.x * blockDim.x + threadIdx.x;
    if (idx >= K * N) return;
    int n = idx / K, k = idx % K;
    out[(size_t)n * K + k] = f2bf(in[(size_t)k * N + n]);
}

// ---------------- bf16 MFMA GEMM + fused attention-logit epilogue ----------------
// C[M,N] = A[M,K] @ Bt[N,K]^T (bf16 out). Col-tile (128) == one head slice:
// epilogue also computes alS/alD contributions via 16-lane reduce + atomicAdd.
// alS/alD must be pre-zeroed.
template <int HEADS>
__global__ __launch_bounds__(256) void gemm_bf16_alpha(const unsigned short* __restrict__ A,
                                                       const unsigned short* __restrict__ Bt,
                                                       unsigned short* __restrict__ C,
                                                       int M, int N, int K,
                                                       const float* __restrict__ a_src,
                                                       const float* __restrict__ a_dst,
                                                       float* __restrict__ alS,
                                                       float* __restrict__ alD) {
    __shared__ unsigned short Asl[128 * 32];
    __shared__ unsigned short Bsl[128 * 32];
    const int tid  = threadIdx.x;
    const int lane = tid & 63;
    const int wave = tid >> 6;
    const int rowBase = blockIdx.y * 128;
    const int colBase = blockIdx.x * 128;
    const int wm = (wave & 1) * 64;
    const int wn = (wave >> 1) * 64;
    const int q   = lane >> 4;
    const int l16 = lane & 15;

    f32x4 acc[4][4] = {};

    for (int k0 = 0; k0 < K; k0 += 32) {
#pragma unroll
        for (int it = 0; it < 2; it++) {
            int s = it * 256 + tid;
            int r = s >> 2;
            int c = (s & 3) * 8;
            int ga = rowBase + r; if (ga >= M) ga = M - 1;
            const unsigned short* gpa = A + (size_t)ga * K + k0 + c;
            __builtin_amdgcn_global_load_lds(
                (const __attribute__((address_space(1))) void*)gpa,
                (__attribute__((address_space(3))) void*)&Asl[(size_t)(it * 256 + wave * 64) * 8],
                16, 0, 0);
            const unsigned short* gpb = Bt + (size_t)(colBase + r) * K + k0 + c;
            __builtin_amdgcn_global_load_lds(
                (const __attribute__((address_space(1))) void*)gpb,
                (__attribute__((address_space(3))) void*)&Bsl[(size_t)(it * 256 + wave * 64) * 8],
                16, 0, 0);
        }
        __syncthreads();

        bf16x8 af[4], bfv[4];
#pragma unroll
        for (int mi = 0; mi < 4; mi++)
            af[mi] = *reinterpret_cast<const bf16x8*>(&Asl[(wm + mi * 16 + l16) * 32 + q * 8]);
#pragma unroll
        for (int ni = 0; ni < 4; ni++)
            bfv[ni] = *reinterpret_cast<const bf16x8*>(&Bsl[(wn + ni * 16 + l16) * 32 + q * 8]);
#pragma unroll
        for (int mi = 0; mi < 4; mi++)
#pragma unroll
            for (int ni = 0; ni < 4; ni++)
                acc[mi][ni] = __builtin_amdgcn_mfma_f32_16x16x32_bf16(af[mi], bfv[ni], acc[mi][ni], 0, 0, 0);
        __syncthreads();
    }

    const int hIdx = colBase >> 7;           // C==128 per head
    const float* asl = a_src + hIdx * 128;
    const float* adl = a_dst + hIdx * 128;
    float acoef[4], dcoef[4];
#pragma unroll
    for (int ni = 0; ni < 4; ni++) {
        int cl = wn + ni * 16 + l16;
        acoef[ni] = asl[cl];
        dcoef[ni] = adl[cl];
    }

#pragma unroll
    for (int mi = 0; mi < 4; mi++) {
#pragma unroll
        for (int r = 0; r < 4; r++) {
            int grow = rowBase + wm + mi * 16 + q * 4 + r;
            bool ok = grow < M;
            float vs = 0.f, vd = 0.f;
#pragma unroll
            for (int ni = 0; ni < 4; ni++) {
                float hv = acc[mi][ni][r];
                vs += hv * acoef[ni];
                vd += hv * dcoef[ni];
                if (ok) {
                    int gcol = colBase + wn + ni * 16 + l16;
                    C[(size_t)grow * N + gcol] = f2bf(hv);
                }
            }
#pragma unroll
            for (int d = 1; d < 16; d <<= 1) {
                vs += __shfl_xor(vs, d);
                vd += __shfl_xor(vd, d);
            }
            if (ok && l16 == 0) {
                atomicAdd(&alS[(size_t)grow * HEADS + hIdx], vs);
                atomicAdd(&alD[(size_t)grow * HEADS + hIdx], vd);
            }
        }
    }
}

// ---------------- fused segment softmax + aggregate (+optional head), wave/node -------
// MODE 0: out = bf16, relu.  MODE 1 (H==1): fuse risk head, out = float per node.
template <int H, int C, int MODE>
__global__ __launch_bounds__(256) void gat_aggregate(const unsigned short* __restrict__ hb,
                                                     const float* __restrict__ alS,
                                                     const float* __restrict__ alD,
                                                     const int* __restrict__ off,
                                                     const int* __restrict__ csr_src,
                                                     const float* __restrict__ bias,
                                                     void* __restrict__ outbuf,
                                                     const float* __restrict__ Ws1,
                                                     const float* __restrict__ bs1,
                                                     const float* __restrict__ Ws2,
                                                     const float* __restrict__ bs2,
                                                     int N) {
    constexpr int HC = H * C;
    constexpr int PER = HC / 64;
    int n = (blockIdx.x * blockDim.x + threadIdx.x) >> 6;
    int lane = threadIdx.x & 63;
    if (n >= N) return;
    int beg = off[n], end = off[n + 1];

    float ad[H];
#pragma unroll
    for (int h = 0; h < H; h++) ad[h] = alD[n * H + h];

    const int myh = (lane * PER) / C;
    const unsigned short* hbl = hb + (size_t)lane * PER;

    float m[H], den[H], acc[PER];
#pragma unroll
    for (int h = 0; h < H; h++) { m[h] = -1e30f; den[h] = 0.f; }
#pragma unroll
    for (int j = 0; j < PER; j++) acc[j] = 0.f;

    for (int base = beg; base < end; base += 64) {
        int cnt = end - base; if (cnt > 64) cnt = 64;
        bool act = lane < cnt;
        int s_l = csr_src[act ? (base + lane) : base];

        // per-lane logit for its edge
        float v[H];
        if (H == 4) {
            float4 a4 = *reinterpret_cast<const float4*>(&alS[s_l * 4]);
            v[0] = a4.x + ad[0]; v[1] = a4.y + ad[1];
            v[2] = a4.z + ad[2]; v[3] = a4.w + ad[3];
        } else {
            v[0] = alS[s_l] + ad[0];
        }
#pragma unroll
        for (int h = 0; h < H; h++) v[h] = act ? lrelu(v[h]) : -1e30f;

        // chunk max + chunk denom
        float mc[H], pl[H], dc[H];
#pragma unroll
        for (int h = 0; h < H; h++) {
            mc[h] = v[h];
#pragma unroll
            for (int d = 1; d < 64; d <<= 1) mc[h] = fmaxf(mc[h], __shfl_xor(mc[h], d));
            pl[h] = __expf(v[h] - mc[h]);           // inactive lanes -> 0
            dc[h] = pl[h];
#pragma unroll
            for (int d = 1; d < 64; d <<= 1) dc[h] += __shfl_xor(dc[h], d);
        }
        // merge into running (m, den); rescale acc
        float soA[H], wl[H];
#pragma unroll
        for (int h = 0; h < H; h++) {
            float nm = fmaxf(m[h], mc[h]);
            float so = __expf(m[h] - nm);
            float sc = __expf(mc[h] - nm);
            den[h] = den[h] * so + dc[h] * sc;
            m[h] = nm;
            soA[h] = so;
            wl[h] = pl[h] * sc;      // this lane's edge weight (unnormalized, vs new m)
        }
        float sAcc = sel_h<H>(soA, myh);
#pragma unroll
        for (int j = 0; j < PER; j++) acc[j] *= sAcc;

        // weighted accumulate: G=4 ping-pong pipelined gathers
        if (PER == 8) {
            uint4 rb[2][4]; float wb[2][4];
            auto FETCH = [&](int i0, int b) {
#pragma unroll
                for (int u = 0; u < 4; u++) {
                    int j = i0 + u;
                    if (j < cnt) {
                        int s = __shfl(s_l, j);
                        float w0 = __shfl(wl[0], j), w1 = __shfl(wl[1], j),
                              w2 = __shfl(wl[2], j), w3 = __shfl(wl[3], j);
                        float t[4] = {w0, w1, w2, w3};
                        wb[b][u] = sel_h<H>(t, myh);
                        rb[b][u] = *reinterpret_cast<const uint4*>(hbl + (size_t)s * HC);
                    }
                }
            };
            FETCH(0, 0);
            int cur = 0;
            for (int i = 0; i < cnt; i += 4) {
                if (i + 4 < cnt) FETCH(i + 4, cur ^ 1);
#pragma unroll
                for (int u = 0; u < 4; u++) {
                    if (i + u < cnt) {
                        uint4 rc = rb[cur][u]; float w = wb[cur][u];
                        acc[0] += bf_lo(rc.x) * w; acc[1] += bf_hi(rc.x) * w;
                        acc[2] += bf_lo(rc.y) * w; acc[3] += bf_hi(rc.y) * w;
                        acc[4] += bf_lo(rc.z) * w; acc[5] += bf_hi(rc.z) * w;
                        acc[6] += bf_lo(rc.w) * w; acc[7] += bf_hi(rc.w) * w;
                    }
                }
                cur ^= 1;
            }
        } else {
            unsigned rb[2][4]; float wb[2][4];
            auto FETCH = [&](int i0, int b) {
#pragma unroll
                for (int u = 0; u < 4; u++) {
                    int j = i0 + u;
                    if (j < cnt) {
                        int s = __shfl(s_l, j);
                        wb[b][u] = __shfl(wl[0], j);
                        rb[b][u] = *reinterpret_cast<const unsigned*>(hbl + (size_t)s * HC);
                    }
                }
            };
            FETCH(0, 0);
            int cur = 0;
            for (int i = 0; i < cnt; i += 4) {
                if (i + 4 < cnt) FETCH(i + 4, cur ^ 1);
#pragma unroll
                for (int u = 0; u < 4; u++) {
                    if (i + u < cnt) {
                        unsigned rc = rb[cur][u]; float w = wb[cur][u];
                        acc[0] += bf_lo(rc) * w; acc[1] += bf_hi(rc) * w;
                    }
                }
                cur ^= 1;
            }
        }
    }

    float invd = 1.f / sel_h<H>(den, myh);

    if (MODE == 0) {
#pragma unroll
        for (int j = 0; j < PER; j++) {
            int c = lane * PER + j;
            float val = fmaxf(acc[j] * invd + bias[c], 0.f);
            ((unsigned short*)outbuf)[(size_t)n * HC + c] = f2bf(val);
        }
    } else {
        // H==1, PER==2: channels (2*lane, 2*lane+1) -> fused risk head
        float h0 = acc[0] * invd + bias[2 * lane];
        float h1 = acc[1] * invd + bias[2 * lane + 1];
        float s = 0.f;
#pragma unroll
        for (int k = 0; k < 64; k++) {
            float a = __shfl(h0, k);
            float b = __shfl(h1, k);
            s += a * Ws1[(2 * k) * 64 + lane];
            s += b * Ws1[(2 * k + 1) * 64 + lane];
        }
        s = fmaxf(s + bs1[lane], 0.f);
        float z = s * Ws2[lane];
#pragma unroll
        for (int d = 1; d < 64; d <<= 1) z += __shfl_xor(z, d);
        if (lane == 0) ((float*)outbuf)[n] = 1.f / (1.f + __expf(-(z + bs2[0])));
    }
}

// ---------------- launch ----------------
extern "C" void kernel_launch(void* const* d_in, const int* in_sizes, int n_in,
                              void* d_out, int out_size, void* d_ws, size_t ws_size,
                              hipStream_t stream) {
    const float* x   = (const float*)d_in[0];
    const int*   ei  = (const int*)d_in[1];
    const float* W1  = (const float*)d_in[2];
    const float* as1 = (const float*)d_in[3];
    const float* ad1 = (const float*)d_in[4];
    const float* b1  = (const float*)d_in[5];
    const float* W2  = (const float*)d_in[6];
    const float* as2 = (const float*)d_in[7];
    const float* ad2 = (const float*)d_in[8];
    const float* b2  = (const float*)d_in[9];
    const float* W3  = (const float*)d_in[10];
    const float* as3 = (const float*)d_in[11];
    const float* ad3 = (const float*)d_in[12];
    const float* b3  = (const float*)d_in[13];
    const float* Ws1 = (const float*)d_in[14];
    const float* bs1 = (const float*)d_in[15];
    const float* Ws2 = (const float*)d_in[16];
    const float* bs2 = (const float*)d_in[17];

    const int N = out_size;            // 20000
    const int E = in_sizes[1] / 2;     // 160000
    const int D = in_sizes[0] / N;     // 768
    const int HC = 512, H = 4, C = 128;
    const int Etot = E + N;

    char* p = (char*)d_ws;
    auto alloc = [&](size_t bytes) -> void* {
        void* q = (void*)p;
        p += (bytes + 255) & ~(size_t)255;
        return q;
    };
    // --- zeroed region (deg, cursor, alS/alD x3) ---
    char*  zbeg   = p;
    int*   deg    = (int*)alloc((size_t)N * 4);
    int*   cursor = (int*)alloc((size_t)N * 4);
    float* alS1   = (float*)alloc((size_t)N * H * 4);
    float* alD1   = (float*)alloc((size_t)N * H * 4);
    float* alS2   = (float*)alloc((size_t)N * H * 4);
    float* alD2   = (float*)alloc((size_t)N * H * 4);
    float* alS3   = (float*)alloc((size_t)N * 4);
    float* alD3   = (float*)alloc((size_t)N * 4);
    char*  zend   = p;
    // --- rest ---
    int*   off    = (int*)alloc((size_t)(N + 1) * 4);
    int*   csr    = (int*)alloc((size_t)Etot * 4);
    unsigned short* hbuf = (unsigned short*)alloc((size_t)N * HC * 2);
    unsigned short* xbf  = (unsigned short*)alloc((size_t)N * D * 2);
    unsigned short* obf  = (unsigned short*)alloc((size_t)N * HC * 2);
    unsigned short* W1t  = (unsigned short*)alloc((size_t)D * HC * 2);
    unsigned short* W2t  = (unsigned short*)alloc((size_t)HC * HC * 2);
    unsigned short* W3t  = (unsigned short*)alloc((size_t)HC * C * 2);

    hipMemsetAsync(zbeg, 0, (size_t)(zend - zbeg), stream);

    const int tb = 256;
    count_deg_kernel<<<(Etot + tb - 1) / tb, tb, 0, stream>>>(ei, E, N, deg);
    scan_kernel<<<1, 1024, 0, stream>>>(deg, off, N);
    scatter_kernel<<<(Etot + tb - 1) / tb, tb, 0, stream>>>(ei, E, N, off, cursor, csr);

    {
        size_t n4 = (size_t)N * D / 4;
        cast_bf16_kernel<<<(int)((n4 + 255) / 256), 256, 0, stream>>>(x, xbf, n4);
        transpose_cast_kernel<<<(D * HC + 255) / 256, 256, 0, stream>>>(W1, W1t, D, HC);
        transpose_cast_kernel<<<(HC * HC + 255) / 256, 256, 0, stream>>>(W2, W2t, HC, HC);
        transpose_cast_kernel<<<(HC * C + 255) / 256, 256, 0, stream>>>(W3, W3t, HC, C);
    }

    int node_blocks = (N + 3) / 4;     // one wave per node
    int rowTiles = (N + 127) / 128;

    // ---- layer 1 ----
    gemm_bf16_alpha<4><<<dim3(HC / 128, rowTiles), 256, 0, stream>>>(
        xbf, W1t, hbuf, N, HC, D, as1, ad1, alS1, alD1);
    gat_aggregate<4, 128, 0><<<node_blocks, 256, 0, stream>>>(
        hbuf, alS1, alD1, off, csr, b1, obf, nullptr, nullptr, nullptr, nullptr, N);

    // ---- layer 2 ----
    gemm_bf16_alpha<4><<<dim3(HC / 128, rowTiles), 256, 0, stream>>>(
        obf, W2t, hbuf, N, HC, HC, as2, ad2, alS2, alD2);
    gat_aggregate<4, 128, 0><<<node_blocks, 256, 0, stream>>>(
        hbuf, alS2, alD2, off, csr, b2, obf, nullptr, nullptr, nullptr, nullptr, N);

    // ---- layer 3 (H=1) + fused head ----
    gemm_bf16_alpha<1><<<dim3(C / 128, rowTiles), 256, 0, stream>>>(
        obf, W3t, hbuf, N, C, HC, as3, ad3, alS3, alD3);
    gat_aggregate<1, 128, 1><<<node_blocks, 256, 0, stream>>>(
        hbuf, alS3, alD3, off, csr, b3, (float*)d_out, Ws1, bs1, Ws2, bs2, N);
}

// Round 6
// 452.890 us; speedup vs baseline: 1.1429x; 1.1429x over previous
//
#include <hip/hip_runtime.h>
#include <hip/hip_bf16.h>
#include <math.h>

#define NEG_SLOPE 0.2f

typedef __attribute__((ext_vector_type(8))) __bf16 bf16x8;
typedef __attribute__((ext_vector_type(4))) float f32x4;

// ---------------- helpers ----------------
__device__ inline float lrelu(float v) { return v > 0.f ? v : NEG_SLOPE * v; }

__device__ inline unsigned short f2bf(float f) {
    __hip_bfloat16 h = __float2bfloat16(f);
    return *reinterpret_cast<unsigned short*>(&h);
}
__device__ inline float bf_lo(unsigned u) { return __uint_as_float(u << 16); }
__device__ inline float bf_hi(unsigned u) { return __uint_as_float(u & 0xffff0000u); }

template <int H>
__device__ inline float sel_h(const float* a, int h) {
    if (H == 1) return a[0];
    return (h & 2) ? ((h & 1) ? a[3] : a[2]) : ((h & 1) ? a[1] : a[0]);
}

// ---------------- CSR build ----------------
__global__ void count_deg_kernel(const int* __restrict__ ei, int E, int N,
                                 int* __restrict__ deg) {
    int e = blockIdx.x * blockDim.x + threadIdx.x;
    if (e >= E + N) return;
    int dst = (e < E) ? ei[E + e] : (e - E);
    atomicAdd(&deg[dst], 1);
}

__global__ void scan_kernel(const int* __restrict__ deg, int* __restrict__ off, int N) {
    __shared__ int sums[1024];
    int tid = threadIdx.x;
    int chunk = (N + 1023) / 1024;
    int start = tid * chunk;
    int end = start + chunk; if (end > N) end = N;
    int s = 0;
    for (int i = start; i < end && i < N; i++) s += deg[i];
    sums[tid] = s;
    __syncthreads();
    for (int d = 1; d < 1024; d <<= 1) {
        int v = 0;
        if (tid >= d) v = sums[tid - d];
        __syncthreads();
        if (tid >= d) sums[tid] += v;
        __syncthreads();
    }
    int prefix = (tid == 0) ? 0 : sums[tid - 1];
    int run = prefix;
    for (int i = start; i < end && i < N; i++) { off[i] = run; run += deg[i]; }
    if (tid == 1023) off[N] = sums[1023];
}

__global__ void scatter_kernel(const int* __restrict__ ei, int E, int N,
                               const int* __restrict__ off, int* __restrict__ cursor,
                               int* __restrict__ csr_src) {
    int e = blockIdx.x * blockDim.x + threadIdx.x;
    if (e >= E + N) return;
    int src, dst;
    if (e < E) { src = ei[e]; dst = ei[E + e]; }
    else       { src = dst = e - E; }
    int pos = off[dst] + atomicAdd(&cursor[dst], 1);
    csr_src[pos] = src;
}

// ---------------- fp32 -> bf16 cast (vectorized), n % 4 == 0 ----------------
__global__ void cast_bf16_kernel(const float* __restrict__ in, unsigned short* __restrict__ out,
                                 size_t n4) {
    size_t i = (size_t)blockIdx.x * blockDim.x + threadIdx.x;
    if (i >= n4) return;
    float4 v = reinterpret_cast<const float4*>(in)[i];
    ushort4 o;
    o.x = f2bf(v.x); o.y = f2bf(v.y); o.z = f2bf(v.z); o.w = f2bf(v.w);
    reinterpret_cast<ushort4*>(out)[i] = o;
}

// ---------------- transpose-cast: out[n*K + k] = bf16(in[k*N + n]) ----------------
__global__ void transpose_cast_kernel(const float* __restrict__ in, unsigned short* __restrict__ out,
                                      int K, int N) {
    int idx = blockIdx.x * blockDim.x + threadIdx.x;
    if (idx >= K * N) return;
    int n = idx / K, k = idx % K;
    out[(size_t)n * K + k] = f2bf(in[(size_t)k * N + n]);
}

// ---------------- bf16 MFMA GEMM + fused attention-logit epilogue ----------------
template <int HEADS>
__global__ __launch_bounds__(256) void gemm_bf16_alpha(const unsigned short* __restrict__ A,
                                                       const unsigned short* __restrict__ Bt,
                                                       unsigned short* __restrict__ C,
                                                       int M, int N, int K,
                                                       const float* __restrict__ a_src,
                                                       const float* __restrict__ a_dst,
                                                       float* __restrict__ alS,
                                                       float* __restrict__ alD) {
    __shared__ unsigned short Asl[128 * 32];
    __shared__ unsigned short Bsl[128 * 32];
    const int tid  = threadIdx.x;
    const int lane = tid & 63;
    const int wave = tid >> 6;
    const int rowBase = blockIdx.y * 128;
    const int colBase = blockIdx.x * 128;
    const int wm = (wave & 1) * 64;
    const int wn = (wave >> 1) * 64;
    const int q   = lane >> 4;
    const int l16 = lane & 15;

    f32x4 acc[4][4] = {};

    for (int k0 = 0; k0 < K; k0 += 32) {
#pragma unroll
        for (int it = 0; it < 2; it++) {
            int s = it * 256 + tid;
            int r = s >> 2;
            int c = (s & 3) * 8;
            int ga = rowBase + r; if (ga >= M) ga = M - 1;
            const unsigned short* gpa = A + (size_t)ga * K + k0 + c;
            __builtin_amdgcn_global_load_lds(
                (const __attribute__((address_space(1))) void*)gpa,
                (__attribute__((address_space(3))) void*)&Asl[(size_t)(it * 256 + wave * 64) * 8],
                16, 0, 0);
            const unsigned short* gpb = Bt + (size_t)(colBase + r) * K + k0 + c;
            __builtin_amdgcn_global_load_lds(
                (const __attribute__((address_space(1))) void*)gpb,
                (__attribute__((address_space(3))) void*)&Bsl[(size_t)(it * 256 + wave * 64) * 8],
                16, 0, 0);
        }
        __syncthreads();

        bf16x8 af[4], bfv[4];
#pragma unroll
        for (int mi = 0; mi < 4; mi++)
            af[mi] = *reinterpret_cast<const bf16x8*>(&Asl[(wm + mi * 16 + l16) * 32 + q * 8]);
#pragma unroll
        for (int ni = 0; ni < 4; ni++)
            bfv[ni] = *reinterpret_cast<const bf16x8*>(&Bsl[(wn + ni * 16 + l16) * 32 + q * 8]);
#pragma unroll
        for (int mi = 0; mi < 4; mi++)
#pragma unroll
            for (int ni = 0; ni < 4; ni++)
                acc[mi][ni] = __builtin_amdgcn_mfma_f32_16x16x32_bf16(af[mi], bfv[ni], acc[mi][ni], 0, 0, 0);
        __syncthreads();
    }

    const int hIdx = colBase >> 7;           // C==128 per head
    const float* asl = a_src + hIdx * 128;
    const float* adl = a_dst + hIdx * 128;
    float acoef[4], dcoef[4];
#pragma unroll
    for (int ni = 0; ni < 4; ni++) {
        int cl = wn + ni * 16 + l16;
        acoef[ni] = asl[cl];
        dcoef[ni] = adl[cl];
    }

#pragma unroll
    for (int mi = 0; mi < 4; mi++) {
#pragma unroll
        for (int r = 0; r < 4; r++) {
            int grow = rowBase + wm + mi * 16 + q * 4 + r;
            bool ok = grow < M;
            float vs = 0.f, vd = 0.f;
#pragma unroll
            for (int ni = 0; ni < 4; ni++) {
                float hv = acc[mi][ni][r];
                vs += hv * acoef[ni];
                vd += hv * dcoef[ni];
                if (ok) {
                    int gcol = colBase + wn + ni * 16 + l16;
                    C[(size_t)grow * N + gcol] = f2bf(hv);
                }
            }
#pragma unroll
            for (int d = 1; d < 16; d <<= 1) {
                vs += __shfl_xor(vs, d);
                vd += __shfl_xor(vd, d);
            }
            if (ok && l16 == 0) {
                atomicAdd(&alS[(size_t)grow * HEADS + hIdx], vs);
                atomicAdd(&alD[(size_t)grow * HEADS + hIdx], vd);
            }
        }
    }
}

// ---------------- fused segment softmax + aggregate (+optional head), wave/node -------
// Static-indexed double-buffered prefetch (depth 4+4) — no dynamic array indices,
// so everything stays in VGPRs (round-5 version was LDS/scratch-promoted).
// MODE 0: out = bf16, relu.  MODE 1 (H==1): fuse risk head, out = float per node.
template <int H, int C, int MODE>
__global__ __launch_bounds__(256) void gat_aggregate(const unsigned short* __restrict__ hb,
                                                     const float* __restrict__ alS,
                                                     const float* __restrict__ alD,
                                                     const int* __restrict__ off,
                                                     const int* __restrict__ csr_src,
                                                     const float* __restrict__ bias,
                                                     void* __restrict__ outbuf,
                                                     const float* __restrict__ Ws1,
                                                     const float* __restrict__ bs1,
                                                     const float* __restrict__ Ws2,
                                                     const float* __restrict__ bs2,
                                                     int N) {
    constexpr int HC = H * C;
    constexpr int PER = HC / 64;
    int n = (blockIdx.x * blockDim.x + threadIdx.x) >> 6;
    int lane = threadIdx.x & 63;
    if (n >= N) return;
    int beg = off[n], end = off[n + 1];

    float ad[H];
#pragma unroll
    for (int h = 0; h < H; h++) ad[h] = alD[n * H + h];

    const int myh = (lane * PER) / C;
    const unsigned short* hbl = hb + (size_t)lane * PER;

    float m[H], den[H], acc[PER];
#pragma unroll
    for (int h = 0; h < H; h++) { m[h] = -1e30f; den[h] = 0.f; }
#pragma unroll
    for (int j = 0; j < PER; j++) acc[j] = 0.f;

    for (int base = beg; base < end; base += 64) {
        int cnt = end - base; if (cnt > 64) cnt = 64;
        bool act = lane < cnt;
        int s_l = csr_src[act ? (base + lane) : base];

        // per-lane logit for its edge
        float v[H];
        if (H == 4) {
            float4 a4 = *reinterpret_cast<const float4*>(&alS[s_l * 4]);
            v[0] = a4.x + ad[0]; v[1] = a4.y + ad[1];
            v[2] = a4.z + ad[2]; v[3] = a4.w + ad[3];
        } else {
            v[0] = alS[s_l] + ad[0];
        }
#pragma unroll
        for (int h = 0; h < H; h++) v[h] = act ? lrelu(v[h]) : -1e30f;

        // chunk max + chunk denom (wave butterflies)
        float mc[H], pl[H], dc[H];
#pragma unroll
        for (int h = 0; h < H; h++) {
            mc[h] = v[h];
#pragma unroll
            for (int d = 1; d < 64; d <<= 1) mc[h] = fmaxf(mc[h], __shfl_xor(mc[h], d));
            pl[h] = __expf(v[h] - mc[h]);           // inactive lanes -> 0
            dc[h] = pl[h];
#pragma unroll
            for (int d = 1; d < 64; d <<= 1) dc[h] += __shfl_xor(dc[h], d);
        }
        // merge chunk stats into running (m, den); rescale acc
        float soA[H], wl[H];
#pragma unroll
        for (int h = 0; h < H; h++) {
            float nm = fmaxf(m[h], mc[h]);
            float so = __expf(m[h] - nm);
            float sc = __expf(mc[h] - nm);
            den[h] = den[h] * so + dc[h] * sc;
            m[h] = nm;
            soA[h] = so;
            wl[h] = pl[h] * sc;      // this lane's edge weight (unnormalized vs new m)
        }
        float sAcc = sel_h<H>(soA, myh);
#pragma unroll
        for (int j = 0; j < PER; j++) acc[j] *= sAcc;

        // weighted accumulate: static double-buffered groups of 4
        if (PER == 8) {
            uint4 bufA0, bufA1, bufA2, bufA3, bufB0, bufB1, bufB2, bufB3;
            float wA0, wA1, wA2, wA3, wB0, wB1, wB2, wB3;

#define FETCH8(B0, B1, B2, B3, W0, W1, W2, W3, I0)                                  \
            {                                                                       \
                int j0 = (I0);                                                      \
                if (j0 + 0 < cnt) {                                                 \
                    int s = __shfl(s_l, j0 + 0);                                    \
                    float t0 = __shfl(wl[0], j0 + 0), t1 = __shfl(wl[1], j0 + 0),   \
                          t2 = __shfl(wl[2], j0 + 0), t3 = __shfl(wl[3], j0 + 0);   \
                    float tt[4] = {t0, t1, t2, t3};                                 \
                    W0 = sel_h<H>(tt, myh);                                         \
                    B0 = *reinterpret_cast<const uint4*>(hbl + (size_t)s * HC);     \
                }                                                                   \
                if (j0 + 1 < cnt) {                                                 \
                    int s = __shfl(s_l, j0 + 1);                                    \
                    float t0 = __shfl(wl[0], j0 + 1), t1 = __shfl(wl[1], j0 + 1),   \
                          t2 = __shfl(wl[2], j0 + 1), t3 = __shfl(wl[3], j0 + 1);   \
                    float tt[4] = {t0, t1, t2, t3};                                 \
                    W1 = sel_h<H>(tt, myh);                                         \
                    B1 = *reinterpret_cast<const uint4*>(hbl + (size_t)s * HC);     \
                }                                                                   \
                if (j0 + 2 < cnt) {                                                 \
                    int s = __shfl(s_l, j0 + 2);                                    \
                    float t0 = __shfl(wl[0], j0 + 2), t1 = __shfl(wl[1], j0 + 2),   \
                          t2 = __shfl(wl[2], j0 + 2), t3 = __shfl(wl[3], j0 + 2);   \
                    float tt[4] = {t0, t1, t2, t3};                                 \
                    W2 = sel_h<H>(tt, myh);                                         \
                    B2 = *reinterpret_cast<const uint4*>(hbl + (size_t)s * HC);     \
                }                                                                   \
                if (j0 + 3 < cnt) {                                                 \
                    int s = __shfl(s_l, j0 + 3);                                    \
                    float t0 = __shfl(wl[0], j0 + 3), t1 = __shfl(wl[1], j0 + 3),   \
                          t2 = __shfl(wl[2], j0 + 3), t3 = __shfl(wl[3], j0 + 3);   \
                    float tt[4] = {t0, t1, t2, t3};                                 \
                    W3 = sel_h<H>(tt, myh);                                         \
                    B3 = *reinterpret_cast<const uint4*>(hbl + (size_t)s * HC);     \
                }                                                                   \
            }

#define CONS8(B0, B1, B2, B3, W0, W1, W2, W3, I0)                                   \
            {                                                                       \
                int j0 = (I0);                                                      \
                if (j0 + 0 < cnt) {                                                 \
                    uint4 rc = B0; float w = W0;                                    \
                    acc[0] += bf_lo(rc.x) * w; acc[1] += bf_hi(rc.x) * w;           \
                    acc[2] += bf_lo(rc.y) * w; acc[3] += bf_hi(rc.y) * w;           \
                    acc[4] += bf_lo(rc.z) * w; acc[5] += bf_hi(rc.z) * w;           \
                    acc[6] += bf_lo(rc.w) * w; acc[7] += bf_hi(rc.w) * w;           \
                }                                                                   \
                if (j0 + 1 < cnt) {                                                 \
                    uint4 rc = B1; float w = W1;                                    \
                    acc[0] += bf_lo(rc.x) * w; acc[1] += bf_hi(rc.x) * w;           \
                    acc[2] += bf_lo(rc.y) * w; acc[3] += bf_hi(rc.y) * w;           \
                    acc[4] += bf_lo(rc.z) * w; acc[5] += bf_hi(rc.z) * w;           \
                    acc[6] += bf_lo(rc.w) * w; acc[7] += bf_hi(rc.w) * w;           \
                }                                                                   \
                if (j0 + 2 < cnt) {                                                 \
                    uint4 rc = B2; float w = W2;                                    \
                    acc[0] += bf_lo(rc.x) * w; acc[1] += bf_hi(rc.x) * w;           \
                    acc[2] += bf_lo(rc.y) * w; acc[3] += bf_hi(rc.y) * w;           \
                    acc[4] += bf_lo(rc.z) * w; acc[5] += bf_hi(rc.z) * w;           \
                    acc[6] += bf_lo(rc.w) * w; acc[7] += bf_hi(rc.w) * w;           \
                }                                                                   \
                if (j0 + 3 < cnt) {                                                 \
                    uint4 rc = B3; float w = W3;                                    \
                    acc[0] += bf_lo(rc.x) * w; acc[1] += bf_hi(rc.x) * w;           \
                    acc[2] += bf_lo(rc.y) * w; acc[3] += bf_hi(rc.y) * w;           \
                    acc[4] += bf_lo(rc.z) * w; acc[5] += bf_hi(rc.z) * w;           \
                    acc[6] += bf_lo(rc.w) * w; acc[7] += bf_hi(rc.w) * w;           \
                }                                                                   \
            }

            FETCH8(bufA0, bufA1, bufA2, bufA3, wA0, wA1, wA2, wA3, 0);
            for (int i = 0; i < cnt; i += 8) {
                FETCH8(bufB0, bufB1, bufB2, bufB3, wB0, wB1, wB2, wB3, i + 4);
                CONS8(bufA0, bufA1, bufA2, bufA3, wA0, wA1, wA2, wA3, i);
                FETCH8(bufA0, bufA1, bufA2, bufA3, wA0, wA1, wA2, wA3, i + 8);
                CONS8(bufB0, bufB1, bufB2, bufB3, wB0, wB1, wB2, wB3, i + 4);
            }
#undef FETCH8
#undef CONS8
        } else {
            unsigned bufA0, bufA1, bufA2, bufA3, bufB0, bufB1, bufB2, bufB3;
            float wA0, wA1, wA2, wA3, wB0, wB1, wB2, wB3;

#define FETCH2(B0, B1, B2, B3, W0, W1, W2, W3, I0)                                  \
            {                                                                       \
                int j0 = (I0);                                                      \
                if (j0 + 0 < cnt) {                                                 \
                    int s = __shfl(s_l, j0 + 0); W0 = __shfl(wl[0], j0 + 0);        \
                    B0 = *reinterpret_cast<const unsigned*>(hbl + (size_t)s * HC);  \
                }                                                                   \
                if (j0 + 1 < cnt) {                                                 \
                    int s = __shfl(s_l, j0 + 1); W1 = __shfl(wl[0], j0 + 1);        \
                    B1 = *reinterpret_cast<const unsigned*>(hbl + (size_t)s * HC);  \
                }                                                                   \
                if (j0 + 2 < cnt) {                                                 \
                    int s = __shfl(s_l, j0 + 2); W2 = __shfl(wl[0], j0 + 2);        \
                    B2 = *reinterpret_cast<const unsigned*>(hbl + (size_t)s * HC);  \
                }                                                                   \
                if (j0 + 3 < cnt) {                                                 \
                    int s = __shfl(s_l, j0 + 3); W3 = __shfl(wl[0], j0 + 3);        \
                    B3 = *reinterpret_cast<const unsigned*>(hbl + (size_t)s * HC);  \
                }                                                                   \
            }

#define CONS2(B0, B1, B2, B3, W0, W1, W2, W3, I0)                                   \
            {                                                                       \
                int j0 = (I0);                                                      \
                if (j0 + 0 < cnt) { acc[0] += bf_lo(B0) * W0; acc[1] += bf_hi(B0) * W0; } \
                if (j0 + 1 < cnt) { acc[0] += bf_lo(B1) * W1; acc[1] += bf_hi(B1) * W1; } \
                if (j0 + 2 < cnt) { acc[0] += bf_lo(B2) * W2; acc[1] += bf_hi(B2) * W2; } \
                if (j0 + 3 < cnt) { acc[0] += bf_lo(B3) * W3; acc[1] += bf_hi(B3) * W3; } \
            }

            FETCH2(bufA0, bufA1, bufA2, bufA3, wA0, wA1, wA2, wA3, 0);
            for (int i = 0; i < cnt; i += 8) {
                FETCH2(bufB0, bufB1, bufB2, bufB3, wB0, wB1, wB2, wB3, i + 4);
                CONS2(bufA0, bufA1, bufA2, bufA3, wA0, wA1, wA2, wA3, i);
                FETCH2(bufA0, bufA1, bufA2, bufA3, wA0, wA1, wA2, wA3, i + 8);
                CONS2(bufB0, bufB1, bufB2, bufB3, wB0, wB1, wB2, wB3, i + 4);
            }
#undef FETCH2
#undef CONS2
        }
    }

    float invd = 1.f / sel_h<H>(den, myh);

    if (MODE == 0) {
#pragma unroll
        for (int j = 0; j < PER; j++) {
            int c = lane * PER + j;
            float val = fmaxf(acc[j] * invd + bias[c], 0.f);
            ((unsigned short*)outbuf)[(size_t)n * HC + c] = f2bf(val);
        }
    } else {
        // H==1, PER==2: channels (2*lane, 2*lane+1) -> fused risk head
        float h0 = acc[0] * invd + bias[2 * lane];
        float h1 = acc[1] * invd + bias[2 * lane + 1];
        float s = 0.f;
#pragma unroll
        for (int k = 0; k < 64; k++) {
            float a = __shfl(h0, k);
            float b = __shfl(h1, k);
            s += a * Ws1[(2 * k) * 64 + lane];
            s += b * Ws1[(2 * k + 1) * 64 + lane];
        }
        s = fmaxf(s + bs1[lane], 0.f);
        float z = s * Ws2[lane];
#pragma unroll
        for (int d = 1; d < 64; d <<= 1) z += __shfl_xor(z, d);
        if (lane == 0) ((float*)outbuf)[n] = 1.f / (1.f + __expf(-(z + bs2[0])));
    }
}

// ---------------- launch ----------------
extern "C" void kernel_launch(void* const* d_in, const int* in_sizes, int n_in,
                              void* d_out, int out_size, void* d_ws, size_t ws_size,
                              hipStream_t stream) {
    const float* x   = (const float*)d_in[0];
    const int*   ei  = (const int*)d_in[1];
    const float* W1  = (const float*)d_in[2];
    const float* as1 = (const float*)d_in[3];
    const float* ad1 = (const float*)d_in[4];
    const float* b1  = (const float*)d_in[5];
    const float* W2  = (const float*)d_in[6];
    const float* as2 = (const float*)d_in[7];
    const float* ad2 = (const float*)d_in[8];
    const float* b2  = (const float*)d_in[9];
    const float* W3  = (const float*)d_in[10];
    const float* as3 = (const float*)d_in[11];
    const float* ad3 = (const float*)d_in[12];
    const float* b3  = (const float*)d_in[13];
    const float* Ws1 = (const float*)d_in[14];
    const float* bs1 = (const float*)d_in[15];
    const float* Ws2 = (const float*)d_in[16];
    const float* bs2 = (const float*)d_in[17];

    const int N = out_size;            // 20000
    const int E = in_sizes[1] / 2;     // 160000
    const int D = in_sizes[0] / N;     // 768
    const int HC = 512, H = 4, C = 128;
    const int Etot = E + N;

    char* p = (char*)d_ws;
    auto alloc = [&](size_t bytes) -> void* {
        void* q = (void*)p;
        p += (bytes + 255) & ~(size_t)255;
        return q;
    };
    // --- zeroed region (deg, cursor, alS/alD x3) ---
    char*  zbeg   = p;
    int*   deg    = (int*)alloc((size_t)N * 4);
    int*   cursor = (int*)alloc((size_t)N * 4);
    float* alS1   = (float*)alloc((size_t)N * H * 4);
    float* alD1   = (float*)alloc((size_t)N * H * 4);
    float* alS2   = (float*)alloc((size_t)N * H * 4);
    float* alD2   = (float*)alloc((size_t)N * H * 4);
    float* alS3   = (float*)alloc((size_t)N * 4);
    float* alD3   = (float*)alloc((size_t)N * 4);
    char*  zend   = p;
    // --- rest ---
    int*   off    = (int*)alloc((size_t)(N + 1) * 4);
    int*   csr    = (int*)alloc((size_t)Etot * 4);
    unsigned short* hbuf = (unsigned short*)alloc((size_t)N * HC * 2);
    unsigned short* xbf  = (unsigned short*)alloc((size_t)N * D * 2);
    unsigned short* obf  = (unsigned short*)alloc((size_t)N * HC * 2);
    unsigned short* W1t  = (unsigned short*)alloc((size_t)D * HC * 2);
    unsigned short* W2t  = (unsigned short*)alloc((size_t)HC * HC * 2);
    unsigned short* W3t  = (unsigned short*)alloc((size_t)HC * C * 2);

    hipMemsetAsync(zbeg, 0, (size_t)(zend - zbeg), stream);

    const int tb = 256;
    count_deg_kernel<<<(Etot + tb - 1) / tb, tb, 0, stream>>>(ei, E, N, deg);
    scan_kernel<<<1, 1024, 0, stream>>>(deg, off, N);
    scatter_kernel<<<(Etot + tb - 1) / tb, tb, 0, stream>>>(ei, E, N, off, cursor, csr);

    {
        size_t n4 = (size_t)N * D / 4;
        cast_bf16_kernel<<<(int)((n4 + 255) / 256), 256, 0, stream>>>(x, xbf, n4);
        transpose_cast_kernel<<<(D * HC + 255) / 256, 256, 0, stream>>>(W1, W1t, D, HC);
        transpose_cast_kernel<<<(HC * HC + 255) / 256, 256, 0, stream>>>(W2, W2t, HC, HC);
        transpose_cast_kernel<<<(HC * C + 255) / 256, 256, 0, stream>>>(W3, W3t, HC, C);
    }

    int node_blocks = (N + 3) / 4;     // one wave per node
    int rowTiles = (N + 127) / 128;

    // ---- layer 1 ----
    gemm_bf16_alpha<4><<<dim3(HC / 128, rowTiles), 256, 0, stream>>>(
        xbf, W1t, hbuf, N, HC, D, as1, ad1, alS1, alD1);
    gat_aggregate<4, 128, 0><<<node_blocks, 256, 0, stream>>>(
        hbuf, alS1, alD1, off, csr, b1, obf, nullptr, nullptr, nullptr, nullptr, N);

    // ---- layer 2 ----
    gemm_bf16_alpha<4><<<dim3(HC / 128, rowTiles), 256, 0, stream>>>(
        obf, W2t, hbuf, N, HC, HC, as2, ad2, alS2, alD2);
    gat_aggregate<4, 128, 0><<<node_blocks, 256, 0, stream>>>(
        hbuf, alS2, alD2, off, csr, b2, obf, nullptr, nullptr, nullptr, nullptr, N);

    // ---- layer 3 (H=1) + fused head ----
    gemm_bf16_alpha<1><<<dim3(C / 128, rowTiles), 256, 0, stream>>>(
        obf, W3t, hbuf, N, C, HC, as3, ad3, alS3, alD3);
    gat_aggregate<1, 128, 1><<<node_blocks, 256, 0, stream>>>(
        hbuf, alS3, alD3, off, csr, b3, (float*)d_out, Ws1, bs1, Ws2, bs2, N);
}

// Round 7
// 397.552 us; speedup vs baseline: 1.3020x; 1.1392x over previous
//
#include <hip/hip_runtime.h>
#include <hip/hip_bf16.h>
#include <math.h>

#define NEG_SLOPE 0.2f

typedef __attribute__((ext_vector_type(8))) __bf16 bf16x8;
typedef __attribute__((ext_vector_type(4))) float f32x4;

// ---------------- helpers ----------------
__device__ inline float lrelu(float v) { return v > 0.f ? v : NEG_SLOPE * v; }

__device__ inline unsigned short f2bf(float f) {
    __hip_bfloat16 h = __float2bfloat16(f);
    return *reinterpret_cast<unsigned short*>(&h);
}
__device__ inline float bf_lo(unsigned u) { return __uint_as_float(u << 16); }
__device__ inline float bf_hi(unsigned u) { return __uint_as_float(u & 0xffff0000u); }

// by-VALUE head select: pure cndmask chain, no address-taken array
__device__ inline float sel4v(float a0, float a1, float a2, float a3, int h) {
    float rlo = (h & 1) ? a1 : a0;
    float rhi = (h & 1) ? a3 : a2;
    return (h & 2) ? rhi : rlo;
}

// online-softmax chunk statistics (scalar refs -> SSA after inline)
__device__ inline void chunk_stats(float v, float& m, float& den, float& wl, float& so) {
    float mc = v;
#pragma unroll
    for (int d = 1; d < 64; d <<= 1) mc = fmaxf(mc, __shfl_xor(mc, d));
    float pl = __expf(v - mc);          // inactive lanes (v=-1e30) -> 0
    float dc = pl;
#pragma unroll
    for (int d = 1; d < 64; d <<= 1) dc += __shfl_xor(dc, d);
    float nm = fmaxf(m, mc);
    so = __expf(m - nm);
    float sc = __expf(mc - nm);
    den = den * so + dc * sc;
    m = nm;
    wl = pl * sc;                       // this lane's edge weight vs new running max
}

// ---------------- CSR build ----------------
__global__ void count_deg_kernel(const int* __restrict__ ei, int E, int N,
                                 int* __restrict__ deg) {
    int e = blockIdx.x * blockDim.x + threadIdx.x;
    if (e >= E + N) return;
    int dst = (e < E) ? ei[E + e] : (e - E);
    atomicAdd(&deg[dst], 1);
}

__global__ void scan_kernel(const int* __restrict__ deg, int* __restrict__ off, int N) {
    __shared__ int sums[1024];
    int tid = threadIdx.x;
    int chunk = (N + 1023) / 1024;
    int start = tid * chunk;
    int end = start + chunk; if (end > N) end = N;
    int s = 0;
    for (int i = start; i < end && i < N; i++) s += deg[i];
    sums[tid] = s;
    __syncthreads();
    for (int d = 1; d < 1024; d <<= 1) {
        int v = 0;
        if (tid >= d) v = sums[tid - d];
        __syncthreads();
        if (tid >= d) sums[tid] += v;
        __syncthreads();
    }
    int prefix = (tid == 0) ? 0 : sums[tid - 1];
    int run = prefix;
    for (int i = start; i < end && i < N; i++) { off[i] = run; run += deg[i]; }
    if (tid == 1023) off[N] = sums[1023];
}

__global__ void scatter_kernel(const int* __restrict__ ei, int E, int N,
                               const int* __restrict__ off, int* __restrict__ cursor,
                               int* __restrict__ csr_src) {
    int e = blockIdx.x * blockDim.x + threadIdx.x;
    if (e >= E + N) return;
    int src, dst;
    if (e < E) { src = ei[e]; dst = ei[E + e]; }
    else       { src = dst = e - E; }
    int pos = off[dst] + atomicAdd(&cursor[dst], 1);
    csr_src[pos] = src;
}

// ---------------- fp32 -> bf16 cast (vectorized), n % 4 == 0 ----------------
__global__ void cast_bf16_kernel(const float* __restrict__ in, unsigned short* __restrict__ out,
                                 size_t n4) {
    size_t i = (size_t)blockIdx.x * blockDim.x + threadIdx.x;
    if (i >= n4) return;
    float4 v = reinterpret_cast<const float4*>(in)[i];
    ushort4 o;
    o.x = f2bf(v.x); o.y = f2bf(v.y); o.z = f2bf(v.z); o.w = f2bf(v.w);
    reinterpret_cast<ushort4*>(out)[i] = o;
}

// ---------------- transpose-cast: out[n*K + k] = bf16(in[k*N + n]) ----------------
__global__ void transpose_cast_kernel(const float* __restrict__ in, unsigned short* __restrict__ out,
                                      int K, int N) {
    int idx = blockIdx.x * blockDim.x + threadIdx.x;
    if (idx >= K * N) return;
    int n = idx / K, k = idx % K;
    out[(size_t)n * K + k] = f2bf(in[(size_t)k * N + n]);
}

// ---------------- bf16 MFMA GEMM + fused attention-logit epilogue ----------------
template <int HEADS>
__global__ __launch_bounds__(256) void gemm_bf16_alpha(const unsigned short* __restrict__ A,
                                                       const unsigned short* __restrict__ Bt,
                                                       unsigned short* __restrict__ C,
                                                       int M, int N, int K,
                                                       const float* __restrict__ a_src,
                                                       const float* __restrict__ a_dst,
                                                       float* __restrict__ alS,
                                                       float* __restrict__ alD) {
    __shared__ unsigned short Asl[128 * 32];
    __shared__ unsigned short Bsl[128 * 32];
    const int tid  = threadIdx.x;
    const int lane = tid & 63;
    const int wave = tid >> 6;
    const int rowBase = blockIdx.y * 128;
    const int colBase = blockIdx.x * 128;
    const int wm = (wave & 1) * 64;
    const int wn = (wave >> 1) * 64;
    const int q   = lane >> 4;
    const int l16 = lane & 15;

    f32x4 acc[4][4] = {};

    for (int k0 = 0; k0 < K; k0 += 32) {
#pragma unroll
        for (int it = 0; it < 2; it++) {
            int s = it * 256 + tid;
            int r = s >> 2;
            int c = (s & 3) * 8;
            int ga = rowBase + r; if (ga >= M) ga = M - 1;
            const unsigned short* gpa = A + (size_t)ga * K + k0 + c;
            __builtin_amdgcn_global_load_lds(
                (const __attribute__((address_space(1))) void*)gpa,
                (__attribute__((address_space(3))) void*)&Asl[(size_t)(it * 256 + wave * 64) * 8],
                16, 0, 0);
            const unsigned short* gpb = Bt + (size_t)(colBase + r) * K + k0 + c;
            __builtin_amdgcn_global_load_lds(
                (const __attribute__((address_space(1))) void*)gpb,
                (__attribute__((address_space(3))) void*)&Bsl[(size_t)(it * 256 + wave * 64) * 8],
                16, 0, 0);
        }
        __syncthreads();

        bf16x8 af[4], bfv[4];
#pragma unroll
        for (int mi = 0; mi < 4; mi++)
            af[mi] = *reinterpret_cast<const bf16x8*>(&Asl[(wm + mi * 16 + l16) * 32 + q * 8]);
#pragma unroll
        for (int ni = 0; ni < 4; ni++)
            bfv[ni] = *reinterpret_cast<const bf16x8*>(&Bsl[(wn + ni * 16 + l16) * 32 + q * 8]);
#pragma unroll
        for (int mi = 0; mi < 4; mi++)
#pragma unroll
            for (int ni = 0; ni < 4; ni++)
                acc[mi][ni] = __builtin_amdgcn_mfma_f32_16x16x32_bf16(af[mi], bfv[ni], acc[mi][ni], 0, 0, 0);
        __syncthreads();
    }

    const int hIdx = colBase >> 7;           // C==128 per head
    const float* asl = a_src + hIdx * 128;
    const float* adl = a_dst + hIdx * 128;
    float acoef[4], dcoef[4];
#pragma unroll
    for (int ni = 0; ni < 4; ni++) {
        int cl = wn + ni * 16 + l16;
        acoef[ni] = asl[cl];
        dcoef[ni] = adl[cl];
    }

#pragma unroll
    for (int mi = 0; mi < 4; mi++) {
#pragma unroll
        for (int r = 0; r < 4; r++) {
            int grow = rowBase + wm + mi * 16 + q * 4 + r;
            bool ok = grow < M;
            float vs = 0.f, vd = 0.f;
#pragma unroll
            for (int ni = 0; ni < 4; ni++) {
                float hv = acc[mi][ni][r];
                vs += hv * acoef[ni];
                vd += hv * dcoef[ni];
                if (ok) {
                    int gcol = colBase + wn + ni * 16 + l16;
                    C[(size_t)grow * N + gcol] = f2bf(hv);
                }
            }
#pragma unroll
            for (int d = 1; d < 16; d <<= 1) {
                vs += __shfl_xor(vs, d);
                vd += __shfl_xor(vd, d);
            }
            if (ok && l16 == 0) {
                atomicAdd(&alS[(size_t)grow * HEADS + hIdx], vs);
                atomicAdd(&alD[(size_t)grow * HEADS + hIdx], vd);
            }
        }
    }
}

// ---------------- fused segment softmax + aggregate (+optional head), wave/node -------
// ALL hot-path state is named scalars; head selection is by-value cndmask (sel4v).
// No address-taken allocas -> nothing can be promoted to LDS/scratch.
// MODE 0: out = bf16 + relu.  MODE 1 (H==1): fused risk head, out = float per node.
template <int H, int C, int MODE>
__global__ __launch_bounds__(256) void gat_aggregate(const unsigned short* __restrict__ hb,
                                                     const float* __restrict__ alS,
                                                     const float* __restrict__ alD,
                                                     const int* __restrict__ off,
                                                     const int* __restrict__ csr_src,
                                                     const float* __restrict__ bias,
                                                     void* __restrict__ outbuf,
                                                     const float* __restrict__ Ws1,
                                                     const float* __restrict__ bs1,
                                                     const float* __restrict__ Ws2,
                                                     const float* __restrict__ bs2,
                                                     int N) {
    constexpr int HC = H * C;
    constexpr int PER = HC / 64;
    int n = (blockIdx.x * blockDim.x + threadIdx.x) >> 6;
    int lane = threadIdx.x & 63;
    if (n >= N) return;
    int beg = off[n], end = off[n + 1];

    float ad0 = 0.f, ad1 = 0.f, ad2 = 0.f, ad3 = 0.f;
    if (H == 4) {
        float4 t = *reinterpret_cast<const float4*>(&alD[n * 4]);
        ad0 = t.x; ad1 = t.y; ad2 = t.z; ad3 = t.w;
    } else {
        ad0 = alD[n];
    }

    const int myh = (lane * PER) / C;
    const unsigned short* hbl = hb + (size_t)lane * PER;

    float m0 = -1e30f, m1 = -1e30f, m2 = -1e30f, m3 = -1e30f;
    float dn0 = 0.f, dn1 = 0.f, dn2 = 0.f, dn3 = 0.f;
    float acc0 = 0.f, acc1 = 0.f, acc2 = 0.f, acc3 = 0.f,
          acc4 = 0.f, acc5 = 0.f, acc6 = 0.f, acc7 = 0.f;

    for (int base = beg; base < end; base += 64) {
        int cnt = end - base; if (cnt > 64) cnt = 64;
        bool act = lane < cnt;
        int s_l = csr_src[act ? (base + lane) : base];

        float v0 = -1e30f, v1 = -1e30f, v2 = -1e30f, v3 = -1e30f;
        if (H == 4) {
            float4 a4 = *reinterpret_cast<const float4*>(&alS[s_l * 4]);
            v0 = act ? lrelu(a4.x + ad0) : -1e30f;
            v1 = act ? lrelu(a4.y + ad1) : -1e30f;
            v2 = act ? lrelu(a4.z + ad2) : -1e30f;
            v3 = act ? lrelu(a4.w + ad3) : -1e30f;
        } else {
            v0 = act ? lrelu(alS[s_l] + ad0) : -1e30f;
        }

        float wl0 = 0.f, wl1 = 0.f, wl2 = 0.f, wl3 = 0.f;
        float so0 = 0.f, so1 = 0.f, so2 = 0.f, so3 = 0.f;
        chunk_stats(v0, m0, dn0, wl0, so0);
        if (H == 4) {
            chunk_stats(v1, m1, dn1, wl1, so1);
            chunk_stats(v2, m2, dn2, wl2, so2);
            chunk_stats(v3, m3, dn3, wl3, so3);
        }
        float sAcc = (H == 4) ? sel4v(so0, so1, so2, so3, myh) : so0;
        acc0 *= sAcc; acc1 *= sAcc;
        if (PER == 8) {
            acc2 *= sAcc; acc3 *= sAcc; acc4 *= sAcc; acc5 *= sAcc;
            acc6 *= sAcc; acc7 *= sAcc;
        }

        if (PER == 8) {
            uint4 bA0 = {}, bA1 = {}, bA2 = {}, bA3 = {},
                  bB0 = {}, bB1 = {}, bB2 = {}, bB3 = {};
            float wA0 = 0, wA1 = 0, wA2 = 0, wA3 = 0,
                  wB0 = 0, wB1 = 0, wB2 = 0, wB3 = 0;
#define FETCH(jj, B, W)                                                          \
            { int j_ = (jj);                                                     \
              if (j_ < cnt) {                                                    \
                int s_ = __shfl(s_l, j_);                                        \
                float u0 = __shfl(wl0, j_), u1 = __shfl(wl1, j_),                \
                      u2 = __shfl(wl2, j_), u3 = __shfl(wl3, j_);                \
                W = sel4v(u0, u1, u2, u3, myh);                                  \
                B = *reinterpret_cast<const uint4*>(hbl + (size_t)s_ * HC);      \
              } }
#define CONS(jj, B, W)                                                           \
            { if ((jj) < cnt) {                                                  \
                acc0 += bf_lo(B.x) * W; acc1 += bf_hi(B.x) * W;                  \
                acc2 += bf_lo(B.y) * W; acc3 += bf_hi(B.y) * W;                  \
                acc4 += bf_lo(B.z) * W; acc5 += bf_hi(B.z) * W;                  \
                acc6 += bf_lo(B.w) * W; acc7 += bf_hi(B.w) * W;                  \
              } }
            FETCH(0, bA0, wA0); FETCH(1, bA1, wA1);
            FETCH(2, bA2, wA2); FETCH(3, bA3, wA3);
            for (int i = 0; i < cnt; i += 8) {
                FETCH(i + 4, bB0, wB0); FETCH(i + 5, bB1, wB1);
                FETCH(i + 6, bB2, wB2); FETCH(i + 7, bB3, wB3);
                CONS(i + 0, bA0, wA0); CONS(i + 1, bA1, wA1);
                CONS(i + 2, bA2, wA2); CONS(i + 3, bA3, wA3);
                FETCH(i + 8, bA0, wA0); FETCH(i + 9, bA1, wA1);
                FETCH(i + 10, bA2, wA2); FETCH(i + 11, bA3, wA3);
                CONS(i + 4, bB0, wB0); CONS(i + 5, bB1, wB1);
                CONS(i + 6, bB2, wB2); CONS(i + 7, bB3, wB3);
            }
#undef FETCH
#undef CONS
        } else {
            unsigned bA0 = 0, bA1 = 0, bA2 = 0, bA3 = 0,
                     bB0 = 0, bB1 = 0, bB2 = 0, bB3 = 0;
            float wA0 = 0, wA1 = 0, wA2 = 0, wA3 = 0,
                  wB0 = 0, wB1 = 0, wB2 = 0, wB3 = 0;
#define FETCH(jj, B, W)                                                          \
            { int j_ = (jj);                                                     \
              if (j_ < cnt) {                                                    \
                int s_ = __shfl(s_l, j_);                                        \
                W = __shfl(wl0, j_);                                             \
                B = *reinterpret_cast<const unsigned*>(hbl + (size_t)s_ * HC);   \
              } }
#define CONS(jj, B, W)                                                           \
            { if ((jj) < cnt) { acc0 += bf_lo(B) * W; acc1 += bf_hi(B) * W; } }
            FETCH(0, bA0, wA0); FETCH(1, bA1, wA1);
            FETCH(2, bA2, wA2); FETCH(3, bA3, wA3);
            for (int i = 0; i < cnt; i += 8) {
                FETCH(i + 4, bB0, wB0); FETCH(i + 5, bB1, wB1);
                FETCH(i + 6, bB2, wB2); FETCH(i + 7, bB3, wB3);
                CONS(i + 0, bA0, wA0); CONS(i + 1, bA1, wA1);
                CONS(i + 2, bA2, wA2); CONS(i + 3, bA3, wA3);
                FETCH(i + 8, bA0, wA0); FETCH(i + 9, bA1, wA1);
                FETCH(i + 10, bA2, wA2); FETCH(i + 11, bA3, wA3);
                CONS(i + 4, bB0, wB0); CONS(i + 5, bB1, wB1);
                CONS(i + 6, bB2, wB2); CONS(i + 7, bB3, wB3);
            }
#undef FETCH
#undef CONS
        }
    }

    float invd = 1.f / ((H == 4) ? sel4v(dn0, dn1, dn2, dn3, myh) : dn0);

    if (MODE == 0) {
        unsigned short* op = (unsigned short*)outbuf + (size_t)n * HC + lane * PER;
        const float* bp = bias + lane * PER;
        if (PER == 8) {
            op[0] = f2bf(fmaxf(acc0 * invd + bp[0], 0.f));
            op[1] = f2bf(fmaxf(acc1 * invd + bp[1], 0.f));
            op[2] = f2bf(fmaxf(acc2 * invd + bp[2], 0.f));
            op[3] = f2bf(fmaxf(acc3 * invd + bp[3], 0.f));
            op[4] = f2bf(fmaxf(acc4 * invd + bp[4], 0.f));
            op[5] = f2bf(fmaxf(acc5 * invd + bp[5], 0.f));
            op[6] = f2bf(fmaxf(acc6 * invd + bp[6], 0.f));
            op[7] = f2bf(fmaxf(acc7 * invd + bp[7], 0.f));
        } else {
            op[0] = f2bf(fmaxf(acc0 * invd + bp[0], 0.f));
            op[1] = f2bf(fmaxf(acc1 * invd + bp[1], 0.f));
        }
    } else {
        // H==1, PER==2: channels (2*lane, 2*lane+1) -> fused risk head
        float h0 = acc0 * invd + bias[2 * lane];
        float h1 = acc1 * invd + bias[2 * lane + 1];
        float s = 0.f;
#pragma unroll
        for (int k = 0; k < 64; k++) {
            float a = __shfl(h0, k);
            float b = __shfl(h1, k);
            s += a * Ws1[(2 * k) * 64 + lane];
            s += b * Ws1[(2 * k + 1) * 64 + lane];
        }
        s = fmaxf(s + bs1[lane], 0.f);
        float z = s * Ws2[lane];
#pragma unroll
        for (int d = 1; d < 64; d <<= 1) z += __shfl_xor(z, d);
        if (lane == 0) ((float*)outbuf)[n] = 1.f / (1.f + __expf(-(z + bs2[0])));
    }
}

// ---------------- launch ----------------
extern "C" void kernel_launch(void* const* d_in, const int* in_sizes, int n_in,
                              void* d_out, int out_size, void* d_ws, size_t ws_size,
                              hipStream_t stream) {
    const float* x   = (const float*)d_in[0];
    const int*   ei  = (const int*)d_in[1];
    const float* W1  = (const float*)d_in[2];
    const float* as1 = (const float*)d_in[3];
    const float* ad1 = (const float*)d_in[4];
    const float* b1  = (const float*)d_in[5];
    const float* W2  = (const float*)d_in[6];
    const float* as2 = (const float*)d_in[7];
    const float* ad2 = (const float*)d_in[8];
    const float* b2  = (const float*)d_in[9];
    const float* W3  = (const float*)d_in[10];
    const float* as3 = (const float*)d_in[11];
    const float* ad3 = (const float*)d_in[12];
    const float* b3  = (const float*)d_in[13];
    const float* Ws1 = (const float*)d_in[14];
    const float* bs1 = (const float*)d_in[15];
    const float* Ws2 = (const float*)d_in[16];
    const float* bs2 = (const float*)d_in[17];

    const int N = out_size;            // 20000
    const int E = in_sizes[1] / 2;     // 160000
    const int D = in_sizes[0] / N;     // 768
    const int HC = 512, H = 4, C = 128;
    const int Etot = E + N;

    char* p = (char*)d_ws;
    auto alloc = [&](size_t bytes) -> void* {
        void* q = (void*)p;
        p += (bytes + 255) & ~(size_t)255;
        return q;
    };
    // --- zeroed region (deg, cursor, alS/alD x3) ---
    char*  zbeg   = p;
    int*   deg    = (int*)alloc((size_t)N * 4);
    int*   cursor = (int*)alloc((size_t)N * 4);
    float* alS1   = (float*)alloc((size_t)N * H * 4);
    float* alD1   = (float*)alloc((size_t)N * H * 4);
    float* alS2   = (float*)alloc((size_t)N * H * 4);
    float* alD2   = (float*)alloc((size_t)N * H * 4);
    float* alS3   = (float*)alloc((size_t)N * 4);
    float* alD3   = (float*)alloc((size_t)N * 4);
    char*  zend   = p;
    // --- rest ---
    int*   off    = (int*)alloc((size_t)(N + 1) * 4);
    int*   csr    = (int*)alloc((size_t)Etot * 4);
    unsigned short* hbuf = (unsigned short*)alloc((size_t)N * HC * 2);
    unsigned short* xbf  = (unsigned short*)alloc((size_t)N * D * 2);
    unsigned short* obf  = (unsigned short*)alloc((size_t)N * HC * 2);
    unsigned short* W1t  = (unsigned short*)alloc((size_t)D * HC * 2);
    unsigned short* W2t  = (unsigned short*)alloc((size_t)HC * HC * 2);
    unsigned short* W3t  = (unsigned short*)alloc((size_t)HC * C * 2);

    hipMemsetAsync(zbeg, 0, (size_t)(zend - zbeg), stream);

    const int tb = 256;
    count_deg_kernel<<<(Etot + tb - 1) / tb, tb, 0, stream>>>(ei, E, N, deg);
    scan_kernel<<<1, 1024, 0, stream>>>(deg, off, N);
    scatter_kernel<<<(Etot + tb - 1) / tb, tb, 0, stream>>>(ei, E, N, off, cursor, csr);

    {
        size_t n4 = (size_t)N * D / 4;
        cast_bf16_kernel<<<(int)((n4 + 255) / 256), 256, 0, stream>>>(x, xbf, n4);
        transpose_cast_kernel<<<(D * HC + 255) / 256, 256, 0, stream>>>(W1, W1t, D, HC);
        transpose_cast_kernel<<<(HC * HC + 255) / 256, 256, 0, stream>>>(W2, W2t, HC, HC);
        transpose_cast_kernel<<<(HC * C + 255) / 256, 256, 0, stream>>>(W3, W3t, HC, C);
    }

    int node_blocks = (N + 3) / 4;     // one wave per node
    int rowTiles = (N + 127) / 128;

    // ---- layer 1 ----
    gemm_bf16_alpha<4><<<dim3(HC / 128, rowTiles), 256, 0, stream>>>(
        xbf, W1t, hbuf, N, HC, D, as1, ad1, alS1, alD1);
    gat_aggregate<4, 128, 0><<<node_blocks, 256, 0, stream>>>(
        hbuf, alS1, alD1, off, csr, b1, obf, nullptr, nullptr, nullptr, nullptr, N);

    // ---- layer 2 ----
    gemm_bf16_alpha<4><<<dim3(HC / 128, rowTiles), 256, 0, stream>>>(
        obf, W2t, hbuf, N, HC, HC, as2, ad2, alS2, alD2);
    gat_aggregate<4, 128, 0><<<node_blocks, 256, 0, stream>>>(
        hbuf, alS2, alD2, off, csr, b2, obf, nullptr, nullptr, nullptr, nullptr, N);

    // ---- layer 3 (H=1) + fused head ----
    gemm_bf16_alpha<1><<<dim3(C / 128, rowTiles), 256, 0, stream>>>(
        obf, W3t, hbuf, N, C, HC, as3, ad3, alS3, alD3);
    gat_aggregate<1, 128, 1><<<node_blocks, 256, 0, stream>>>(
        hbuf, alS3, alD3, off, csr, b3, (float*)d_out, Ws1, bs1, Ws2, bs2, N);
}

// Round 8
// 380.587 us; speedup vs baseline: 1.3600x; 1.0446x over previous
//
#include <hip/hip_runtime.h>
#include <hip/hip_bf16.h>
#include <math.h>

#define NEG_SLOPE 0.2f

typedef __attribute__((ext_vector_type(8))) __bf16 bf16x8;
typedef __attribute__((ext_vector_type(4))) float f32x4;

// ---------------- helpers ----------------
__device__ inline float lrelu(float v) { return v > 0.f ? v : NEG_SLOPE * v; }

__device__ inline unsigned short f2bf(float f) {
    __hip_bfloat16 h = __float2bfloat16(f);
    return *reinterpret_cast<unsigned short*>(&h);
}
__device__ inline float bf_lo(unsigned u) { return __uint_as_float(u << 16); }
__device__ inline float bf_hi(unsigned u) { return __uint_as_float(u & 0xffff0000u); }

// by-VALUE head select: pure cndmask chain, no address-taken array
__device__ inline float sel4v(float a0, float a1, float a2, float a3, int h) {
    float rlo = (h & 1) ? a1 : a0;
    float rhi = (h & 1) ? a3 : a2;
    return (h & 2) ? rhi : rlo;
}

// online-softmax chunk statistics (scalar refs -> SSA after inline)
__device__ inline void chunk_stats(float v, float& m, float& den, float& wl, float& so) {
    float mc = v;
#pragma unroll
    for (int d = 1; d < 64; d <<= 1) mc = fmaxf(mc, __shfl_xor(mc, d));
    float pl = __expf(v - mc);          // inactive lanes (v=-1e30) -> 0
    float dc = pl;
#pragma unroll
    for (int d = 1; d < 64; d <<= 1) dc += __shfl_xor(dc, d);
    float nm = fmaxf(m, mc);
    so = __expf(m - nm);
    float sc = __expf(mc - nm);
    den = den * so + dc * sc;
    m = nm;
    wl = pl * sc;                       // this lane's edge weight vs new running max
}

// ---------------- CSR build ----------------
__global__ void count_deg_kernel(const int* __restrict__ ei, int E, int N,
                                 int* __restrict__ deg) {
    int e = blockIdx.x * blockDim.x + threadIdx.x;
    if (e >= E + N) return;
    int dst = (e < E) ? ei[E + e] : (e - E);
    atomicAdd(&deg[dst], 1);
}

__global__ void scan_kernel(const int* __restrict__ deg, int* __restrict__ off, int N) {
    __shared__ int sums[1024];
    int tid = threadIdx.x;
    int chunk = (N + 1023) / 1024;
    int start = tid * chunk;
    int end = start + chunk; if (end > N) end = N;
    int s = 0;
    for (int i = start; i < end && i < N; i++) s += deg[i];
    sums[tid] = s;
    __syncthreads();
    for (int d = 1; d < 1024; d <<= 1) {
        int v = 0;
        if (tid >= d) v = sums[tid - d];
        __syncthreads();
        if (tid >= d) sums[tid] += v;
        __syncthreads();
    }
    int prefix = (tid == 0) ? 0 : sums[tid - 1];
    int run = prefix;
    for (int i = start; i < end && i < N; i++) { off[i] = run; run += deg[i]; }
    if (tid == 1023) off[N] = sums[1023];
}

__global__ void scatter_kernel(const int* __restrict__ ei, int E, int N,
                               const int* __restrict__ off, int* __restrict__ cursor,
                               int* __restrict__ csr_src) {
    int e = blockIdx.x * blockDim.x + threadIdx.x;
    if (e >= E + N) return;
    int src, dst;
    if (e < E) { src = ei[e]; dst = ei[E + e]; }
    else       { src = dst = e - E; }
    int pos = off[dst] + atomicAdd(&cursor[dst], 1);
    csr_src[pos] = src;
}

// ---------------- fp32 -> bf16 cast (vectorized), n % 4 == 0 ----------------
__global__ void cast_bf16_kernel(const float* __restrict__ in, unsigned short* __restrict__ out,
                                 size_t n4) {
    size_t i = (size_t)blockIdx.x * blockDim.x + threadIdx.x;
    if (i >= n4) return;
    float4 v = reinterpret_cast<const float4*>(in)[i];
    ushort4 o;
    o.x = f2bf(v.x); o.y = f2bf(v.y); o.z = f2bf(v.z); o.w = f2bf(v.w);
    reinterpret_cast<ushort4*>(out)[i] = o;
}

// ---------------- transpose-cast: out[n*K + k] = bf16(in[k*N + n]) ----------------
__global__ void transpose_cast_kernel(const float* __restrict__ in, unsigned short* __restrict__ out,
                                      int K, int N) {
    int idx = blockIdx.x * blockDim.x + threadIdx.x;
    if (idx >= K * N) return;
    int n = idx / K, k = idx % K;
    out[(size_t)n * K + k] = f2bf(in[(size_t)k * N + n]);
}

// ---------------- bf16 MFMA GEMM (BK=64, XOR-swizzled LDS) + alpha epilogue --------
// C[M,N] = A[M,K] @ Bt[N,K]^T, bf16 out. Col-tile (128) == one head slice.
// LDS layout: row-major [128][64] shorts, 16B chunk c stored at slot c ^ (row&7)
// -> ds_read_b128 bank-starts are 8 distinct x 2 lanes (2-way, free).
// Alpha epilogue: per-wave 64-col partials combined through LDS (no atomics).
template <int HEADS>
__global__ __launch_bounds__(256) void gemm_bf16_alpha(const unsigned short* __restrict__ A,
                                                       const unsigned short* __restrict__ Bt,
                                                       unsigned short* __restrict__ C,
                                                       int M, int N, int K,
                                                       const float* __restrict__ a_src,
                                                       const float* __restrict__ a_dst,
                                                       float* __restrict__ alS,
                                                       float* __restrict__ alD) {
    __shared__ unsigned short Asl[128 * 64];   // 16 KB
    __shared__ unsigned short Bsl[128 * 64];   // 16 KB
    const int tid  = threadIdx.x;
    const int lane = tid & 63;
    const int wave = tid >> 6;
    const int rowBase = blockIdx.y * 128;
    const int colBase = blockIdx.x * 128;
    const int wm = (wave & 1) * 64;
    const int wn = (wave >> 1) * 64;
    const int q   = lane >> 4;
    const int l16 = lane & 15;

    // staging geometry: slot s = it*256+tid covers row r=s>>3, chunk slot cs=s&7;
    // global chunk cg = cs ^ (r&7). r&7 == (tid>>3)&7 for all it -> cg is per-thread const.
    const int r0 = tid >> 3;                  // 0..31, row within 32-row group
    const int cg = (tid & 7) ^ (r0 & 7);      // global 16B-chunk index to fetch

    f32x4 acc[4][4] = {};

    for (int k0 = 0; k0 < K; k0 += 64) {
#pragma unroll
        for (int it = 0; it < 4; it++) {
            int s = it * 256 + tid;
            int r = it * 32 + r0;
            int ga = rowBase + r; if (ga >= M) ga = M - 1;
            const unsigned short* gpa = A + (size_t)ga * K + k0 + cg * 8;
            __builtin_amdgcn_global_load_lds(
                (const __attribute__((address_space(1))) void*)gpa,
                (__attribute__((address_space(3))) void*)&Asl[(size_t)s * 8],
                16, 0, 0);
            const unsigned short* gpb = Bt + (size_t)(colBase + r) * K + k0 + cg * 8;
            __builtin_amdgcn_global_load_lds(
                (const __attribute__((address_space(1))) void*)gpb,
                (__attribute__((address_space(3))) void*)&Bsl[(size_t)s * 8],
                16, 0, 0);
        }
        __syncthreads();

#pragma unroll
        for (int kh = 0; kh < 2; kh++) {
            bf16x8 af[4], bfv[4];
#pragma unroll
            for (int mi = 0; mi < 4; mi++) {
                int row = wm + mi * 16 + l16;
                int ch = (kh * 4 + q) ^ (row & 7);
                af[mi] = *reinterpret_cast<const bf16x8*>(&Asl[row * 64 + ch * 8]);
            }
#pragma unroll
            for (int ni = 0; ni < 4; ni++) {
                int row = wn + ni * 16 + l16;
                int ch = (kh * 4 + q) ^ (row & 7);
                bfv[ni] = *reinterpret_cast<const bf16x8*>(&Bsl[row * 64 + ch * 8]);
            }
#pragma unroll
            for (int mi = 0; mi < 4; mi++)
#pragma unroll
                for (int ni = 0; ni < 4; ni++)
                    acc[mi][ni] = __builtin_amdgcn_mfma_f32_16x16x32_bf16(af[mi], bfv[ni], acc[mi][ni], 0, 0, 0);
        }
        __syncthreads();
    }

    const int hIdx = colBase >> 7;           // C==128 per head
    const float* asl = a_src + hIdx * 128;
    const float* adl = a_dst + hIdx * 128;
    float acoef[4], dcoef[4];
#pragma unroll
    for (int ni = 0; ni < 4; ni++) {
        int cl = wn + ni * 16 + l16;
        acoef[ni] = asl[cl];
        dcoef[ni] = adl[cl];
    }

    // reduction buffer overlaid on Asl (safe: last barrier above drained all reads)
    float2* red = reinterpret_cast<float2*>(Asl);   // red[row*2 + half]
    const int half = wn >> 6;

#pragma unroll
    for (int mi = 0; mi < 4; mi++) {
#pragma unroll
        for (int r = 0; r < 4; r++) {
            int grow = rowBase + wm + mi * 16 + q * 4 + r;
            bool ok = grow < M;
            float vs = 0.f, vd = 0.f;
#pragma unroll
            for (int ni = 0; ni < 4; ni++) {
                float hv = acc[mi][ni][r];
                vs += hv * acoef[ni];
                vd += hv * dcoef[ni];
                if (ok) {
                    int gcol = colBase + wn + ni * 16 + l16;
                    C[(size_t)grow * N + gcol] = f2bf(hv);
                }
            }
#pragma unroll
            for (int d = 1; d < 16; d <<= 1) {
                vs += __shfl_xor(vs, d);
                vd += __shfl_xor(vd, d);
            }
            if (l16 == 0) {
                int lrow = wm + mi * 16 + q * 4 + r;
                red[lrow * 2 + half] = make_float2(vs, vd);
            }
        }
    }
    __syncthreads();
    if (tid < 128) {
        int grow = rowBase + tid;
        if (grow < M) {
            float2 a = red[tid * 2 + 0];
            float2 b = red[tid * 2 + 1];
            alS[(size_t)grow * HEADS + hIdx] = a.x + b.x;
            alD[(size_t)grow * HEADS + hIdx] = a.y + b.y;
        }
    }
}

// ---------------- fused segment softmax + aggregate (+optional head), wave/node -------
// ALL hot-path state is named scalars; head selection is by-value cndmask (sel4v).
// MODE 0: out = bf16 + relu.  MODE 1 (H==1): fused risk head, out = float per node.
template <int H, int C, int MODE>
__global__ __launch_bounds__(256) void gat_aggregate(const unsigned short* __restrict__ hb,
                                                     const float* __restrict__ alS,
                                                     const float* __restrict__ alD,
                                                     const int* __restrict__ off,
                                                     const int* __restrict__ csr_src,
                                                     const float* __restrict__ bias,
                                                     void* __restrict__ outbuf,
                                                     const float* __restrict__ Ws1,
                                                     const float* __restrict__ bs1,
                                                     const float* __restrict__ Ws2,
                                                     const float* __restrict__ bs2,
                                                     int N) {
    constexpr int HC = H * C;
    constexpr int PER = HC / 64;
    int n = (blockIdx.x * blockDim.x + threadIdx.x) >> 6;
    int lane = threadIdx.x & 63;
    if (n >= N) return;
    int beg = off[n], end = off[n + 1];

    float ad0 = 0.f, ad1 = 0.f, ad2 = 0.f, ad3 = 0.f;
    if (H == 4) {
        float4 t = *reinterpret_cast<const float4*>(&alD[n * 4]);
        ad0 = t.x; ad1 = t.y; ad2 = t.z; ad3 = t.w;
    } else {
        ad0 = alD[n];
    }

    const int myh = (lane * PER) / C;
    const unsigned short* hbl = hb + (size_t)lane * PER;

    float m0 = -1e30f, m1 = -1e30f, m2 = -1e30f, m3 = -1e30f;
    float dn0 = 0.f, dn1 = 0.f, dn2 = 0.f, dn3 = 0.f;
    float acc0 = 0.f, acc1 = 0.f, acc2 = 0.f, acc3 = 0.f,
          acc4 = 0.f, acc5 = 0.f, acc6 = 0.f, acc7 = 0.f;

    for (int base = beg; base < end; base += 64) {
        int cnt = end - base; if (cnt > 64) cnt = 64;
        bool act = lane < cnt;
        int s_l = csr_src[act ? (base + lane) : base];

        float v0 = -1e30f, v1 = -1e30f, v2 = -1e30f, v3 = -1e30f;
        if (H == 4) {
            float4 a4 = *reinterpret_cast<const float4*>(&alS[s_l * 4]);
            v0 = act ? lrelu(a4.x + ad0) : -1e30f;
            v1 = act ? lrelu(a4.y + ad1) : -1e30f;
            v2 = act ? lrelu(a4.z + ad2) : -1e30f;
            v3 = act ? lrelu(a4.w + ad3) : -1e30f;
        } else {
            v0 = act ? lrelu(alS[s_l] + ad0) : -1e30f;
        }

        float wl0 = 0.f, wl1 = 0.f, wl2 = 0.f, wl3 = 0.f;
        float so0 = 0.f, so1 = 0.f, so2 = 0.f, so3 = 0.f;
        chunk_stats(v0, m0, dn0, wl0, so0);
        if (H == 4) {
            chunk_stats(v1, m1, dn1, wl1, so1);
            chunk_stats(v2, m2, dn2, wl2, so2);
            chunk_stats(v3, m3, dn3, wl3, so3);
        }
        float sAcc = (H == 4) ? sel4v(so0, so1, so2, so3, myh) : so0;
        acc0 *= sAcc; acc1 *= sAcc;
        if (PER == 8) {
            acc2 *= sAcc; acc3 *= sAcc; acc4 *= sAcc; acc5 *= sAcc;
            acc6 *= sAcc; acc7 *= sAcc;
        }

        if (PER == 8) {
            uint4 bA0 = {}, bA1 = {}, bA2 = {}, bA3 = {},
                  bB0 = {}, bB1 = {}, bB2 = {}, bB3 = {};
            float wA0 = 0, wA1 = 0, wA2 = 0, wA3 = 0,
                  wB0 = 0, wB1 = 0, wB2 = 0, wB3 = 0;
#define FETCH(jj, B, W)                                                          \
            { int j_ = (jj);                                                     \
              if (j_ < cnt) {                                                    \
                int s_ = __shfl(s_l, j_);                                        \
                float u0 = __shfl(wl0, j_), u1 = __shfl(wl1, j_),                \
                      u2 = __shfl(wl2, j_), u3 = __shfl(wl3, j_);                \
                W = sel4v(u0, u1, u2, u3, myh);                                  \
                B = *reinterpret_cast<const uint4*>(hbl + (size_t)s_ * HC);      \
              } }
#define CONS(jj, B, W)                                                           \
            { if ((jj) < cnt) {                                                  \
                acc0 += bf_lo(B.x) * W; acc1 += bf_hi(B.x) * W;                  \
                acc2 += bf_lo(B.y) * W; acc3 += bf_hi(B.y) * W;                  \
                acc4 += bf_lo(B.z) * W; acc5 += bf_hi(B.z) * W;                  \
                acc6 += bf_lo(B.w) * W; acc7 += bf_hi(B.w) * W;                  \
              } }
            FETCH(0, bA0, wA0); FETCH(1, bA1, wA1);
            FETCH(2, bA2, wA2); FETCH(3, bA3, wA3);
            for (int i = 0; i < cnt; i += 8) {
                FETCH(i + 4, bB0, wB0); FETCH(i + 5, bB1, wB1);
                FETCH(i + 6, bB2, wB2); FETCH(i + 7, bB3, wB3);
                CONS(i + 0, bA0, wA0); CONS(i + 1, bA1, wA1);
                CONS(i + 2, bA2, wA2); CONS(i + 3, bA3, wA3);
                FETCH(i + 8, bA0, wA0); FETCH(i + 9, bA1, wA1);
                FETCH(i + 10, bA2, wA2); FETCH(i + 11, bA3, wA3);
                CONS(i + 4, bB0, wB0); CONS(i + 5, bB1, wB1);
                CONS(i + 6, bB2, wB2); CONS(i + 7, bB3, wB3);
            }
#undef FETCH
#undef CONS
        } else {
            unsigned bA0 = 0, bA1 = 0, bA2 = 0, bA3 = 0,
                     bB0 = 0, bB1 = 0, bB2 = 0, bB3 = 0;
            float wA0 = 0, wA1 = 0, wA2 = 0, wA3 = 0,
                  wB0 = 0, wB1 = 0, wB2 = 0, wB3 = 0;
#define FETCH(jj, B, W)                                                          \
            { int j_ = (jj);                                                     \
              if (j_ < cnt) {                                                    \
                int s_ = __shfl(s_l, j_);                                        \
                W = __shfl(wl0, j_);                                             \
                B = *reinterpret_cast<const unsigned*>(hbl + (size_t)s_ * HC);   \
              } }
#define CONS(jj, B, W)                                                           \
            { if ((jj) < cnt) { acc0 += bf_lo(B) * W; acc1 += bf_hi(B) * W; } }
            FETCH(0, bA0, wA0); FETCH(1, bA1, wA1);
            FETCH(2, bA2, wA2); FETCH(3, bA3, wA3);
            for (int i = 0; i < cnt; i += 8) {
                FETCH(i + 4, bB0, wB0); FETCH(i + 5, bB1, wB1);
                FETCH(i + 6, bB2, wB2); FETCH(i + 7, bB3, wB3);
                CONS(i + 0, bA0, wA0); CONS(i + 1, bA1, wA1);
                CONS(i + 2, bA2, wA2); CONS(i + 3, bA3, wA3);
                FETCH(i + 8, bA0, wA0); FETCH(i + 9, bA1, wA1);
                FETCH(i + 10, bA2, wA2); FETCH(i + 11, bA3, wA3);
                CONS(i + 4, bB0, wB0); CONS(i + 5, bB1, wB1);
                CONS(i + 6, bB2, wB2); CONS(i + 7, bB3, wB3);
            }
#undef FETCH
#undef CONS
        }
    }

    float invd = 1.f / ((H == 4) ? sel4v(dn0, dn1, dn2, dn3, myh) : dn0);

    if (MODE == 0) {
        unsigned short* op = (unsigned short*)outbuf + (size_t)n * HC + lane * PER;
        const float* bp = bias + lane * PER;
        if (PER == 8) {
            op[0] = f2bf(fmaxf(acc0 * invd + bp[0], 0.f));
            op[1] = f2bf(fmaxf(acc1 * invd + bp[1], 0.f));
            op[2] = f2bf(fmaxf(acc2 * invd + bp[2], 0.f));
            op[3] = f2bf(fmaxf(acc3 * invd + bp[3], 0.f));
            op[4] = f2bf(fmaxf(acc4 * invd + bp[4], 0.f));
            op[5] = f2bf(fmaxf(acc5 * invd + bp[5], 0.f));
            op[6] = f2bf(fmaxf(acc6 * invd + bp[6], 0.f));
            op[7] = f2bf(fmaxf(acc7 * invd + bp[7], 0.f));
        } else {
            op[0] = f2bf(fmaxf(acc0 * invd + bp[0], 0.f));
            op[1] = f2bf(fmaxf(acc1 * invd + bp[1], 0.f));
        }
    } else {
        // H==1, PER==2: channels (2*lane, 2*lane+1) -> fused risk head
        float h0 = acc0 * invd + bias[2 * lane];
        float h1 = acc1 * invd + bias[2 * lane + 1];
        float s = 0.f;
#pragma unroll
        for (int k = 0; k < 64; k++) {
            float a = __shfl(h0, k);
            float b = __shfl(h1, k);
            s += a * Ws1[(2 * k) * 64 + lane];
            s += b * Ws1[(2 * k + 1) * 64 + lane];
        }
        s = fmaxf(s + bs1[lane], 0.f);
        float z = s * Ws2[lane];
#pragma unroll
        for (int d = 1; d < 64; d <<= 1) z += __shfl_xor(z, d);
        if (lane == 0) ((float*)outbuf)[n] = 1.f / (1.f + __expf(-(z + bs2[0])));
    }
}

// ---------------- launch ----------------
extern "C" void kernel_launch(void* const* d_in, const int* in_sizes, int n_in,
                              void* d_out, int out_size, void* d_ws, size_t ws_size,
                              hipStream_t stream) {
    const float* x   = (const float*)d_in[0];
    const int*   ei  = (const int*)d_in[1];
    const float* W1  = (const float*)d_in[2];
    const float* as1 = (const float*)d_in[3];
    const float* ad1 = (const float*)d_in[4];
    const float* b1  = (const float*)d_in[5];
    const float* W2  = (const float*)d_in[6];
    const float* as2 = (const float*)d_in[7];
    const float* ad2 = (const float*)d_in[8];
    const float* b2  = (const float*)d_in[9];
    const float* W3  = (const float*)d_in[10];
    const float* as3 = (const float*)d_in[11];
    const float* ad3 = (const float*)d_in[12];
    const float* b3  = (const float*)d_in[13];
    const float* Ws1 = (const float*)d_in[14];
    const float* bs1 = (const float*)d_in[15];
    const float* Ws2 = (const float*)d_in[16];
    const float* bs2 = (const float*)d_in[17];

    const int N = out_size;            // 20000
    const int E = in_sizes[1] / 2;     // 160000
    const int D = in_sizes[0] / N;     // 768
    const int HC = 512, H = 4, C = 128;
    const int Etot = E + N;

    char* p = (char*)d_ws;
    auto alloc = [&](size_t bytes) -> void* {
        void* q = (void*)p;
        p += (bytes + 255) & ~(size_t)255;
        return q;
    };
    // --- zeroed region (deg, cursor only — alpha arrays now plain-stored) ---
    char*  zbeg   = p;
    int*   deg    = (int*)alloc((size_t)N * 4);
    int*   cursor = (int*)alloc((size_t)N * 4);
    char*  zend   = p;
    // --- rest ---
    float* alS1   = (float*)alloc((size_t)N * H * 4);
    float* alD1   = (float*)alloc((size_t)N * H * 4);
    float* alS2   = (float*)alloc((size_t)N * H * 4);
    float* alD2   = (float*)alloc((size_t)N * H * 4);
    float* alS3   = (float*)alloc((size_t)N * 4);
    float* alD3   = (float*)alloc((size_t)N * 4);
    int*   off    = (int*)alloc((size_t)(N + 1) * 4);
    int*   csr    = (int*)alloc((size_t)Etot * 4);
    unsigned short* hbuf = (unsigned short*)alloc((size_t)N * HC * 2);
    unsigned short* xbf  = (unsigned short*)alloc((size_t)N * D * 2);
    unsigned short* obf  = (unsigned short*)alloc((size_t)N * HC * 2);
    unsigned short* W1t  = (unsigned short*)alloc((size_t)D * HC * 2);
    unsigned short* W2t  = (unsigned short*)alloc((size_t)HC * HC * 2);
    unsigned short* W3t  = (unsigned short*)alloc((size_t)HC * C * 2);

    hipMemsetAsync(zbeg, 0, (size_t)(zend - zbeg), stream);

    const int tb = 256;
    count_deg_kernel<<<(Etot + tb - 1) / tb, tb, 0, stream>>>(ei, E, N, deg);
    scan_kernel<<<1, 1024, 0, stream>>>(deg, off, N);
    scatter_kernel<<<(Etot + tb - 1) / tb, tb, 0, stream>>>(ei, E, N, off, cursor, csr);

    {
        size_t n4 = (size_t)N * D / 4;
        cast_bf16_kernel<<<(int)((n4 + 255) / 256), 256, 0, stream>>>(x, xbf, n4);
        transpose_cast_kernel<<<(D * HC + 255) / 256, 256, 0, stream>>>(W1, W1t, D, HC);
        transpose_cast_kernel<<<(HC * HC + 255) / 256, 256, 0, stream>>>(W2, W2t, HC, HC);
        transpose_cast_kernel<<<(HC * C + 255) / 256, 256, 0, stream>>>(W3, W3t, HC, C);
    }

    int node_blocks = (N + 3) / 4;     // one wave per node
    int rowTiles = (N + 127) / 128;

    // ---- layer 1 ----
    gemm_bf16_alpha<4><<<dim3(HC / 128, rowTiles), 256, 0, stream>>>(
        xbf, W1t, hbuf, N, HC, D, as1, ad1, alS1, alD1);
    gat_aggregate<4, 128, 0><<<node_blocks, 256, 0, stream>>>(
        hbuf, alS1, alD1, off, csr, b1, obf, nullptr, nullptr, nullptr, nullptr, N);

    // ---- layer 2 ----
    gemm_bf16_alpha<4><<<dim3(HC / 128, rowTiles), 256, 0, stream>>>(
        obf, W2t, hbuf, N, HC, HC, as2, ad2, alS2, alD2);
    gat_aggregate<4, 128, 0><<<node_blocks, 256, 0, stream>>>(
        hbuf, alS2, alD2, off, csr, b2, obf, nullptr, nullptr, nullptr, nullptr, N);

    // ---- layer 3 (H=1) + fused head ----
    gemm_bf16_alpha<1><<<dim3(C / 128, rowTiles), 256, 0, stream>>>(
        obf, W3t, hbuf, N, C, HC, as3, ad3, alS3, alD3);
    gat_aggregate<1, 128, 1><<<node_blocks, 256, 0, stream>>>(
        hbuf, alS3, alD3, off, csr, b3, (float*)d_out, Ws1, bs1, Ws2, bs2, N);
}

// Round 9
// 368.241 us; speedup vs baseline: 1.4056x; 1.0335x over previous
//
#include <hip/hip_runtime.h>
#include <hip/hip_bf16.h>
#include <math.h>

#define NEG_SLOPE 0.2f

typedef __attribute__((ext_vector_type(8))) __bf16 bf16x8;
typedef __attribute__((ext_vector_type(4))) float f32x4;

// ---------------- helpers ----------------
__device__ inline float lrelu(float v) { return v > 0.f ? v : NEG_SLOPE * v; }

__device__ inline unsigned short f2bf(float f) {
    __hip_bfloat16 h = __float2bfloat16(f);
    return *reinterpret_cast<unsigned short*>(&h);
}
__device__ inline float bf_lo(unsigned u) { return __uint_as_float(u << 16); }
__device__ inline float bf_hi(unsigned u) { return __uint_as_float(u & 0xffff0000u); }

// by-VALUE head select: pure cndmask chain, no address-taken array
__device__ inline float sel4v(float a0, float a1, float a2, float a3, int h) {
    float rlo = (h & 1) ? a1 : a0;
    float rhi = (h & 1) ? a3 : a2;
    return (h & 2) ? rhi : rlo;
}

// online-softmax chunk statistics (scalar refs -> SSA after inline)
__device__ inline void chunk_stats(float v, float& m, float& den, float& wl, float& so) {
    float mc = v;
#pragma unroll
    for (int d = 1; d < 64; d <<= 1) mc = fmaxf(mc, __shfl_xor(mc, d));
    float pl = __expf(v - mc);          // inactive lanes (v=-1e30) -> 0
    float dc = pl;
#pragma unroll
    for (int d = 1; d < 64; d <<= 1) dc += __shfl_xor(dc, d);
    float nm = fmaxf(m, mc);
    so = __expf(m - nm);
    float sc = __expf(mc - nm);
    den = den * so + dc * sc;
    m = nm;
    wl = pl * sc;                       // this lane's edge weight vs new running max
}

// ---------------- CSR build ----------------
__global__ void count_deg_kernel(const int* __restrict__ ei, int E, int N,
                                 int* __restrict__ deg) {
    int e = blockIdx.x * blockDim.x + threadIdx.x;
    if (e >= E + N) return;
    int dst = (e < E) ? ei[E + e] : (e - E);
    atomicAdd(&deg[dst], 1);
}

__global__ void scan_kernel(const int* __restrict__ deg, int* __restrict__ off, int N) {
    __shared__ int sums[1024];
    int tid = threadIdx.x;
    int chunk = (N + 1023) / 1024;
    int start = tid * chunk;
    int end = start + chunk; if (end > N) end = N;
    int s = 0;
    for (int i = start; i < end && i < N; i++) s += deg[i];
    sums[tid] = s;
    __syncthreads();
    for (int d = 1; d < 1024; d <<= 1) {
        int v = 0;
        if (tid >= d) v = sums[tid - d];
        __syncthreads();
        if (tid >= d) sums[tid] += v;
        __syncthreads();
    }
    int prefix = (tid == 0) ? 0 : sums[tid - 1];
    int run = prefix;
    for (int i = start; i < end && i < N; i++) { off[i] = run; run += deg[i]; }
    if (tid == 1023) off[N] = sums[1023];
}

__global__ void scatter_kernel(const int* __restrict__ ei, int E, int N,
                               const int* __restrict__ off, int* __restrict__ cursor,
                               int* __restrict__ csr_src) {
    int e = blockIdx.x * blockDim.x + threadIdx.x;
    if (e >= E + N) return;
    int src, dst;
    if (e < E) { src = ei[e]; dst = ei[E + e]; }
    else       { src = dst = e - E; }
    int pos = off[dst] + atomicAdd(&cursor[dst], 1);
    csr_src[pos] = src;
}

// ---------------- fp32 -> bf16 cast (vectorized), n % 4 == 0 ----------------
__global__ void cast_bf16_kernel(const float* __restrict__ in, unsigned short* __restrict__ out,
                                 size_t n4) {
    size_t i = (size_t)blockIdx.x * blockDim.x + threadIdx.x;
    if (i >= n4) return;
    float4 v = reinterpret_cast<const float4*>(in)[i];
    ushort4 o;
    o.x = f2bf(v.x); o.y = f2bf(v.y); o.z = f2bf(v.z); o.w = f2bf(v.w);
    reinterpret_cast<ushort4*>(out)[i] = o;
}

// ---------------- transpose-cast: out[n*K + k] = bf16(in[k*N + n]) ----------------
__global__ void transpose_cast_kernel(const float* __restrict__ in, unsigned short* __restrict__ out,
                                      int K, int N) {
    int idx = blockIdx.x * blockDim.x + threadIdx.x;
    if (idx >= K * N) return;
    int n = idx / K, k = idx % K;
    out[(size_t)n * K + k] = f2bf(in[(size_t)k * N + n]);
}

// ---------------- bf16 MFMA GEMM (BM=64, BN=128, BK=64, XOR swizzle) + alpha --------
// C[M,N] = A[M,K] @ Bt[N,K]^T, bf16 out. Col-tile (128) == one head slice.
// Grid: (N/128) x ceil(M/64) -> 2x the blocks of the 128x128 tile (latency hiding).
// LDS: row-major [rows][64] shorts, 16B chunk c stored at slot c ^ (row&7).
// Alpha epilogue: per-wave 64-col partials combined through LDS (no atomics).
template <int HEADS>
__global__ __launch_bounds__(256) void gemm_bf16_alpha(const unsigned short* __restrict__ A,
                                                       const unsigned short* __restrict__ Bt,
                                                       unsigned short* __restrict__ C,
                                                       int M, int N, int K,
                                                       const float* __restrict__ a_src,
                                                       const float* __restrict__ a_dst,
                                                       float* __restrict__ alS,
                                                       float* __restrict__ alD) {
    __shared__ unsigned short Asl[64 * 64];    // 8 KB
    __shared__ unsigned short Bsl[128 * 64];   // 16 KB
    const int tid  = threadIdx.x;
    const int lane = tid & 63;
    const int wave = tid >> 6;
    const int rowBase = blockIdx.y * 64;
    const int colBase = blockIdx.x * 128;
    const int wm = (wave & 1) * 32;    // 2 row-halves
    const int wn = (wave >> 1) * 64;   // 2 col-halves
    const int q   = lane >> 4;
    const int l16 = lane & 15;

    // staging geometry: slot s = it*256+tid covers row r=it*32+(tid>>3), chunk slot tid&7;
    // global chunk cg = (tid&7) ^ (r&7); r&7 == (tid>>3)&7 for all it.
    const int r0 = tid >> 3;                  // 0..31
    const int cg = (tid & 7) ^ (r0 & 7);

    f32x4 acc[2][4] = {};

    for (int k0 = 0; k0 < K; k0 += 64) {
#pragma unroll
        for (int it = 0; it < 2; it++) {       // A: 64 rows
            int s = it * 256 + tid;
            int r = it * 32 + r0;
            int ga = rowBase + r; if (ga >= M) ga = M - 1;
            const unsigned short* gpa = A + (size_t)ga * K + k0 + cg * 8;
            __builtin_amdgcn_global_load_lds(
                (const __attribute__((address_space(1))) void*)gpa,
                (__attribute__((address_space(3))) void*)&Asl[(size_t)s * 8],
                16, 0, 0);
        }
#pragma unroll
        for (int it = 0; it < 4; it++) {       // B: 128 rows
            int s = it * 256 + tid;
            int r = it * 32 + r0;
            const unsigned short* gpb = Bt + (size_t)(colBase + r) * K + k0 + cg * 8;
            __builtin_amdgcn_global_load_lds(
                (const __attribute__((address_space(1))) void*)gpb,
                (__attribute__((address_space(3))) void*)&Bsl[(size_t)s * 8],
                16, 0, 0);
        }
        __syncthreads();

#pragma unroll
        for (int kh = 0; kh < 2; kh++) {
            bf16x8 af[2], bfv[4];
#pragma unroll
            for (int mi = 0; mi < 2; mi++) {
                int row = wm + mi * 16 + l16;
                int ch = (kh * 4 + q) ^ (row & 7);
                af[mi] = *reinterpret_cast<const bf16x8*>(&Asl[row * 64 + ch * 8]);
            }
#pragma unroll
            for (int ni = 0; ni < 4; ni++) {
                int row = wn + ni * 16 + l16;
                int ch = (kh * 4 + q) ^ (row & 7);
                bfv[ni] = *reinterpret_cast<const bf16x8*>(&Bsl[row * 64 + ch * 8]);
            }
#pragma unroll
            for (int mi = 0; mi < 2; mi++)
#pragma unroll
                for (int ni = 0; ni < 4; ni++)
                    acc[mi][ni] = __builtin_amdgcn_mfma_f32_16x16x32_bf16(af[mi], bfv[ni], acc[mi][ni], 0, 0, 0);
        }
        __syncthreads();
    }

    const int hIdx = colBase >> 7;           // C==128 per head
    const float* asl = a_src + hIdx * 128;
    const float* adl = a_dst + hIdx * 128;
    float acoef[4], dcoef[4];
#pragma unroll
    for (int ni = 0; ni < 4; ni++) {
        int cl = wn + ni * 16 + l16;
        acoef[ni] = asl[cl];
        dcoef[ni] = adl[cl];
    }

    // reduction buffer overlaid on Asl (safe: last barrier drained all reads)
    float2* red = reinterpret_cast<float2*>(Asl);   // red[row*2 + half], 64 rows
    const int half = wn >> 6;

#pragma unroll
    for (int mi = 0; mi < 2; mi++) {
#pragma unroll
        for (int r = 0; r < 4; r++) {
            int lrow = wm + mi * 16 + q * 4 + r;
            int grow = rowBase + lrow;
            bool ok = grow < M;
            float vs = 0.f, vd = 0.f;
#pragma unroll
            for (int ni = 0; ni < 4; ni++) {
                float hv = acc[mi][ni][r];
                vs += hv * acoef[ni];
                vd += hv * dcoef[ni];
                if (ok) {
                    int gcol = colBase + wn + ni * 16 + l16;
                    C[(size_t)grow * N + gcol] = f2bf(hv);
                }
            }
#pragma unroll
            for (int d = 1; d < 16; d <<= 1) {
                vs += __shfl_xor(vs, d);
                vd += __shfl_xor(vd, d);
            }
            if (l16 == 0) red[lrow * 2 + half] = make_float2(vs, vd);
        }
    }
    __syncthreads();
    if (tid < 64) {
        int grow = rowBase + tid;
        if (grow < M) {
            float2 a = red[tid * 2 + 0];
            float2 b = red[tid * 2 + 1];
            alS[(size_t)grow * HEADS + hIdx] = a.x + b.x;
            alD[(size_t)grow * HEADS + hIdx] = a.y + b.y;
        }
    }
}

// ---------------- fused segment softmax + aggregate (+optional head), wave/node -------
// ALL hot-path state is named scalars; head selection is by-value cndmask (sel4v).
// MODE 0: out = bf16 + relu.  MODE 1 (H==1): fused risk head, out = float per node.
template <int H, int C, int MODE>
__global__ __launch_bounds__(256) void gat_aggregate(const unsigned short* __restrict__ hb,
                                                     const float* __restrict__ alS,
                                                     const float* __restrict__ alD,
                                                     const int* __restrict__ off,
                                                     const int* __restrict__ csr_src,
                                                     const float* __restrict__ bias,
                                                     void* __restrict__ outbuf,
                                                     const float* __restrict__ Ws1,
                                                     const float* __restrict__ bs1,
                                                     const float* __restrict__ Ws2,
                                                     const float* __restrict__ bs2,
                                                     int N) {
    constexpr int HC = H * C;
    constexpr int PER = HC / 64;
    int n = (blockIdx.x * blockDim.x + threadIdx.x) >> 6;
    int lane = threadIdx.x & 63;
    if (n >= N) return;
    int beg = off[n], end = off[n + 1];

    float ad0 = 0.f, ad1 = 0.f, ad2 = 0.f, ad3 = 0.f;
    if (H == 4) {
        float4 t = *reinterpret_cast<const float4*>(&alD[n * 4]);
        ad0 = t.x; ad1 = t.y; ad2 = t.z; ad3 = t.w;
    } else {
        ad0 = alD[n];
    }

    const int myh = (lane * PER) / C;
    const unsigned short* hbl = hb + (size_t)lane * PER;

    float m0 = -1e30f, m1 = -1e30f, m2 = -1e30f, m3 = -1e30f;
    float dn0 = 0.f, dn1 = 0.f, dn2 = 0.f, dn3 = 0.f;
    float acc0 = 0.f, acc1 = 0.f, acc2 = 0.f, acc3 = 0.f,
          acc4 = 0.f, acc5 = 0.f, acc6 = 0.f, acc7 = 0.f;

    for (int base = beg; base < end; base += 64) {
        int cnt = end - base; if (cnt > 64) cnt = 64;
        bool act = lane < cnt;
        int s_l = csr_src[act ? (base + lane) : base];

        float v0 = -1e30f, v1 = -1e30f, v2 = -1e30f, v3 = -1e30f;
        if (H == 4) {
            float4 a4 = *reinterpret_cast<const float4*>(&alS[s_l * 4]);
            v0 = act ? lrelu(a4.x + ad0) : -1e30f;
            v1 = act ? lrelu(a4.y + ad1) : -1e30f;
            v2 = act ? lrelu(a4.z + ad2) : -1e30f;
            v3 = act ? lrelu(a4.w + ad3) : -1e30f;
        } else {
            v0 = act ? lrelu(alS[s_l] + ad0) : -1e30f;
        }

        float wl0 = 0.f, wl1 = 0.f, wl2 = 0.f, wl3 = 0.f;
        float so0 = 0.f, so1 = 0.f, so2 = 0.f, so3 = 0.f;
        chunk_stats(v0, m0, dn0, wl0, so0);
        if (H == 4) {
            chunk_stats(v1, m1, dn1, wl1, so1);
            chunk_stats(v2, m2, dn2, wl2, so2);
            chunk_stats(v3, m3, dn3, wl3, so3);
        }
        float sAcc = (H == 4) ? sel4v(so0, so1, so2, so3, myh) : so0;
        acc0 *= sAcc; acc1 *= sAcc;
        if (PER == 8) {
            acc2 *= sAcc; acc3 *= sAcc; acc4 *= sAcc; acc5 *= sAcc;
            acc6 *= sAcc; acc7 *= sAcc;
        }

        if (PER == 8) {
            uint4 bA0 = {}, bA1 = {}, bA2 = {}, bA3 = {},
                  bB0 = {}, bB1 = {}, bB2 = {}, bB3 = {};
            float wA0 = 0, wA1 = 0, wA2 = 0, wA3 = 0,
                  wB0 = 0, wB1 = 0, wB2 = 0, wB3 = 0;
#define FETCH(jj, B, W)                                                          \
            { int j_ = (jj);                                                     \
              if (j_ < cnt) {                                                    \
                int s_ = __shfl(s_l, j_);                                        \
                float u0 = __shfl(wl0, j_), u1 = __shfl(wl1, j_),                \
                      u2 = __shfl(wl2, j_), u3 = __shfl(wl3, j_);                \
                W = sel4v(u0, u1, u2, u3, myh);                                  \
                B = *reinterpret_cast<const uint4*>(hbl + (size_t)s_ * HC);      \
              } }
#define CONS(jj, B, W)                                                           \
            { if ((jj) < cnt) {                                                  \
                acc0 += bf_lo(B.x) * W; acc1 += bf_hi(B.x) * W;                  \
                acc2 += bf_lo(B.y) * W; acc3 += bf_hi(B.y) * W;                  \
                acc4 += bf_lo(B.z) * W; acc5 += bf_hi(B.z) * W;                  \
                acc6 += bf_lo(B.w) * W; acc7 += bf_hi(B.w) * W;                  \
              } }
            FETCH(0, bA0, wA0); FETCH(1, bA1, wA1);
            FETCH(2, bA2, wA2); FETCH(3, bA3, wA3);
            for (int i = 0; i < cnt; i += 8) {
                FETCH(i + 4, bB0, wB0); FETCH(i + 5, bB1, wB1);
                FETCH(i + 6, bB2, wB2); FETCH(i + 7, bB3, wB3);
                CONS(i + 0, bA0, wA0); CONS(i + 1, bA1, wA1);
                CONS(i + 2, bA2, wA2); CONS(i + 3, bA3, wA3);
                FETCH(i + 8, bA0, wA0); FETCH(i + 9, bA1, wA1);
                FETCH(i + 10, bA2, wA2); FETCH(i + 11, bA3, wA3);
                CONS(i + 4, bB0, wB0); CONS(i + 5, bB1, wB1);
                CONS(i + 6, bB2, wB2); CONS(i + 7, bB3, wB3);
            }
#undef FETCH
#undef CONS
        } else {
            unsigned bA0 = 0, bA1 = 0, bA2 = 0, bA3 = 0,
                     bB0 = 0, bB1 = 0, bB2 = 0, bB3 = 0;
            float wA0 = 0, wA1 = 0, wA2 = 0, wA3 = 0,
                  wB0 = 0, wB1 = 0, wB2 = 0, wB3 = 0;
#define FETCH(jj, B, W)                                                          \
            { int j_ = (jj);                                                     \
              if (j_ < cnt) {                                                    \
                int s_ = __shfl(s_l, j_);                                        \
                W = __shfl(wl0, j_);                                             \
                B = *reinterpret_cast<const unsigned*>(hbl + (size_t)s_ * HC);   \
              } }
#define CONS(jj, B, W)                                                           \
            { if ((jj) < cnt) { acc0 += bf_lo(B) * W; acc1 += bf_hi(B) * W; } }
            FETCH(0, bA0, wA0); FETCH(1, bA1, wA1);
            FETCH(2, bA2, wA2); FETCH(3, bA3, wA3);
            for (int i = 0; i < cnt; i += 8) {
                FETCH(i + 4, bB0, wB0); FETCH(i + 5, bB1, wB1);
                FETCH(i + 6, bB2, wB2); FETCH(i + 7, bB3, wB3);
                CONS(i + 0, bA0, wA0); CONS(i + 1, bA1, wA1);
                CONS(i + 2, bA2, wA2); CONS(i + 3, bA3, wA3);
                FETCH(i + 8, bA0, wA0); FETCH(i + 9, bA1, wA1);
                FETCH(i + 10, bA2, wA2); FETCH(i + 11, bA3, wA3);
                CONS(i + 4, bB0, wB0); CONS(i + 5, bB1, wB1);
                CONS(i + 6, bB2, wB2); CONS(i + 7, bB3, wB3);
            }
#undef FETCH
#undef CONS
        }
    }

    float invd = 1.f / ((H == 4) ? sel4v(dn0, dn1, dn2, dn3, myh) : dn0);

    if (MODE == 0) {
        unsigned short* op = (unsigned short*)outbuf + (size_t)n * HC + lane * PER;
        const float* bp = bias + lane * PER;
        if (PER == 8) {
            op[0] = f2bf(fmaxf(acc0 * invd + bp[0], 0.f));
            op[1] = f2bf(fmaxf(acc1 * invd + bp[1], 0.f));
            op[2] = f2bf(fmaxf(acc2 * invd + bp[2], 0.f));
            op[3] = f2bf(fmaxf(acc3 * invd + bp[3], 0.f));
            op[4] = f2bf(fmaxf(acc4 * invd + bp[4], 0.f));
            op[5] = f2bf(fmaxf(acc5 * invd + bp[5], 0.f));
            op[6] = f2bf(fmaxf(acc6 * invd + bp[6], 0.f));
            op[7] = f2bf(fmaxf(acc7 * invd + bp[7], 0.f));
        } else {
            op[0] = f2bf(fmaxf(acc0 * invd + bp[0], 0.f));
            op[1] = f2bf(fmaxf(acc1 * invd + bp[1], 0.f));
        }
    } else {
        // H==1, PER==2: channels (2*lane, 2*lane+1) -> fused risk head
        float h0 = acc0 * invd + bias[2 * lane];
        float h1 = acc1 * invd + bias[2 * lane + 1];
        float s = 0.f;
#pragma unroll
        for (int k = 0; k < 64; k++) {
            float a = __shfl(h0, k);
            float b = __shfl(h1, k);
            s += a * Ws1[(2 * k) * 64 + lane];
            s += b * Ws1[(2 * k + 1) * 64 + lane];
        }
        s = fmaxf(s + bs1[lane], 0.f);
        float z = s * Ws2[lane];
#pragma unroll
        for (int d = 1; d < 64; d <<= 1) z += __shfl_xor(z, d);
        if (lane == 0) ((float*)outbuf)[n] = 1.f / (1.f + __expf(-(z + bs2[0])));
    }
}

// ---------------- launch ----------------
extern "C" void kernel_launch(void* const* d_in, const int* in_sizes, int n_in,
                              void* d_out, int out_size, void* d_ws, size_t ws_size,
                              hipStream_t stream) {
    const float* x   = (const float*)d_in[0];
    const int*   ei  = (const int*)d_in[1];
    const float* W1  = (const float*)d_in[2];
    const float* as1 = (const float*)d_in[3];
    const float* ad1 = (const float*)d_in[4];
    const float* b1  = (const float*)d_in[5];
    const float* W2  = (const float*)d_in[6];
    const float* as2 = (const float*)d_in[7];
    const float* ad2 = (const float*)d_in[8];
    const float* b2  = (const float*)d_in[9];
    const float* W3  = (const float*)d_in[10];
    const float* as3 = (const float*)d_in[11];
    const float* ad3 = (const float*)d_in[12];
    const float* b3  = (const float*)d_in[13];
    const float* Ws1 = (const float*)d_in[14];
    const float* bs1 = (const float*)d_in[15];
    const float* Ws2 = (const float*)d_in[16];
    const float* bs2 = (const float*)d_in[17];

    const int N = out_size;            // 20000
    const int E = in_sizes[1] / 2;     // 160000
    const int D = in_sizes[0] / N;     // 768
    const int HC = 512, H = 4, C = 128;
    const int Etot = E + N;

    char* p = (char*)d_ws;
    auto alloc = [&](size_t bytes) -> void* {
        void* q = (void*)p;
        p += (bytes + 255) & ~(size_t)255;
        return q;
    };
    // --- zeroed region (deg, cursor only) ---
    char*  zbeg   = p;
    int*   deg    = (int*)alloc((size_t)N * 4);
    int*   cursor = (int*)alloc((size_t)N * 4);
    char*  zend   = p;
    // --- rest ---
    float* alS1   = (float*)alloc((size_t)N * H * 4);
    float* alD1   = (float*)alloc((size_t)N * H * 4);
    float* alS2   = (float*)alloc((size_t)N * H * 4);
    float* alD2   = (float*)alloc((size_t)N * H * 4);
    float* alS3   = (float*)alloc((size_t)N * 4);
    float* alD3   = (float*)alloc((size_t)N * 4);
    int*   off    = (int*)alloc((size_t)(N + 1) * 4);
    int*   csr    = (int*)alloc((size_t)Etot * 4);
    unsigned short* hbuf = (unsigned short*)alloc((size_t)N * HC * 2);
    unsigned short* xbf  = (unsigned short*)alloc((size_t)N * D * 2);
    unsigned short* obf  = (unsigned short*)alloc((size_t)N * HC * 2);
    unsigned short* W1t  = (unsigned short*)alloc((size_t)D * HC * 2);
    unsigned short* W2t  = (unsigned short*)alloc((size_t)HC * HC * 2);
    unsigned short* W3t  = (unsigned short*)alloc((size_t)HC * C * 2);

    hipMemsetAsync(zbeg, 0, (size_t)(zend - zbeg), stream);

    const int tb = 256;
    count_deg_kernel<<<(Etot + tb - 1) / tb, tb, 0, stream>>>(ei, E, N, deg);
    scan_kernel<<<1, 1024, 0, stream>>>(deg, off, N);
    scatter_kernel<<<(Etot + tb - 1) / tb, tb, 0, stream>>>(ei, E, N, off, cursor, csr);

    {
        size_t n4 = (size_t)N * D / 4;
        cast_bf16_kernel<<<(int)((n4 + 255) / 256), 256, 0, stream>>>(x, xbf, n4);
        transpose_cast_kernel<<<(D * HC + 255) / 256, 256, 0, stream>>>(W1, W1t, D, HC);
        transpose_cast_kernel<<<(HC * HC + 255) / 256, 256, 0, stream>>>(W2, W2t, HC, HC);
        transpose_cast_kernel<<<(HC * C + 255) / 256, 256, 0, stream>>>(W3, W3t, HC, C);
    }

    int node_blocks = (N + 3) / 4;       // one wave per node
    int rowTiles64 = (N + 63) / 64;      // BM=64

    // ---- layer 1 ----
    gemm_bf16_alpha<4><<<dim3(HC / 128, rowTiles64), 256, 0, stream>>>(
        xbf, W1t, hbuf, N, HC, D, as1, ad1, alS1, alD1);
    gat_aggregate<4, 128, 0><<<node_blocks, 256, 0, stream>>>(
        hbuf, alS1, alD1, off, csr, b1, obf, nullptr, nullptr, nullptr, nullptr, N);

    // ---- layer 2 ----
    gemm_bf16_alpha<4><<<dim3(HC / 128, rowTiles64), 256, 0, stream>>>(
        obf, W2t, hbuf, N, HC, HC, as2, ad2, alS2, alD2);
    gat_aggregate<4, 128, 0><<<node_blocks, 256, 0, stream>>>(
        hbuf, alS2, alD2, off, csr, b2, obf, nullptr, nullptr, nullptr, nullptr, N);

    // ---- layer 3 (H=1) + fused head ----
    gemm_bf16_alpha<1><<<dim3(C / 128, rowTiles64), 256, 0, stream>>>(
        obf, W3t, hbuf, N, C, HC, as3, ad3, alS3, alD3);
    gat_aggregate<1, 128, 1><<<node_blocks, 256, 0, stream>>>(
        hbuf, alS3, alD3, off, csr, b3, (float*)d_out, Ws1, bs1, Ws2, bs2, N);
}

// Round 10
// 358.003 us; speedup vs baseline: 1.4458x; 1.0286x over previous
//
#include <hip/hip_runtime.h>
#include <hip/hip_bf16.h>
#include <math.h>

#define NEG_SLOPE 0.2f

typedef __attribute__((ext_vector_type(8))) __bf16 bf16x8;
typedef __attribute__((ext_vector_type(4))) float f32x4;

// ---------------- helpers ----------------
__device__ inline float lrelu(float v) { return v > 0.f ? v : NEG_SLOPE * v; }

__device__ inline unsigned short f2bf(float f) {
    __hip_bfloat16 h = __float2bfloat16(f);
    return *reinterpret_cast<unsigned short*>(&h);
}
__device__ inline float bf_lo(unsigned u) { return __uint_as_float(u << 16); }
__device__ inline float bf_hi(unsigned u) { return __uint_as_float(u & 0xffff0000u); }

// online-softmax chunk statistics (scalar refs -> SSA after inline)
__device__ inline void chunk_stats(float v, float& m, float& den, float& wl, float& so) {
    float mc = v;
#pragma unroll
    for (int d = 1; d < 64; d <<= 1) mc = fmaxf(mc, __shfl_xor(mc, d));
    float pl = __expf(v - mc);          // inactive lanes (v=-1e30) -> 0 exactly
    float dc = pl;
#pragma unroll
    for (int d = 1; d < 64; d <<= 1) dc += __shfl_xor(dc, d);
    float nm = fmaxf(m, mc);
    so = __expf(m - nm);
    float sc = __expf(mc - nm);
    den = den * so + dc * sc;
    m = nm;
    wl = pl * sc;                       // this lane's edge weight vs new running max
}

// ---------------- CSR build ----------------
__global__ void count_deg_kernel(const int* __restrict__ ei, int E, int N,
                                 int* __restrict__ deg) {
    int e = blockIdx.x * blockDim.x + threadIdx.x;
    if (e >= E + N) return;
    int dst = (e < E) ? ei[E + e] : (e - E);
    atomicAdd(&deg[dst], 1);
}

__global__ void scan_kernel(const int* __restrict__ deg, int* __restrict__ off, int N) {
    __shared__ int sums[1024];
    int tid = threadIdx.x;
    int chunk = (N + 1023) / 1024;
    int start = tid * chunk;
    int end = start + chunk; if (end > N) end = N;
    int s = 0;
    for (int i = start; i < end && i < N; i++) s += deg[i];
    sums[tid] = s;
    __syncthreads();
    for (int d = 1; d < 1024; d <<= 1) {
        int v = 0;
        if (tid >= d) v = sums[tid - d];
        __syncthreads();
        if (tid >= d) sums[tid] += v;
        __syncthreads();
    }
    int prefix = (tid == 0) ? 0 : sums[tid - 1];
    int run = prefix;
    for (int i = start; i < end && i < N; i++) { off[i] = run; run += deg[i]; }
    if (tid == 1023) off[N] = sums[1023];
}

__global__ void scatter_kernel(const int* __restrict__ ei, int E, int N,
                               const int* __restrict__ off, int* __restrict__ cursor,
                               int* __restrict__ csr_src) {
    int e = blockIdx.x * blockDim.x + threadIdx.x;
    if (e >= E + N) return;
    int src, dst;
    if (e < E) { src = ei[e]; dst = ei[E + e]; }
    else       { src = dst = e - E; }
    int pos = off[dst] + atomicAdd(&cursor[dst], 1);
    csr_src[pos] = src;
}

// ---------------- fp32 -> bf16 cast (vectorized), n % 4 == 0 ----------------
__global__ void cast_bf16_kernel(const float* __restrict__ in, unsigned short* __restrict__ out,
                                 size_t n4) {
    size_t i = (size_t)blockIdx.x * blockDim.x + threadIdx.x;
    if (i >= n4) return;
    float4 v = reinterpret_cast<const float4*>(in)[i];
    ushort4 o;
    o.x = f2bf(v.x); o.y = f2bf(v.y); o.z = f2bf(v.z); o.w = f2bf(v.w);
    reinterpret_cast<ushort4*>(out)[i] = o;
}

// ---------------- transpose-cast: out[n*K + k] = bf16(in[k*N + n]) ----------------
__global__ void transpose_cast_kernel(const float* __restrict__ in, unsigned short* __restrict__ out,
                                      int K, int N) {
    int idx = blockIdx.x * blockDim.x + threadIdx.x;
    if (idx >= K * N) return;
    int n = idx / K, k = idx % K;
    out[(size_t)n * K + k] = f2bf(in[(size_t)k * N + n]);
}

// ---------------- bf16 MFMA GEMM (BM=64, BN=128, BK=64, XOR swizzle) + alpha --------
// Flat 1-D grid with XCD-aware decode: the 4 col-tiles of one row-tile get block ids
// congruent mod 8 -> same XCD -> A row-tile cached once per XCD L2 and reused 4x.
template <int HEADS>
__global__ __launch_bounds__(256) void gemm_bf16_alpha(const unsigned short* __restrict__ A,
                                                       const unsigned short* __restrict__ Bt,
                                                       unsigned short* __restrict__ C,
                                                       int M, int N, int K, int rowTiles,
                                                       const float* __restrict__ a_src,
                                                       const float* __restrict__ a_dst,
                                                       float* __restrict__ alS,
                                                       float* __restrict__ alD) {
    __shared__ unsigned short Asl[64 * 64];    // 8 KB
    __shared__ unsigned short Bsl[128 * 64];   // 16 KB
    const int tid  = threadIdx.x;
    const int lane = tid & 63;
    const int wave = tid >> 6;

    // XCD-aware block decode
    int r, c;
    {
        int b = blockIdx.x;
        int colTiles = N >> 7;
        if (colTiles == 4) {
            int mainRows = rowTiles & ~7;
            int mainBlocks = mainRows * 4;
            if (b < mainBlocks) {
                int xcd = b & 7;
                c = (b >> 3) & 3;
                r = (b >> 5) * 8 + xcd;
            } else {
                int idx = b - mainBlocks;
                r = mainRows + (idx >> 2);
                c = idx & 3;
            }
        } else { r = b; c = 0; }
    }
    const int rowBase = r * 64;
    const int colBase = c * 128;
    const int wm = (wave & 1) * 32;
    const int wn = (wave >> 1) * 64;
    const int q   = lane >> 4;
    const int l16 = lane & 15;

    const int r0 = tid >> 3;                  // 0..31
    const int cg = (tid & 7) ^ (r0 & 7);

    f32x4 acc[2][4] = {};

    for (int k0 = 0; k0 < K; k0 += 64) {
#pragma unroll
        for (int it = 0; it < 2; it++) {       // A: 64 rows
            int s = it * 256 + tid;
            int rr = it * 32 + r0;
            int ga = rowBase + rr; if (ga >= M) ga = M - 1;
            const unsigned short* gpa = A + (size_t)ga * K + k0 + cg * 8;
            __builtin_amdgcn_global_load_lds(
                (const __attribute__((address_space(1))) void*)gpa,
                (__attribute__((address_space(3))) void*)&Asl[(size_t)s * 8],
                16, 0, 0);
        }
#pragma unroll
        for (int it = 0; it < 4; it++) {       // B: 128 rows
            int s = it * 256 + tid;
            int rr = it * 32 + r0;
            const unsigned short* gpb = Bt + (size_t)(colBase + rr) * K + k0 + cg * 8;
            __builtin_amdgcn_global_load_lds(
                (const __attribute__((address_space(1))) void*)gpb,
                (__attribute__((address_space(3))) void*)&Bsl[(size_t)s * 8],
                16, 0, 0);
        }
        __syncthreads();

#pragma unroll
        for (int kh = 0; kh < 2; kh++) {
            bf16x8 af[2], bfv[4];
#pragma unroll
            for (int mi = 0; mi < 2; mi++) {
                int row = wm + mi * 16 + l16;
                int ch = (kh * 4 + q) ^ (row & 7);
                af[mi] = *reinterpret_cast<const bf16x8*>(&Asl[row * 64 + ch * 8]);
            }
#pragma unroll
            for (int ni = 0; ni < 4; ni++) {
                int row = wn + ni * 16 + l16;
                int ch = (kh * 4 + q) ^ (row & 7);
                bfv[ni] = *reinterpret_cast<const bf16x8*>(&Bsl[row * 64 + ch * 8]);
            }
#pragma unroll
            for (int mi = 0; mi < 2; mi++)
#pragma unroll
                for (int ni = 0; ni < 4; ni++)
                    acc[mi][ni] = __builtin_amdgcn_mfma_f32_16x16x32_bf16(af[mi], bfv[ni], acc[mi][ni], 0, 0, 0);
        }
        __syncthreads();
    }

    const int hIdx = colBase >> 7;           // C==128 per head
    const float* asl = a_src + hIdx * 128;
    const float* adl = a_dst + hIdx * 128;
    float acoef[4], dcoef[4];
#pragma unroll
    for (int ni = 0; ni < 4; ni++) {
        int cl = wn + ni * 16 + l16;
        acoef[ni] = asl[cl];
        dcoef[ni] = adl[cl];
    }

    // reduction buffer overlaid on Asl (safe: last barrier drained all reads)
    float2* red = reinterpret_cast<float2*>(Asl);   // red[row*2 + half], 64 rows
    const int half = wn >> 6;

#pragma unroll
    for (int mi = 0; mi < 2; mi++) {
#pragma unroll
        for (int rr = 0; rr < 4; rr++) {
            int lrow = wm + mi * 16 + q * 4 + rr;
            int grow = rowBase + lrow;
            bool ok = grow < M;
            float vs = 0.f, vd = 0.f;
#pragma unroll
            for (int ni = 0; ni < 4; ni++) {
                float hv = acc[mi][ni][rr];
                vs += hv * acoef[ni];
                vd += hv * dcoef[ni];
                if (ok) {
                    int gcol = colBase + wn + ni * 16 + l16;
                    C[(size_t)grow * N + gcol] = f2bf(hv);
                }
            }
#pragma unroll
            for (int d = 1; d < 16; d <<= 1) {
                vs += __shfl_xor(vs, d);
                vd += __shfl_xor(vd, d);
            }
            if (l16 == 0) red[lrow * 2 + half] = make_float2(vs, vd);
        }
    }
    __syncthreads();
    if (tid < 64) {
        int grow = rowBase + tid;
        if (grow < M) {
            float2 a = red[tid * 2 + 0];
            float2 b = red[tid * 2 + 1];
            alS[(size_t)grow * HEADS + hIdx] = a.x + b.x;
            alD[(size_t)grow * HEADS + hIdx] = a.y + b.y;
        }
    }
}

// ---------------- fused segment softmax + aggregate (+optional head), wave/node -------
// Weight redistribution via wave-private LDS slab (2 ds_read_b128 per 4 edges)
// instead of 5 bpermutes/edge. Inactive-lane weights are exactly 0, so the consume
// loop runs in unconditional groups of 4.
// MODE 0: out = bf16 + relu.  MODE 1 (H==1): fused risk head, out = float per node.
template <int H, int C, int MODE>
__global__ __launch_bounds__(256) void gat_aggregate(const unsigned short* __restrict__ hb,
                                                     const float* __restrict__ alS,
                                                     const float* __restrict__ alD,
                                                     const int* __restrict__ off,
                                                     const int* __restrict__ csr_src,
                                                     const float* __restrict__ bias,
                                                     void* __restrict__ outbuf,
                                                     const float* __restrict__ Ws1,
                                                     const float* __restrict__ bs1,
                                                     const float* __restrict__ Ws2,
                                                     const float* __restrict__ bs2,
                                                     int N) {
    constexpr int HC = H * C;
    constexpr int PER = HC / 64;
    __shared__ int   sIdx[4][64];        // [wave][edge]
    __shared__ float sW[4][H][68];       // [wave][head][edge], padded to 68 (16B-aligned rows, no bank clash)

    int n = (blockIdx.x * blockDim.x + threadIdx.x) >> 6;
    int lane = threadIdx.x & 63;
    int wave = threadIdx.x >> 6;
    if (n >= N) return;
    int beg = off[n], end = off[n + 1];

    float ad0 = 0.f, ad1 = 0.f, ad2 = 0.f, ad3 = 0.f;
    if (H == 4) {
        float4 t = *reinterpret_cast<const float4*>(&alD[n * 4]);
        ad0 = t.x; ad1 = t.y; ad2 = t.z; ad3 = t.w;
    } else {
        ad0 = alD[n];
    }

    const int myh = (lane * PER) / C;
    const unsigned short* hbl = hb + (size_t)lane * PER;
    const float* sWrow = &sW[wave][0][0] + (size_t)myh * 68;

    float m0 = -1e30f, m1 = -1e30f, m2 = -1e30f, m3 = -1e30f;
    float dn0 = 0.f, dn1 = 0.f, dn2 = 0.f, dn3 = 0.f;
    float acc0 = 0.f, acc1 = 0.f, acc2 = 0.f, acc3 = 0.f,
          acc4 = 0.f, acc5 = 0.f, acc6 = 0.f, acc7 = 0.f;

    for (int base = beg; base < end; base += 64) {
        int cnt = end - base; if (cnt > 64) cnt = 64;
        bool act = lane < cnt;
        int s_l = csr_src[act ? (base + lane) : base];

        float v0 = -1e30f, v1 = -1e30f, v2 = -1e30f, v3 = -1e30f;
        if (H == 4) {
            float4 a4 = *reinterpret_cast<const float4*>(&alS[s_l * 4]);
            v0 = act ? lrelu(a4.x + ad0) : -1e30f;
            v1 = act ? lrelu(a4.y + ad1) : -1e30f;
            v2 = act ? lrelu(a4.z + ad2) : -1e30f;
            v3 = act ? lrelu(a4.w + ad3) : -1e30f;
        } else {
            v0 = act ? lrelu(alS[s_l] + ad0) : -1e30f;
        }

        float wl0 = 0.f, wl1 = 0.f, wl2 = 0.f, wl3 = 0.f;
        float so0 = 0.f, so1 = 0.f, so2 = 0.f, so3 = 0.f;
        chunk_stats(v0, m0, dn0, wl0, so0);
        if (H == 4) {
            chunk_stats(v1, m1, dn1, wl1, so1);
            chunk_stats(v2, m2, dn2, wl2, so2);
            chunk_stats(v3, m3, dn3, wl3, so3);
        }
        // stash edge (src, weights) in wave-private LDS
        sIdx[wave][lane] = s_l;
        sW[wave][0][lane] = wl0;
        if (H == 4) {
            sW[wave][1][lane] = wl1;
            sW[wave][2][lane] = wl2;
            sW[wave][3][lane] = wl3;
        }

        // rescale acc by this chunk's carry factor (per this lane's head)
        float sAcc;
        if (H == 4) {
            float rlo = (myh & 1) ? so1 : so0;
            float rhi = (myh & 1) ? so3 : so2;
            sAcc = (myh & 2) ? rhi : rlo;
        } else sAcc = so0;
        acc0 *= sAcc; acc1 *= sAcc;
        if (PER == 8) {
            acc2 *= sAcc; acc3 *= sAcc; acc4 *= sAcc; acc5 *= sAcc;
            acc6 *= sAcc; acc7 *= sAcc;
        }

        int cntR = (cnt + 3) & ~3;

        if (PER == 8) {
            // prologue: group 0
            int4   sI = *reinterpret_cast<const int4*>(&sIdx[wave][0]);
            float4 wv = *reinterpret_cast<const float4*>(&sWrow[0]);
            uint4 gA0 = *reinterpret_cast<const uint4*>(hbl + (size_t)sI.x * HC);
            uint4 gA1 = *reinterpret_cast<const uint4*>(hbl + (size_t)sI.y * HC);
            uint4 gA2 = *reinterpret_cast<const uint4*>(hbl + (size_t)sI.z * HC);
            uint4 gA3 = *reinterpret_cast<const uint4*>(hbl + (size_t)sI.w * HC);
            for (int i = 0; i < cntR; i += 4) {
                int4 sI2 = {}; float4 wv2 = {};
                uint4 gB0 = {}, gB1 = {}, gB2 = {}, gB3 = {};
                if (i + 4 < cntR) {
                    sI2 = *reinterpret_cast<const int4*>(&sIdx[wave][i + 4]);
                    wv2 = *reinterpret_cast<const float4*>(&sWrow[i + 4]);
                    gB0 = *reinterpret_cast<const uint4*>(hbl + (size_t)sI2.x * HC);
                    gB1 = *reinterpret_cast<const uint4*>(hbl + (size_t)sI2.y * HC);
                    gB2 = *reinterpret_cast<const uint4*>(hbl + (size_t)sI2.z * HC);
                    gB3 = *reinterpret_cast<const uint4*>(hbl + (size_t)sI2.w * HC);
                }
#define CONSUME(G, W)                                                   \
                { uint4 rc = G; float w = W;                            \
                  acc0 += bf_lo(rc.x) * w; acc1 += bf_hi(rc.x) * w;     \
                  acc2 += bf_lo(rc.y) * w; acc3 += bf_hi(rc.y) * w;     \
                  acc4 += bf_lo(rc.z) * w; acc5 += bf_hi(rc.z) * w;     \
                  acc6 += bf_lo(rc.w) * w; acc7 += bf_hi(rc.w) * w; }
                CONSUME(gA0, wv.x); CONSUME(gA1, wv.y);
                CONSUME(gA2, wv.z); CONSUME(gA3, wv.w);
#undef CONSUME
                sI = sI2; wv = wv2;
                gA0 = gB0; gA1 = gB1; gA2 = gB2; gA3 = gB3;
            }
        } else {
            int4   sI = *reinterpret_cast<const int4*>(&sIdx[wave][0]);
            float4 wv = *reinterpret_cast<const float4*>(&sWrow[0]);
            unsigned gA0 = *reinterpret_cast<const unsigned*>(hbl + (size_t)sI.x * HC);
            unsigned gA1 = *reinterpret_cast<const unsigned*>(hbl + (size_t)sI.y * HC);
            unsigned gA2 = *reinterpret_cast<const unsigned*>(hbl + (size_t)sI.z * HC);
            unsigned gA3 = *reinterpret_cast<const unsigned*>(hbl + (size_t)sI.w * HC);
            for (int i = 0; i < cntR; i += 4) {
                int4 sI2 = {}; float4 wv2 = {};
                unsigned gB0 = 0, gB1 = 0, gB2 = 0, gB3 = 0;
                if (i + 4 < cntR) {
                    sI2 = *reinterpret_cast<const int4*>(&sIdx[wave][i + 4]);
                    wv2 = *reinterpret_cast<const float4*>(&sWrow[i + 4]);
                    gB0 = *reinterpret_cast<const unsigned*>(hbl + (size_t)sI2.x * HC);
                    gB1 = *reinterpret_cast<const unsigned*>(hbl + (size_t)sI2.y * HC);
                    gB2 = *reinterpret_cast<const unsigned*>(hbl + (size_t)sI2.z * HC);
                    gB3 = *reinterpret_cast<const unsigned*>(hbl + (size_t)sI2.w * HC);
                }
                acc0 += bf_lo(gA0) * wv.x; acc1 += bf_hi(gA0) * wv.x;
                acc0 += bf_lo(gA1) * wv.y; acc1 += bf_hi(gA1) * wv.y;
                acc0 += bf_lo(gA2) * wv.z; acc1 += bf_hi(gA2) * wv.z;
                acc0 += bf_lo(gA3) * wv.w; acc1 += bf_hi(gA3) * wv.w;
                sI = sI2; wv = wv2;
                gA0 = gB0; gA1 = gB1; gA2 = gB2; gA3 = gB3;
            }
        }
    }

    float invd;
    if (H == 4) {
        float rlo = (myh & 1) ? dn1 : dn0;
        float rhi = (myh & 1) ? dn3 : dn2;
        invd = 1.f / ((myh & 2) ? rhi : rlo);
    } else invd = 1.f / dn0;

    if (MODE == 0) {
        unsigned short* op = (unsigned short*)outbuf + (size_t)n * HC + lane * PER;
        const float* bp = bias + lane * PER;
        if (PER == 8) {
            op[0] = f2bf(fmaxf(acc0 * invd + bp[0], 0.f));
            op[1] = f2bf(fmaxf(acc1 * invd + bp[1], 0.f));
            op[2] = f2bf(fmaxf(acc2 * invd + bp[2], 0.f));
            op[3] = f2bf(fmaxf(acc3 * invd + bp[3], 0.f));
            op[4] = f2bf(fmaxf(acc4 * invd + bp[4], 0.f));
            op[5] = f2bf(fmaxf(acc5 * invd + bp[5], 0.f));
            op[6] = f2bf(fmaxf(acc6 * invd + bp[6], 0.f));
            op[7] = f2bf(fmaxf(acc7 * invd + bp[7], 0.f));
        } else {
            op[0] = f2bf(fmaxf(acc0 * invd + bp[0], 0.f));
            op[1] = f2bf(fmaxf(acc1 * invd + bp[1], 0.f));
        }
    } else {
        // H==1, PER==2: channels (2*lane, 2*lane+1) -> fused risk head
        float h0 = acc0 * invd + bias[2 * lane];
        float h1 = acc1 * invd + bias[2 * lane + 1];
        float s = 0.f;
#pragma unroll
        for (int k = 0; k < 64; k++) {
            float a = __shfl(h0, k);
            float b = __shfl(h1, k);
            s += a * Ws1[(2 * k) * 64 + lane];
            s += b * Ws1[(2 * k + 1) * 64 + lane];
        }
        s = fmaxf(s + bs1[lane], 0.f);
        float z = s * Ws2[lane];
#pragma unroll
        for (int d = 1; d < 64; d <<= 1) z += __shfl_xor(z, d);
        if (lane == 0) ((float*)outbuf)[n] = 1.f / (1.f + __expf(-(z + bs2[0])));
    }
}

// ---------------- launch ----------------
extern "C" void kernel_launch(void* const* d_in, const int* in_sizes, int n_in,
                              void* d_out, int out_size, void* d_ws, size_t ws_size,
                              hipStream_t stream) {
    const float* x   = (const float*)d_in[0];
    const int*   ei  = (const int*)d_in[1];
    const float* W1  = (const float*)d_in[2];
    const float* as1 = (const float*)d_in[3];
    const float* ad1 = (const float*)d_in[4];
    const float* b1  = (const float*)d_in[5];
    const float* W2  = (const float*)d_in[6];
    const float* as2 = (const float*)d_in[7];
    const float* ad2 = (const float*)d_in[8];
    const float* b2  = (const float*)d_in[9];
    const float* W3  = (const float*)d_in[10];
    const float* as3 = (const float*)d_in[11];
    const float* ad3 = (const float*)d_in[12];
    const float* b3  = (const float*)d_in[13];
    const float* Ws1 = (const float*)d_in[14];
    const float* bs1 = (const float*)d_in[15];
    const float* Ws2 = (const float*)d_in[16];
    const float* bs2 = (const float*)d_in[17];

    const int N = out_size;            // 20000
    const int E = in_sizes[1] / 2;     // 160000
    const int D = in_sizes[0] / N;     // 768
    const int HC = 512, H = 4, C = 128;
    const int Etot = E + N;

    char* p = (char*)d_ws;
    auto alloc = [&](size_t bytes) -> void* {
        void* q = (void*)p;
        p += (bytes + 255) & ~(size_t)255;
        return q;
    };
    // --- zeroed region (deg, cursor only) ---
    char*  zbeg   = p;
    int*   deg    = (int*)alloc((size_t)N * 4);
    int*   cursor = (int*)alloc((size_t)N * 4);
    char*  zend   = p;
    // --- rest ---
    float* alS1   = (float*)alloc((size_t)N * H * 4);
    float* alD1   = (float*)alloc((size_t)N * H * 4);
    float* alS2   = (float*)alloc((size_t)N * H * 4);
    float* alD2   = (float*)alloc((size_t)N * H * 4);
    float* alS3   = (float*)alloc((size_t)N * 4);
    float* alD3   = (float*)alloc((size_t)N * 4);
    int*   off    = (int*)alloc((size_t)(N + 1) * 4);
    int*   csr    = (int*)alloc((size_t)Etot * 4);
    unsigned short* hbuf = (unsigned short*)alloc((size_t)N * HC * 2);
    unsigned short* xbf  = (unsigned short*)alloc((size_t)N * D * 2);
    unsigned short* obf  = (unsigned short*)alloc((size_t)N * HC * 2);
    unsigned short* W1t  = (unsigned short*)alloc((size_t)D * HC * 2);
    unsigned short* W2t  = (unsigned short*)alloc((size_t)HC * HC * 2);
    unsigned short* W3t  = (unsigned short*)alloc((size_t)HC * C * 2);

    hipMemsetAsync(zbeg, 0, (size_t)(zend - zbeg), stream);

    const int tb = 256;
    count_deg_kernel<<<(Etot + tb - 1) / tb, tb, 0, stream>>>(ei, E, N, deg);
    scan_kernel<<<1, 1024, 0, stream>>>(deg, off, N);
    scatter_kernel<<<(Etot + tb - 1) / tb, tb, 0, stream>>>(ei, E, N, off, cursor, csr);

    {
        size_t n4 = (size_t)N * D / 4;
        cast_bf16_kernel<<<(int)((n4 + 255) / 256), 256, 0, stream>>>(x, xbf, n4);
        transpose_cast_kernel<<<(D * HC + 255) / 256, 256, 0, stream>>>(W1, W1t, D, HC);
        transpose_cast_kernel<<<(HC * HC + 255) / 256, 256, 0, stream>>>(W2, W2t, HC, HC);
        transpose_cast_kernel<<<(HC * C + 255) / 256, 256, 0, stream>>>(W3, W3t, HC, C);
    }

    int node_blocks = (N + 3) / 4;       // one wave per node
    int rowTiles64 = (N + 63) / 64;      // BM=64 -> 313

    // ---- layer 1 ----
    gemm_bf16_alpha<4><<<rowTiles64 * 4, 256, 0, stream>>>(
        xbf, W1t, hbuf, N, HC, D, rowTiles64, as1, ad1, alS1, alD1);
    gat_aggregate<4, 128, 0><<<node_blocks, 256, 0, stream>>>(
        hbuf, alS1, alD1, off, csr, b1, obf, nullptr, nullptr, nullptr, nullptr, N);

    // ---- layer 2 ----
    gemm_bf16_alpha<4><<<rowTiles64 * 4, 256, 0, stream>>>(
        obf, W2t, hbuf, N, HC, HC, rowTiles64, as2, ad2, alS2, alD2);
    gat_aggregate<4, 128, 0><<<node_blocks, 256, 0, stream>>>(
        hbuf, alS2, alD2, off, csr, b2, obf, nullptr, nullptr, nullptr, nullptr, N);

    // ---- layer 3 (H=1) + fused head ----
    gemm_bf16_alpha<1><<<rowTiles64, 256, 0, stream>>>(
        obf, W3t, hbuf, N, C, HC, rowTiles64, as3, ad3, alS3, alD3);
    gat_aggregate<1, 128, 1><<<node_blocks, 256, 0, stream>>>(
        hbuf, alS3, alD3, off, csr, b3, (float*)d_out, Ws1, bs1, Ws2, bs2, N);
}

// Round 11
// 326.065 us; speedup vs baseline: 1.5875x; 1.0979x over previous
//
#include <hip/hip_runtime.h>
#include <hip/hip_bf16.h>
#include <math.h>

#define NEG_SLOPE 0.2f

typedef __attribute__((ext_vector_type(8))) __bf16 bf16x8;
typedef __attribute__((ext_vector_type(4))) float f32x4;

// ---------------- helpers ----------------
__device__ inline float lrelu(float v) { return v > 0.f ? v : NEG_SLOPE * v; }

__device__ inline unsigned short f2bf(float f) {
    __hip_bfloat16 h = __float2bfloat16(f);
    return *reinterpret_cast<unsigned short*>(&h);
}
__device__ inline float bf_lo(unsigned u) { return __uint_as_float(u << 16); }
__device__ inline float bf_hi(unsigned u) { return __uint_as_float(u & 0xffff0000u); }

// ---------------- CSR build ----------------
__global__ void count_deg_kernel(const int* __restrict__ ei, int E, int N,
                                 int* __restrict__ deg) {
    int e = blockIdx.x * blockDim.x + threadIdx.x;
    if (e >= E + N) return;
    int dst = (e < E) ? ei[E + e] : (e - E);
    atomicAdd(&deg[dst], 1);
}

__global__ void scan_kernel(const int* __restrict__ deg, int* __restrict__ off, int N) {
    __shared__ int sums[1024];
    int tid = threadIdx.x;
    int chunk = (N + 1023) / 1024;
    int start = tid * chunk;
    int end = start + chunk; if (end > N) end = N;
    int s = 0;
    for (int i = start; i < end && i < N; i++) s += deg[i];
    sums[tid] = s;
    __syncthreads();
    for (int d = 1; d < 1024; d <<= 1) {
        int v = 0;
        if (tid >= d) v = sums[tid - d];
        __syncthreads();
        if (tid >= d) sums[tid] += v;
        __syncthreads();
    }
    int prefix = (tid == 0) ? 0 : sums[tid - 1];
    int run = prefix;
    for (int i = start; i < end && i < N; i++) { off[i] = run; run += deg[i]; }
    if (tid == 1023) off[N] = sums[1023];
}

__global__ void scatter_kernel(const int* __restrict__ ei, int E, int N,
                               const int* __restrict__ off, int* __restrict__ cursor,
                               int* __restrict__ csr_src) {
    int e = blockIdx.x * blockDim.x + threadIdx.x;
    if (e >= E + N) return;
    int src, dst;
    if (e < E) { src = ei[e]; dst = ei[E + e]; }
    else       { src = dst = e - E; }
    int pos = off[dst] + atomicAdd(&cursor[dst], 1);
    csr_src[pos] = src;
}

// ---------------- fp32 -> bf16 cast (vectorized), n % 4 == 0 ----------------
__global__ void cast_bf16_kernel(const float* __restrict__ in, unsigned short* __restrict__ out,
                                 size_t n4) {
    size_t i = (size_t)blockIdx.x * blockDim.x + threadIdx.x;
    if (i >= n4) return;
    float4 v = reinterpret_cast<const float4*>(in)[i];
    ushort4 o;
    o.x = f2bf(v.x); o.y = f2bf(v.y); o.z = f2bf(v.z); o.w = f2bf(v.w);
    reinterpret_cast<ushort4*>(out)[i] = o;
}

// ---------------- transpose-cast: out[n*K + k] = bf16(in[k*N + n]) ----------------
__global__ void transpose_cast_kernel(const float* __restrict__ in, unsigned short* __restrict__ out,
                                      int K, int N) {
    int idx = blockIdx.x * blockDim.x + threadIdx.x;
    if (idx >= K * N) return;
    int n = idx / K, k = idx % K;
    out[(size_t)n * K + k] = f2bf(in[(size_t)k * N + n]);
}

// ---------------- bf16 MFMA GEMM (BM=64, BN=128, BK=64, XOR swizzle) + alpha --------
template <int HEADS>
__global__ __launch_bounds__(256) void gemm_bf16_alpha(const unsigned short* __restrict__ A,
                                                       const unsigned short* __restrict__ Bt,
                                                       unsigned short* __restrict__ C,
                                                       int M, int N, int K, int rowTiles,
                                                       const float* __restrict__ a_src,
                                                       const float* __restrict__ a_dst,
                                                       float* __restrict__ alS,
                                                       float* __restrict__ alD) {
    __shared__ unsigned short Asl[64 * 64];    // 8 KB
    __shared__ unsigned short Bsl[128 * 64];   // 16 KB
    const int tid  = threadIdx.x;
    const int lane = tid & 63;
    const int wave = tid >> 6;

    // XCD-aware block decode: the 4 col-tiles of one row-tile share an XCD
    int r, c;
    {
        int b = blockIdx.x;
        int colTiles = N >> 7;
        if (colTiles == 4) {
            int mainRows = rowTiles & ~7;
            int mainBlocks = mainRows * 4;
            if (b < mainBlocks) {
                int xcd = b & 7;
                c = (b >> 3) & 3;
                r = (b >> 5) * 8 + xcd;
            } else {
                int idx = b - mainBlocks;
                r = mainRows + (idx >> 2);
                c = idx & 3;
            }
        } else { r = b; c = 0; }
    }
    const int rowBase = r * 64;
    const int colBase = c * 128;
    const int wm = (wave & 1) * 32;
    const int wn = (wave >> 1) * 64;
    const int q   = lane >> 4;
    const int l16 = lane & 15;

    const int r0 = tid >> 3;                  // 0..31
    const int cg = (tid & 7) ^ (r0 & 7);

    f32x4 acc[2][4] = {};

    for (int k0 = 0; k0 < K; k0 += 64) {
#pragma unroll
        for (int it = 0; it < 2; it++) {       // A: 64 rows
            int s = it * 256 + tid;
            int rr = it * 32 + r0;
            int ga = rowBase + rr; if (ga >= M) ga = M - 1;
            const unsigned short* gpa = A + (size_t)ga * K + k0 + cg * 8;
            __builtin_amdgcn_global_load_lds(
                (const __attribute__((address_space(1))) void*)gpa,
                (__attribute__((address_space(3))) void*)&Asl[(size_t)s * 8],
                16, 0, 0);
        }
#pragma unroll
        for (int it = 0; it < 4; it++) {       // B: 128 rows
            int s = it * 256 + tid;
            int rr = it * 32 + r0;
            const unsigned short* gpb = Bt + (size_t)(colBase + rr) * K + k0 + cg * 8;
            __builtin_amdgcn_global_load_lds(
                (const __attribute__((address_space(1))) void*)gpb,
                (__attribute__((address_space(3))) void*)&Bsl[(size_t)s * 8],
                16, 0, 0);
        }
        __syncthreads();

#pragma unroll
        for (int kh = 0; kh < 2; kh++) {
            bf16x8 af[2], bfv[4];
#pragma unroll
            for (int mi = 0; mi < 2; mi++) {
                int row = wm + mi * 16 + l16;
                int ch = (kh * 4 + q) ^ (row & 7);
                af[mi] = *reinterpret_cast<const bf16x8*>(&Asl[row * 64 + ch * 8]);
            }
#pragma unroll
            for (int ni = 0; ni < 4; ni++) {
                int row = wn + ni * 16 + l16;
                int ch = (kh * 4 + q) ^ (row & 7);
                bfv[ni] = *reinterpret_cast<const bf16x8*>(&Bsl[row * 64 + ch * 8]);
            }
#pragma unroll
            for (int mi = 0; mi < 2; mi++)
#pragma unroll
                for (int ni = 0; ni < 4; ni++)
                    acc[mi][ni] = __builtin_amdgcn_mfma_f32_16x16x32_bf16(af[mi], bfv[ni], acc[mi][ni], 0, 0, 0);
        }
        __syncthreads();
    }

    const int hIdx = colBase >> 7;           // C==128 per head
    const float* asl = a_src + hIdx * 128;
    const float* adl = a_dst + hIdx * 128;
    float acoef[4], dcoef[4];
#pragma unroll
    for (int ni = 0; ni < 4; ni++) {
        int cl = wn + ni * 16 + l16;
        acoef[ni] = asl[cl];
        dcoef[ni] = adl[cl];
    }

    float2* red = reinterpret_cast<float2*>(Asl);   // overlaid after final barrier
    const int half = wn >> 6;

#pragma unroll
    for (int mi = 0; mi < 2; mi++) {
#pragma unroll
        for (int rr = 0; rr < 4; rr++) {
            int lrow = wm + mi * 16 + q * 4 + rr;
            int grow = rowBase + lrow;
            bool ok = grow < M;
            float vs = 0.f, vd = 0.f;
#pragma unroll
            for (int ni = 0; ni < 4; ni++) {
                float hv = acc[mi][ni][rr];
                vs += hv * acoef[ni];
                vd += hv * dcoef[ni];
                if (ok) {
                    int gcol = colBase + wn + ni * 16 + l16;
                    C[(size_t)grow * N + gcol] = f2bf(hv);
                }
            }
#pragma unroll
            for (int d = 1; d < 16; d <<= 1) {
                vs += __shfl_xor(vs, d);
                vd += __shfl_xor(vd, d);
            }
            if (l16 == 0) red[lrow * 2 + half] = make_float2(vs, vd);
        }
    }
    __syncthreads();
    if (tid < 64) {
        int grow = rowBase + tid;
        if (grow < M) {
            float2 a = red[tid * 2 + 0];
            float2 b = red[tid * 2 + 1];
            alS[(size_t)grow * HEADS + hIdx] = a.x + b.x;
            alD[(size_t)grow * HEADS + hIdx] = a.y + b.y;
        }
    }
}

// ---------------- fused segment softmax + aggregate, wave/node ----------------------
// 16-lane subgroup stats: chunk = 16 edges; each lane computes the logit for ITS OWN
// head only; butterflies are 4 steps over the 16-lane group (8 bpermutes/chunk vs 48).
// Weight redistribution via wave-private LDS. MODE 0: bf16 + relu. MODE 2: bf16 + bias.
template <int H, int C, int MODE>
__global__ __launch_bounds__(256) void gat_aggregate(const unsigned short* __restrict__ hb,
                                                     const float* __restrict__ alS,
                                                     const float* __restrict__ alD,
                                                     const int* __restrict__ off,
                                                     const int* __restrict__ csr_src,
                                                     const float* __restrict__ bias,
                                                     unsigned short* __restrict__ outbuf,
                                                     int N) {
    constexpr int HC = H * C;
    constexpr int PER = HC / 64;
    __shared__ int   sIdx[4][16];
    __shared__ float sW[4][64];

    int n = (blockIdx.x * blockDim.x + threadIdx.x) >> 6;
    int lane = threadIdx.x & 63;
    int wave = threadIdx.x >> 6;
    if (n >= N) return;
    int beg = off[n], end = off[n + 1];

    const int grp  = lane >> 4;                 // 16-lane subgroup
    const int slot = lane & 15;                 // edge slot within chunk
    const int myh  = (H == 4) ? grp : 0;        // own head (H=1: groups redundant)
    const float adh = alD[n * H + myh];
    const unsigned short* hbl = hb + (size_t)lane * PER;
    const float* sWrow = &sW[wave][grp * 16];

    float m = -1e30f, dn = 0.f;
    float acc0 = 0.f, acc1 = 0.f, acc2 = 0.f, acc3 = 0.f,
          acc4 = 0.f, acc5 = 0.f, acc6 = 0.f, acc7 = 0.f;

    for (int base = beg; base < end; base += 16) {
        int cnt = end - base; if (cnt > 16) cnt = 16;
        bool act = slot < cnt;
        int s_l = csr_src[act ? (base + slot) : base];
        float v = act ? lrelu(alS[s_l * H + myh] + adh) : -1e30f;

        // 16-wide online-softmax chunk stats (own head)
        float mc = v;
#pragma unroll
        for (int d = 1; d < 16; d <<= 1) mc = fmaxf(mc, __shfl_xor(mc, d));
        float pl = __expf(v - mc);              // inactive -> exactly 0
        float dc = pl;
#pragma unroll
        for (int d = 1; d < 16; d <<= 1) dc += __shfl_xor(dc, d);
        float nm = fmaxf(m, mc);
        float so = __expf(m - nm);
        float sc = __expf(mc - nm);
        dn = dn * so + dc * sc;
        m = nm;
        float wl = pl * sc;                     // this slot's weight (own head)

        if (lane < 16) sIdx[wave][lane] = s_l;  // slot==lane for group 0; same across groups
        sW[wave][lane] = wl;

        acc0 *= so; acc1 *= so;
        if (PER == 8) {
            acc2 *= so; acc3 *= so; acc4 *= so; acc5 *= so;
            acc6 *= so; acc7 *= so;
        }

        int cntR = (cnt + 3) & ~3;

        if (PER == 8) {
            int4   sI = *reinterpret_cast<const int4*>(&sIdx[wave][0]);
            float4 wv = *reinterpret_cast<const float4*>(&sWrow[0]);
            uint4 gA0 = *reinterpret_cast<const uint4*>(hbl + (size_t)sI.x * HC);
            uint4 gA1 = *reinterpret_cast<const uint4*>(hbl + (size_t)sI.y * HC);
            uint4 gA2 = *reinterpret_cast<const uint4*>(hbl + (size_t)sI.z * HC);
            uint4 gA3 = *reinterpret_cast<const uint4*>(hbl + (size_t)sI.w * HC);
            for (int i = 0; i < cntR; i += 4) {
                int4 sI2 = {}; float4 wv2 = {};
                uint4 gB0 = {}, gB1 = {}, gB2 = {}, gB3 = {};
                if (i + 4 < cntR) {
                    sI2 = *reinterpret_cast<const int4*>(&sIdx[wave][i + 4]);
                    wv2 = *reinterpret_cast<const float4*>(&sWrow[i + 4]);
                    gB0 = *reinterpret_cast<const uint4*>(hbl + (size_t)sI2.x * HC);
                    gB1 = *reinterpret_cast<const uint4*>(hbl + (size_t)sI2.y * HC);
                    gB2 = *reinterpret_cast<const uint4*>(hbl + (size_t)sI2.z * HC);
                    gB3 = *reinterpret_cast<const uint4*>(hbl + (size_t)sI2.w * HC);
                }
#define CONSUME(G, W)                                                   \
                { uint4 rc = G; float w = W;                            \
                  acc0 += bf_lo(rc.x) * w; acc1 += bf_hi(rc.x) * w;     \
                  acc2 += bf_lo(rc.y) * w; acc3 += bf_hi(rc.y) * w;     \
                  acc4 += bf_lo(rc.z) * w; acc5 += bf_hi(rc.z) * w;     \
                  acc6 += bf_lo(rc.w) * w; acc7 += bf_hi(rc.w) * w; }
                CONSUME(gA0, wv.x); CONSUME(gA1, wv.y);
                CONSUME(gA2, wv.z); CONSUME(gA3, wv.w);
#undef CONSUME
                sI = sI2; wv = wv2;
                gA0 = gB0; gA1 = gB1; gA2 = gB2; gA3 = gB3;
            }
        } else {
            int4   sI = *reinterpret_cast<const int4*>(&sIdx[wave][0]);
            float4 wv = *reinterpret_cast<const float4*>(&sWrow[0]);
            unsigned gA0 = *reinterpret_cast<const unsigned*>(hbl + (size_t)sI.x * HC);
            unsigned gA1 = *reinterpret_cast<const unsigned*>(hbl + (size_t)sI.y * HC);
            unsigned gA2 = *reinterpret_cast<const unsigned*>(hbl + (size_t)sI.z * HC);
            unsigned gA3 = *reinterpret_cast<const unsigned*>(hbl + (size_t)sI.w * HC);
            for (int i = 0; i < cntR; i += 4) {
                int4 sI2 = {}; float4 wv2 = {};
                unsigned gB0 = 0, gB1 = 0, gB2 = 0, gB3 = 0;
                if (i + 4 < cntR) {
                    sI2 = *reinterpret_cast<const int4*>(&sIdx[wave][i + 4]);
                    wv2 = *reinterpret_cast<const float4*>(&sWrow[i + 4]);
                    gB0 = *reinterpret_cast<const unsigned*>(hbl + (size_t)sI2.x * HC);
                    gB1 = *reinterpret_cast<const unsigned*>(hbl + (size_t)sI2.y * HC);
                    gB2 = *reinterpret_cast<const unsigned*>(hbl + (size_t)sI2.z * HC);
                    gB3 = *reinterpret_cast<const unsigned*>(hbl + (size_t)sI2.w * HC);
                }
                acc0 += bf_lo(gA0) * wv.x; acc1 += bf_hi(gA0) * wv.x;
                acc0 += bf_lo(gA1) * wv.y; acc1 += bf_hi(gA1) * wv.y;
                acc0 += bf_lo(gA2) * wv.z; acc1 += bf_hi(gA2) * wv.z;
                acc0 += bf_lo(gA3) * wv.w; acc1 += bf_hi(gA3) * wv.w;
                sI = sI2; wv = wv2;
                gA0 = gB0; gA1 = gB1; gA2 = gB2; gA3 = gB3;
            }
        }
    }

    float invd = 1.f / dn;
    unsigned short* op = outbuf + (size_t)n * HC + lane * PER;
    const float* bp = bias + lane * PER;
    if (PER == 8) {
        float o0 = acc0 * invd + bp[0], o1 = acc1 * invd + bp[1];
        float o2 = acc2 * invd + bp[2], o3 = acc3 * invd + bp[3];
        float o4 = acc4 * invd + bp[4], o5 = acc5 * invd + bp[5];
        float o6 = acc6 * invd + bp[6], o7 = acc7 * invd + bp[7];
        if (MODE == 0) {
            o0 = fmaxf(o0, 0.f); o1 = fmaxf(o1, 0.f); o2 = fmaxf(o2, 0.f); o3 = fmaxf(o3, 0.f);
            o4 = fmaxf(o4, 0.f); o5 = fmaxf(o5, 0.f); o6 = fmaxf(o6, 0.f); o7 = fmaxf(o7, 0.f);
        }
        op[0] = f2bf(o0); op[1] = f2bf(o1); op[2] = f2bf(o2); op[3] = f2bf(o3);
        op[4] = f2bf(o4); op[5] = f2bf(o5); op[6] = f2bf(o6); op[7] = f2bf(o7);
    } else {
        float o0 = acc0 * invd + bp[0], o1 = acc1 * invd + bp[1];
        if (MODE == 0) { o0 = fmaxf(o0, 0.f); o1 = fmaxf(o1, 0.f); }
        op[0] = f2bf(o0); op[1] = f2bf(o1);
    }
}

// ---------------- MFMA risk head: sigmoid(relu(H3@Ws1+bs1)@Ws2+bs2) ----------------
// H3 [N,128] bf16; W1t [64,128] bf16 (j-major). 128 nodes per block.
__global__ __launch_bounds__(256) void head_mfma(const unsigned short* __restrict__ H3,
                                                 const unsigned short* __restrict__ W1t,
                                                 const float* __restrict__ bs1,
                                                 const float* __restrict__ Ws2,
                                                 const float* __restrict__ bs2,
                                                 float* __restrict__ out, int M) {
    __shared__ unsigned short Asl[128 * 128];  // 32 KB
    __shared__ unsigned short Bsl[64 * 128];   // 16 KB
    const int tid = threadIdx.x, lane = tid & 63, wave = tid >> 6;
    const int q = lane >> 4, l16 = lane & 15;
    const int rowBase = blockIdx.x * 128;
    const int r0 = tid >> 4;        // 0..15
    const int cg = (tid & 15) ^ (r0 & 7);

#pragma unroll
    for (int it = 0; it < 8; it++) {       // A: 128 rows x 16 chunks
        int s = it * 256 + tid;
        int r = it * 16 + r0;
        int ga = rowBase + r; if (ga >= M) ga = M - 1;
        const unsigned short* gp = H3 + (size_t)ga * 128 + cg * 8;
        __builtin_amdgcn_global_load_lds(
            (const __attribute__((address_space(1))) void*)gp,
            (__attribute__((address_space(3))) void*)&Asl[(size_t)s * 8], 16, 0, 0);
    }
#pragma unroll
    for (int it = 0; it < 4; it++) {       // B: 64 rows x 16 chunks
        int s = it * 256 + tid;
        int r = it * 16 + r0;
        const unsigned short* gp = W1t + (size_t)r * 128 + cg * 8;
        __builtin_amdgcn_global_load_lds(
            (const __attribute__((address_space(1))) void*)gp,
            (__attribute__((address_space(3))) void*)&Bsl[(size_t)s * 8], 16, 0, 0);
    }
    __syncthreads();

    const int wm = wave * 32;
    f32x4 acc[2][4] = {};
#pragma unroll
    for (int kh = 0; kh < 4; kh++) {
        bf16x8 af[2], bfv[4];
#pragma unroll
        for (int mi = 0; mi < 2; mi++) {
            int row = wm + mi * 16 + l16;
            int ch = (kh * 4 + q) ^ (row & 7);
            af[mi] = *reinterpret_cast<const bf16x8*>(&Asl[row * 128 + ch * 8]);
        }
#pragma unroll
        for (int ni = 0; ni < 4; ni++) {
            int row = ni * 16 + l16;
            int ch = (kh * 4 + q) ^ (row & 7);
            bfv[ni] = *reinterpret_cast<const bf16x8*>(&Bsl[row * 128 + ch * 8]);
        }
#pragma unroll
        for (int mi = 0; mi < 2; mi++)
#pragma unroll
            for (int ni = 0; ni < 4; ni++)
                acc[mi][ni] = __builtin_amdgcn_mfma_f32_16x16x32_bf16(af[mi], bfv[ni], acc[mi][ni], 0, 0, 0);
    }
    __syncthreads();                           // drain LDS reads before overlay

    float b1v[4], w2v[4];
#pragma unroll
    for (int ni = 0; ni < 4; ni++) {
        int cI = ni * 16 + l16;
        b1v[ni] = bs1[cI];
        w2v[ni] = Ws2[cI];
    }
    float* red = reinterpret_cast<float*>(Bsl);
#pragma unroll
    for (int mi = 0; mi < 2; mi++) {
#pragma unroll
        for (int r = 0; r < 4; r++) {
            int lrow = wm + mi * 16 + q * 4 + r;
            float p = 0.f;
#pragma unroll
            for (int ni = 0; ni < 4; ni++)
                p += fmaxf(acc[mi][ni][r] + b1v[ni], 0.f) * w2v[ni];
#pragma unroll
            for (int d = 1; d < 16; d <<= 1) p += __shfl_xor(p, d);
            if (l16 == 0) red[lrow] = p;
        }
    }
    __syncthreads();
    if (tid < 128) {
        int g = rowBase + tid;
        if (g < M) out[g] = 1.f / (1.f + __expf(-(red[tid] + bs2[0])));
    }
}

// ---------------- launch ----------------
extern "C" void kernel_launch(void* const* d_in, const int* in_sizes, int n_in,
                              void* d_out, int out_size, void* d_ws, size_t ws_size,
                              hipStream_t stream) {
    const float* x   = (const float*)d_in[0];
    const int*   ei  = (const int*)d_in[1];
    const float* W1  = (const float*)d_in[2];
    const float* as1 = (const float*)d_in[3];
    const float* ad1 = (const float*)d_in[4];
    const float* b1  = (const float*)d_in[5];
    const float* W2  = (const float*)d_in[6];
    const float* as2 = (const float*)d_in[7];
    const float* ad2 = (const float*)d_in[8];
    const float* b2  = (const float*)d_in[9];
    const float* W3  = (const float*)d_in[10];
    const float* as3 = (const float*)d_in[11];
    const float* ad3 = (const float*)d_in[12];
    const float* b3  = (const float*)d_in[13];
    const float* Ws1 = (const float*)d_in[14];
    const float* bs1 = (const float*)d_in[15];
    const float* Ws2 = (const float*)d_in[16];
    const float* bs2 = (const float*)d_in[17];

    const int N = out_size;            // 20000
    const int E = in_sizes[1] / 2;     // 160000
    const int D = in_sizes[0] / N;     // 768
    const int HC = 512, H = 4, C = 128;
    const int Etot = E + N;

    char* p = (char*)d_ws;
    auto alloc = [&](size_t bytes) -> void* {
        void* q = (void*)p;
        p += (bytes + 255) & ~(size_t)255;
        return q;
    };
    // --- zeroed region (deg, cursor only) ---
    char*  zbeg   = p;
    int*   deg    = (int*)alloc((size_t)N * 4);
    int*   cursor = (int*)alloc((size_t)N * 4);
    char*  zend   = p;
    // --- rest ---
    float* alS1   = (float*)alloc((size_t)N * H * 4);
    float* alD1   = (float*)alloc((size_t)N * H * 4);
    float* alS2   = (float*)alloc((size_t)N * H * 4);
    float* alD2   = (float*)alloc((size_t)N * H * 4);
    float* alS3   = (float*)alloc((size_t)N * 4);
    float* alD3   = (float*)alloc((size_t)N * 4);
    int*   off    = (int*)alloc((size_t)(N + 1) * 4);
    int*   csr    = (int*)alloc((size_t)Etot * 4);
    unsigned short* hbuf = (unsigned short*)alloc((size_t)N * HC * 2);
    unsigned short* xbf  = (unsigned short*)alloc((size_t)N * D * 2);   // also reused as h3 bf16
    unsigned short* obf  = (unsigned short*)alloc((size_t)N * HC * 2);
    unsigned short* W1t  = (unsigned short*)alloc((size_t)D * HC * 2);
    unsigned short* W2t  = (unsigned short*)alloc((size_t)HC * HC * 2);
    unsigned short* W3t  = (unsigned short*)alloc((size_t)HC * C * 2);
    unsigned short* Ws1t = (unsigned short*)alloc((size_t)C * 64 * 2);  // [64][128] j-major

    hipMemsetAsync(zbeg, 0, (size_t)(zend - zbeg), stream);

    const int tb = 256;
    count_deg_kernel<<<(Etot + tb - 1) / tb, tb, 0, stream>>>(ei, E, N, deg);
    scan_kernel<<<1, 1024, 0, stream>>>(deg, off, N);
    scatter_kernel<<<(Etot + tb - 1) / tb, tb, 0, stream>>>(ei, E, N, off, cursor, csr);

    {
        size_t n4 = (size_t)N * D / 4;
        cast_bf16_kernel<<<(int)((n4 + 255) / 256), 256, 0, stream>>>(x, xbf, n4);
        transpose_cast_kernel<<<(D * HC + 255) / 256, 256, 0, stream>>>(W1, W1t, D, HC);
        transpose_cast_kernel<<<(HC * HC + 255) / 256, 256, 0, stream>>>(W2, W2t, HC, HC);
        transpose_cast_kernel<<<(HC * C + 255) / 256, 256, 0, stream>>>(W3, W3t, HC, C);
        transpose_cast_kernel<<<(128 * 64 + 255) / 256, 256, 0, stream>>>(Ws1, Ws1t, 128, 64);
    }

    int node_blocks = (N + 3) / 4;       // one wave per node
    int rowTiles64 = (N + 63) / 64;      // BM=64 -> 313
    int headTiles = (N + 127) / 128;     // 157

    // ---- layer 1 ----
    gemm_bf16_alpha<4><<<rowTiles64 * 4, 256, 0, stream>>>(
        xbf, W1t, hbuf, N, HC, D, rowTiles64, as1, ad1, alS1, alD1);
    gat_aggregate<4, 128, 0><<<node_blocks, 256, 0, stream>>>(
        hbuf, alS1, alD1, off, csr, b1, obf, N);

    // ---- layer 2 ----
    gemm_bf16_alpha<4><<<rowTiles64 * 4, 256, 0, stream>>>(
        obf, W2t, hbuf, N, HC, HC, rowTiles64, as2, ad2, alS2, alD2);
    gat_aggregate<4, 128, 0><<<node_blocks, 256, 0, stream>>>(
        hbuf, alS2, alD2, off, csr, b2, obf, N);

    // ---- layer 3 (H=1): aggregate -> h3 bf16 (bias, no relu) ----
    gemm_bf16_alpha<1><<<rowTiles64, 256, 0, stream>>>(
        obf, W3t, hbuf, N, C, HC, rowTiles64, as3, ad3, alS3, alD3);
    gat_aggregate<1, 128, 2><<<node_blocks, 256, 0, stream>>>(
        hbuf, alS3, alD3, off, csr, b3, xbf, N);

    // ---- MFMA risk head ----
    head_mfma<<<headTiles, 256, 0, stream>>>(xbf, Ws1t, bs1, Ws2, bs2, (float*)d_out, N);
}

// Round 12
// 300.955 us; speedup vs baseline: 1.7199x; 1.0834x over previous
//
#include <hip/hip_runtime.h>
#include <hip/hip_bf16.h>
#include <math.h>

#define NEG_SLOPE 0.2f

typedef __attribute__((ext_vector_type(8))) __bf16 bf16x8;
typedef __attribute__((ext_vector_type(4))) float f32x4;

// ---------------- helpers ----------------
__device__ inline float lrelu(float v) { return v > 0.f ? v : NEG_SLOPE * v; }

__device__ inline unsigned short f2bf(float f) {
    __hip_bfloat16 h = __float2bfloat16(f);
    return *reinterpret_cast<unsigned short*>(&h);
}
__device__ inline float bf_lo(unsigned u) { return __uint_as_float(u << 16); }
__device__ inline float bf_hi(unsigned u) { return __uint_as_float(u & 0xffff0000u); }

__device__ inline void transpose_one(const float* __restrict__ in,
                                     unsigned short* __restrict__ out,
                                     int K, int N, int idx) {
    if (idx >= K * N) return;
    int n = idx / K, k = idx % K;
    out[(size_t)n * K + k] = f2bf(in[(size_t)k * N + n]);
}

// ---------------- fused preprocessing: x-cast + 4 transposes + degree count --------
// One dispatch, block-range decode; all segments independent.
__global__ __launch_bounds__(256) void preproc_kernel(
    const float* __restrict__ x, unsigned short* __restrict__ xbf, int n4,
    const float* __restrict__ W1, unsigned short* __restrict__ W1t,
    const float* __restrict__ W2, unsigned short* __restrict__ W2t,
    const float* __restrict__ W3, unsigned short* __restrict__ W3t,
    const float* __restrict__ Ws1, unsigned short* __restrict__ Ws1t,
    const int* __restrict__ ei, int E, int N, int* __restrict__ deg,
    int c0, int c1, int c2, int c3, int c4,
    int D, int HC, int C) {
    int b = blockIdx.x;
    int t = threadIdx.x;
    if (b < c0) {                                   // x fp32 -> bf16 (float4)
        int i = b * 256 + t;
        if (i < n4) {
            float4 v = reinterpret_cast<const float4*>(x)[i];
            ushort4 o;
            o.x = f2bf(v.x); o.y = f2bf(v.y); o.z = f2bf(v.z); o.w = f2bf(v.w);
            reinterpret_cast<ushort4*>(xbf)[i] = o;
        }
        return;
    }
    b -= c0;
    if (b < c1) { transpose_one(W1, W1t, D, HC, b * 256 + t); return; }
    b -= c1;
    if (b < c2) { transpose_one(W2, W2t, HC, HC, b * 256 + t); return; }
    b -= c2;
    if (b < c3) { transpose_one(W3, W3t, HC, C, b * 256 + t); return; }
    b -= c3;
    if (b < c4) { transpose_one(Ws1, Ws1t, 128, 64, b * 256 + t); return; }
    b -= c4;
    {                                               // degree count (incl. self-loops)
        int e = b * 256 + t;
        if (e < E + N) {
            int dst = (e < E) ? ei[E + e] : (e - E);
            atomicAdd(&deg[dst], 1);
        }
    }
}

// ---------------- CSR scan + scatter ----------------
__global__ void scan_kernel(const int* __restrict__ deg, int* __restrict__ off, int N) {
    __shared__ int sums[1024];
    int tid = threadIdx.x;
    int chunk = (N + 1023) / 1024;
    int start = tid * chunk;
    int end = start + chunk; if (end > N) end = N;
    int s = 0;
#pragma unroll 4
    for (int i = start; i < end && i < N; i++) s += deg[i];
    sums[tid] = s;
    __syncthreads();
    for (int d = 1; d < 1024; d <<= 1) {
        int v = 0;
        if (tid >= d) v = sums[tid - d];
        __syncthreads();
        if (tid >= d) sums[tid] += v;
        __syncthreads();
    }
    int prefix = (tid == 0) ? 0 : sums[tid - 1];
    int run = prefix;
#pragma unroll 4
    for (int i = start; i < end && i < N; i++) { off[i] = run; run += deg[i]; }
    if (tid == 1023) off[N] = sums[1023];
}

__global__ void scatter_kernel(const int* __restrict__ ei, int E, int N,
                               const int* __restrict__ off, int* __restrict__ cursor,
                               int* __restrict__ csr_src) {
    int e = blockIdx.x * blockDim.x + threadIdx.x;
    if (e >= E + N) return;
    int src, dst;
    if (e < E) { src = ei[e]; dst = ei[E + e]; }
    else       { src = dst = e - E; }
    int pos = off[dst] + atomicAdd(&cursor[dst], 1);
    csr_src[pos] = src;
}

// ---------------- bf16 MFMA GEMM (BM=64, BN=128, BK=64, XOR swizzle) + alpha --------
template <int HEADS>
__global__ __launch_bounds__(256) void gemm_bf16_alpha(const unsigned short* __restrict__ A,
                                                       const unsigned short* __restrict__ Bt,
                                                       unsigned short* __restrict__ C,
                                                       int M, int N, int K, int rowTiles,
                                                       const float* __restrict__ a_src,
                                                       const float* __restrict__ a_dst,
                                                       float* __restrict__ alS,
                                                       float* __restrict__ alD) {
    __shared__ unsigned short Asl[64 * 64];    // 8 KB
    __shared__ unsigned short Bsl[128 * 64];   // 16 KB
    const int tid  = threadIdx.x;
    const int lane = tid & 63;
    const int wave = tid >> 6;

    // XCD-aware block decode: the 4 col-tiles of one row-tile share an XCD
    int r, c;
    {
        int b = blockIdx.x;
        int colTiles = N >> 7;
        if (colTiles == 4) {
            int mainRows = rowTiles & ~7;
            int mainBlocks = mainRows * 4;
            if (b < mainBlocks) {
                int xcd = b & 7;
                c = (b >> 3) & 3;
                r = (b >> 5) * 8 + xcd;
            } else {
                int idx = b - mainBlocks;
                r = mainRows + (idx >> 2);
                c = idx & 3;
            }
        } else { r = b; c = 0; }
    }
    const int rowBase = r * 64;
    const int colBase = c * 128;
    const int wm = (wave & 1) * 32;
    const int wn = (wave >> 1) * 64;
    const int q   = lane >> 4;
    const int l16 = lane & 15;

    const int r0 = tid >> 3;                  // 0..31
    const int cg = (tid & 7) ^ (r0 & 7);

    f32x4 acc[2][4] = {};

    for (int k0 = 0; k0 < K; k0 += 64) {
#pragma unroll
        for (int it = 0; it < 2; it++) {       // A: 64 rows
            int s = it * 256 + tid;
            int rr = it * 32 + r0;
            int ga = rowBase + rr; if (ga >= M) ga = M - 1;
            const unsigned short* gpa = A + (size_t)ga * K + k0 + cg * 8;
            __builtin_amdgcn_global_load_lds(
                (const __attribute__((address_space(1))) void*)gpa,
                (__attribute__((address_space(3))) void*)&Asl[(size_t)s * 8],
                16, 0, 0);
        }
#pragma unroll
        for (int it = 0; it < 4; it++) {       // B: 128 rows
            int s = it * 256 + tid;
            int rr = it * 32 + r0;
            const unsigned short* gpb = Bt + (size_t)(colBase + rr) * K + k0 + cg * 8;
            __builtin_amdgcn_global_load_lds(
                (const __attribute__((address_space(1))) void*)gpb,
                (__attribute__((address_space(3))) void*)&Bsl[(size_t)s * 8],
                16, 0, 0);
        }
        __syncthreads();

#pragma unroll
        for (int kh = 0; kh < 2; kh++) {
            bf16x8 af[2], bfv[4];
#pragma unroll
            for (int mi = 0; mi < 2; mi++) {
                int row = wm + mi * 16 + l16;
                int ch = (kh * 4 + q) ^ (row & 7);
                af[mi] = *reinterpret_cast<const bf16x8*>(&Asl[row * 64 + ch * 8]);
            }
#pragma unroll
            for (int ni = 0; ni < 4; ni++) {
                int row = wn + ni * 16 + l16;
                int ch = (kh * 4 + q) ^ (row & 7);
                bfv[ni] = *reinterpret_cast<const bf16x8*>(&Bsl[row * 64 + ch * 8]);
            }
#pragma unroll
            for (int mi = 0; mi < 2; mi++)
#pragma unroll
                for (int ni = 0; ni < 4; ni++)
                    acc[mi][ni] = __builtin_amdgcn_mfma_f32_16x16x32_bf16(af[mi], bfv[ni], acc[mi][ni], 0, 0, 0);
        }
        __syncthreads();
    }

    const int hIdx = colBase >> 7;           // C==128 per head
    const float* asl = a_src + hIdx * 128;
    const float* adl = a_dst + hIdx * 128;
    float acoef[4], dcoef[4];
#pragma unroll
    for (int ni = 0; ni < 4; ni++) {
        int cl = wn + ni * 16 + l16;
        acoef[ni] = asl[cl];
        dcoef[ni] = adl[cl];
    }

    float2* red = reinterpret_cast<float2*>(Asl);   // overlaid after final barrier
    const int half = wn >> 6;

#pragma unroll
    for (int mi = 0; mi < 2; mi++) {
#pragma unroll
        for (int rr = 0; rr < 4; rr++) {
            int lrow = wm + mi * 16 + q * 4 + rr;
            int grow = rowBase + lrow;
            bool ok = grow < M;
            float vs = 0.f, vd = 0.f;
#pragma unroll
            for (int ni = 0; ni < 4; ni++) {
                float hv = acc[mi][ni][rr];
                vs += hv * acoef[ni];
                vd += hv * dcoef[ni];
                if (ok) {
                    int gcol = colBase + wn + ni * 16 + l16;
                    C[(size_t)grow * N + gcol] = f2bf(hv);
                }
            }
#pragma unroll
            for (int d = 1; d < 16; d <<= 1) {
                vs += __shfl_xor(vs, d);
                vd += __shfl_xor(vd, d);
            }
            if (l16 == 0) red[lrow * 2 + half] = make_float2(vs, vd);
        }
    }
    __syncthreads();
    if (tid < 64) {
        int grow = rowBase + tid;
        if (grow < M) {
            float2 a = red[tid * 2 + 0];
            float2 b = red[tid * 2 + 1];
            alS[(size_t)grow * HEADS + hIdx] = a.x + b.x;
            alD[(size_t)grow * HEADS + hIdx] = a.y + b.y;
        }
    }
}

// ---------------- fused segment softmax + aggregate, wave/node ----------------------
// 16-lane subgroup stats; weight redistribution via wave-private LDS.
// MODE 0: bf16 + relu. MODE 2: bf16 + bias (no relu).
template <int H, int C, int MODE>
__global__ __launch_bounds__(256) void gat_aggregate(const unsigned short* __restrict__ hb,
                                                     const float* __restrict__ alS,
                                                     const float* __restrict__ alD,
                                                     const int* __restrict__ off,
                                                     const int* __restrict__ csr_src,
                                                     const float* __restrict__ bias,
                                                     unsigned short* __restrict__ outbuf,
                                                     int N) {
    constexpr int HC = H * C;
    constexpr int PER = HC / 64;
    __shared__ int   sIdx[4][16];
    __shared__ float sW[4][64];

    int n = (blockIdx.x * blockDim.x + threadIdx.x) >> 6;
    int lane = threadIdx.x & 63;
    int wave = threadIdx.x >> 6;
    if (n >= N) return;
    int beg = off[n], end = off[n + 1];

    const int grp  = lane >> 4;
    const int slot = lane & 15;
    const int myh  = (H == 4) ? grp : 0;
    const float adh = alD[n * H + myh];
    const unsigned short* hbl = hb + (size_t)lane * PER;
    const float* sWrow = &sW[wave][grp * 16];

    float m = -1e30f, dn = 0.f;
    float acc0 = 0.f, acc1 = 0.f, acc2 = 0.f, acc3 = 0.f,
          acc4 = 0.f, acc5 = 0.f, acc6 = 0.f, acc7 = 0.f;

    for (int base = beg; base < end; base += 16) {
        int cnt = end - base; if (cnt > 16) cnt = 16;
        bool act = slot < cnt;
        int s_l = csr_src[act ? (base + slot) : base];
        float v = act ? lrelu(alS[s_l * H + myh] + adh) : -1e30f;

        float mc = v;
#pragma unroll
        for (int d = 1; d < 16; d <<= 1) mc = fmaxf(mc, __shfl_xor(mc, d));
        float pl = __expf(v - mc);
        float dc = pl;
#pragma unroll
        for (int d = 1; d < 16; d <<= 1) dc += __shfl_xor(dc, d);
        float nm = fmaxf(m, mc);
        float so = __expf(m - nm);
        float sc = __expf(mc - nm);
        dn = dn * so + dc * sc;
        m = nm;
        float wl = pl * sc;

        if (lane < 16) sIdx[wave][lane] = s_l;
        sW[wave][lane] = wl;

        acc0 *= so; acc1 *= so;
        if (PER == 8) {
            acc2 *= so; acc3 *= so; acc4 *= so; acc5 *= so;
            acc6 *= so; acc7 *= so;
        }

        int cntR = (cnt + 3) & ~3;

        if (PER == 8) {
            int4   sI = *reinterpret_cast<const int4*>(&sIdx[wave][0]);
            float4 wv = *reinterpret_cast<const float4*>(&sWrow[0]);
            uint4 gA0 = *reinterpret_cast<const uint4*>(hbl + (size_t)sI.x * HC);
            uint4 gA1 = *reinterpret_cast<const uint4*>(hbl + (size_t)sI.y * HC);
            uint4 gA2 = *reinterpret_cast<const uint4*>(hbl + (size_t)sI.z * HC);
            uint4 gA3 = *reinterpret_cast<const uint4*>(hbl + (size_t)sI.w * HC);
            for (int i = 0; i < cntR; i += 4) {
                int4 sI2 = {}; float4 wv2 = {};
                uint4 gB0 = {}, gB1 = {}, gB2 = {}, gB3 = {};
                if (i + 4 < cntR) {
                    sI2 = *reinterpret_cast<const int4*>(&sIdx[wave][i + 4]);
                    wv2 = *reinterpret_cast<const float4*>(&sWrow[i + 4]);
                    gB0 = *reinterpret_cast<const uint4*>(hbl + (size_t)sI2.x * HC);
                    gB1 = *reinterpret_cast<const uint4*>(hbl + (size_t)sI2.y * HC);
                    gB2 = *reinterpret_cast<const uint4*>(hbl + (size_t)sI2.z * HC);
                    gB3 = *reinterpret_cast<const uint4*>(hbl + (size_t)sI2.w * HC);
                }
#define CONSUME(G, W)                                                   \
                { uint4 rc = G; float w = W;                            \
                  acc0 += bf_lo(rc.x) * w; acc1 += bf_hi(rc.x) * w;     \
                  acc2 += bf_lo(rc.y) * w; acc3 += bf_hi(rc.y) * w;     \
                  acc4 += bf_lo(rc.z) * w; acc5 += bf_hi(rc.z) * w;     \
                  acc6 += bf_lo(rc.w) * w; acc7 += bf_hi(rc.w) * w; }
                CONSUME(gA0, wv.x); CONSUME(gA1, wv.y);
                CONSUME(gA2, wv.z); CONSUME(gA3, wv.w);
#undef CONSUME
                sI = sI2; wv = wv2;
                gA0 = gB0; gA1 = gB1; gA2 = gB2; gA3 = gB3;
            }
        } else {
            int4   sI = *reinterpret_cast<const int4*>(&sIdx[wave][0]);
            float4 wv = *reinterpret_cast<const float4*>(&sWrow[0]);
            unsigned gA0 = *reinterpret_cast<const unsigned*>(hbl + (size_t)sI.x * HC);
            unsigned gA1 = *reinterpret_cast<const unsigned*>(hbl + (size_t)sI.y * HC);
            unsigned gA2 = *reinterpret_cast<const unsigned*>(hbl + (size_t)sI.z * HC);
            unsigned gA3 = *reinterpret_cast<const unsigned*>(hbl + (size_t)sI.w * HC);
            for (int i = 0; i < cntR; i += 4) {
                int4 sI2 = {}; float4 wv2 = {};
                unsigned gB0 = 0, gB1 = 0, gB2 = 0, gB3 = 0;
                if (i + 4 < cntR) {
                    sI2 = *reinterpret_cast<const int4*>(&sIdx[wave][i + 4]);
                    wv2 = *reinterpret_cast<const float4*>(&sWrow[i + 4]);
                    gB0 = *reinterpret_cast<const unsigned*>(hbl + (size_t)sI2.x * HC);
                    gB1 = *reinterpret_cast<const unsigned*>(hbl + (size_t)sI2.y * HC);
                    gB2 = *reinterpret_cast<const unsigned*>(hbl + (size_t)sI2.z * HC);
                    gB3 = *reinterpret_cast<const unsigned*>(hbl + (size_t)sI2.w * HC);
                }
                acc0 += bf_lo(gA0) * wv.x; acc1 += bf_hi(gA0) * wv.x;
                acc0 += bf_lo(gA1) * wv.y; acc1 += bf_hi(gA1) * wv.y;
                acc0 += bf_lo(gA2) * wv.z; acc1 += bf_hi(gA2) * wv.z;
                acc0 += bf_lo(gA3) * wv.w; acc1 += bf_hi(gA3) * wv.w;
                sI = sI2; wv = wv2;
                gA0 = gB0; gA1 = gB1; gA2 = gB2; gA3 = gB3;
            }
        }
    }

    float invd = 1.f / dn;
    unsigned short* op = outbuf + (size_t)n * HC + lane * PER;
    const float* bp = bias + lane * PER;
    if (PER == 8) {
        float o0 = acc0 * invd + bp[0], o1 = acc1 * invd + bp[1];
        float o2 = acc2 * invd + bp[2], o3 = acc3 * invd + bp[3];
        float o4 = acc4 * invd + bp[4], o5 = acc5 * invd + bp[5];
        float o6 = acc6 * invd + bp[6], o7 = acc7 * invd + bp[7];
        if (MODE == 0) {
            o0 = fmaxf(o0, 0.f); o1 = fmaxf(o1, 0.f); o2 = fmaxf(o2, 0.f); o3 = fmaxf(o3, 0.f);
            o4 = fmaxf(o4, 0.f); o5 = fmaxf(o5, 0.f); o6 = fmaxf(o6, 0.f); o7 = fmaxf(o7, 0.f);
        }
        op[0] = f2bf(o0); op[1] = f2bf(o1); op[2] = f2bf(o2); op[3] = f2bf(o3);
        op[4] = f2bf(o4); op[5] = f2bf(o5); op[6] = f2bf(o6); op[7] = f2bf(o7);
    } else {
        float o0 = acc0 * invd + bp[0], o1 = acc1 * invd + bp[1];
        if (MODE == 0) { o0 = fmaxf(o0, 0.f); o1 = fmaxf(o1, 0.f); }
        op[0] = f2bf(o0); op[1] = f2bf(o1);
    }
}

// ---------------- MFMA risk head: sigmoid(relu(H3@Ws1+bs1)@Ws2+bs2) ----------------
__global__ __launch_bounds__(256) void head_mfma(const unsigned short* __restrict__ H3,
                                                 const unsigned short* __restrict__ W1t,
                                                 const float* __restrict__ bs1,
                                                 const float* __restrict__ Ws2,
                                                 const float* __restrict__ bs2,
                                                 float* __restrict__ out, int M) {
    __shared__ unsigned short Asl[128 * 128];  // 32 KB
    __shared__ unsigned short Bsl[64 * 128];   // 16 KB
    const int tid = threadIdx.x, lane = tid & 63, wave = tid >> 6;
    const int q = lane >> 4, l16 = lane & 15;
    const int rowBase = blockIdx.x * 128;
    const int r0 = tid >> 4;        // 0..15
    const int cg = (tid & 15) ^ (r0 & 7);

#pragma unroll
    for (int it = 0; it < 8; it++) {
        int s = it * 256 + tid;
        int r = it * 16 + r0;
        int ga = rowBase + r; if (ga >= M) ga = M - 1;
        const unsigned short* gp = H3 + (size_t)ga * 128 + cg * 8;
        __builtin_amdgcn_global_load_lds(
            (const __attribute__((address_space(1))) void*)gp,
            (__attribute__((address_space(3))) void*)&Asl[(size_t)s * 8], 16, 0, 0);
    }
#pragma unroll
    for (int it = 0; it < 4; it++) {
        int s = it * 256 + tid;
        int r = it * 16 + r0;
        const unsigned short* gp = W1t + (size_t)r * 128 + cg * 8;
        __builtin_amdgcn_global_load_lds(
            (const __attribute__((address_space(1))) void*)gp,
            (__attribute__((address_space(3))) void*)&Bsl[(size_t)s * 8], 16, 0, 0);
    }
    __syncthreads();

    const int wm = wave * 32;
    f32x4 acc[2][4] = {};
#pragma unroll
    for (int kh = 0; kh < 4; kh++) {
        bf16x8 af[2], bfv[4];
#pragma unroll
        for (int mi = 0; mi < 2; mi++) {
            int row = wm + mi * 16 + l16;
            int ch = (kh * 4 + q) ^ (row & 7);
            af[mi] = *reinterpret_cast<const bf16x8*>(&Asl[row * 128 + ch * 8]);
        }
#pragma unroll
        for (int ni = 0; ni < 4; ni++) {
            int row = ni * 16 + l16;
            int ch = (kh * 4 + q) ^ (row & 7);
            bfv[ni] = *reinterpret_cast<const bf16x8*>(&Bsl[row * 128 + ch * 8]);
        }
#pragma unroll
        for (int mi = 0; mi < 2; mi++)
#pragma unroll
            for (int ni = 0; ni < 4; ni++)
                acc[mi][ni] = __builtin_amdgcn_mfma_f32_16x16x32_bf16(af[mi], bfv[ni], acc[mi][ni], 0, 0, 0);
    }
    __syncthreads();

    float b1v[4], w2v[4];
#pragma unroll
    for (int ni = 0; ni < 4; ni++) {
        int cI = ni * 16 + l16;
        b1v[ni] = bs1[cI];
        w2v[ni] = Ws2[cI];
    }
    float* red = reinterpret_cast<float*>(Bsl);
#pragma unroll
    for (int mi = 0; mi < 2; mi++) {
#pragma unroll
        for (int r = 0; r < 4; r++) {
            int lrow = wm + mi * 16 + q * 4 + r;
            float p = 0.f;
#pragma unroll
            for (int ni = 0; ni < 4; ni++)
                p += fmaxf(acc[mi][ni][r] + b1v[ni], 0.f) * w2v[ni];
#pragma unroll
            for (int d = 1; d < 16; d <<= 1) p += __shfl_xor(p, d);
            if (l16 == 0) red[lrow] = p;
        }
    }
    __syncthreads();
    if (tid < 128) {
        int g = rowBase + tid;
        if (g < M) out[g] = 1.f / (1.f + __expf(-(red[tid] + bs2[0])));
    }
}

// ---------------- launch ----------------
extern "C" void kernel_launch(void* const* d_in, const int* in_sizes, int n_in,
                              void* d_out, int out_size, void* d_ws, size_t ws_size,
                              hipStream_t stream) {
    const float* x   = (const float*)d_in[0];
    const int*   ei  = (const int*)d_in[1];
    const float* W1  = (const float*)d_in[2];
    const float* as1 = (const float*)d_in[3];
    const float* ad1 = (const float*)d_in[4];
    const float* b1  = (const float*)d_in[5];
    const float* W2  = (const float*)d_in[6];
    const float* as2 = (const float*)d_in[7];
    const float* ad2 = (const float*)d_in[8];
    const float* b2  = (const float*)d_in[9];
    const float* W3  = (const float*)d_in[10];
    const float* as3 = (const float*)d_in[11];
    const float* ad3 = (const float*)d_in[12];
    const float* b3  = (const float*)d_in[13];
    const float* Ws1 = (const float*)d_in[14];
    const float* bs1 = (const float*)d_in[15];
    const float* Ws2 = (const float*)d_in[16];
    const float* bs2 = (const float*)d_in[17];

    const int N = out_size;            // 20000
    const int E = in_sizes[1] / 2;     // 160000
    const int D = in_sizes[0] / N;     // 768
    const int HC = 512, H = 4, C = 128;
    const int Etot = E + N;

    char* p = (char*)d_ws;
    auto alloc = [&](size_t bytes) -> void* {
        void* q = (void*)p;
        p += (bytes + 255) & ~(size_t)255;
        return q;
    };
    // --- zeroed region (deg, cursor only) ---
    char*  zbeg   = p;
    int*   deg    = (int*)alloc((size_t)N * 4);
    int*   cursor = (int*)alloc((size_t)N * 4);
    char*  zend   = p;
    // --- rest ---
    float* alS1   = (float*)alloc((size_t)N * H * 4);
    float* alD1   = (float*)alloc((size_t)N * H * 4);
    float* alS2   = (float*)alloc((size_t)N * H * 4);
    float* alD2   = (float*)alloc((size_t)N * H * 4);
    float* alS3   = (float*)alloc((size_t)N * 4);
    float* alD3   = (float*)alloc((size_t)N * 4);
    int*   off    = (int*)alloc((size_t)(N + 1) * 4);
    int*   csr    = (int*)alloc((size_t)Etot * 4);
    unsigned short* hbuf = (unsigned short*)alloc((size_t)N * HC * 2);
    unsigned short* xbf  = (unsigned short*)alloc((size_t)N * D * 2);   // reused as h3 bf16
    unsigned short* obf  = (unsigned short*)alloc((size_t)N * HC * 2);
    unsigned short* W1t  = (unsigned short*)alloc((size_t)D * HC * 2);
    unsigned short* W2t  = (unsigned short*)alloc((size_t)HC * HC * 2);
    unsigned short* W3t  = (unsigned short*)alloc((size_t)HC * C * 2);
    unsigned short* Ws1t = (unsigned short*)alloc((size_t)C * 64 * 2);

    hipMemsetAsync(zbeg, 0, (size_t)(zend - zbeg), stream);

    // ---- fused preprocessing (cast + transposes + degree count) ----
    {
        int n4 = N * D / 4;
        int c0 = (n4 + 255) / 256;
        int c1 = (D * HC + 255) / 256;
        int c2 = (HC * HC + 255) / 256;
        int c3 = (HC * C + 255) / 256;
        int c4 = (128 * 64 + 255) / 256;
        int c5 = (Etot + 255) / 256;
        int total = c0 + c1 + c2 + c3 + c4 + c5;
        preproc_kernel<<<total, 256, 0, stream>>>(
            x, xbf, n4, W1, W1t, W2, W2t, W3, W3t, Ws1, Ws1t,
            ei, E, N, deg, c0, c1, c2, c3, c4, D, HC, C);
    }
    scan_kernel<<<1, 1024, 0, stream>>>(deg, off, N);
    scatter_kernel<<<(Etot + 255) / 256, 256, 0, stream>>>(ei, E, N, off, cursor, csr);

    int node_blocks = (N + 3) / 4;       // one wave per node
    int rowTiles64 = (N + 63) / 64;      // BM=64 -> 313
    int headTiles = (N + 127) / 128;     // 157

    // ---- layer 1 ----
    gemm_bf16_alpha<4><<<rowTiles64 * 4, 256, 0, stream>>>(
        xbf, W1t, hbuf, N, HC, D, rowTiles64, as1, ad1, alS1, alD1);
    gat_aggregate<4, 128, 0><<<node_blocks, 256, 0, stream>>>(
        hbuf, alS1, alD1, off, csr, b1, obf, N);

    // ---- layer 2 ----
    gemm_bf16_alpha<4><<<rowTiles64 * 4, 256, 0, stream>>>(
        obf, W2t, hbuf, N, HC, HC, rowTiles64, as2, ad2, alS2, alD2);
    gat_aggregate<4, 128, 0><<<node_blocks, 256, 0, stream>>>(
        hbuf, alS2, alD2, off, csr, b2, obf, N);

    // ---- layer 3 (H=1): aggregate -> h3 bf16 (bias, no relu) ----
    gemm_bf16_alpha<1><<<rowTiles64, 256, 0, stream>>>(
        obf, W3t, hbuf, N, C, HC, rowTiles64, as3, ad3, alS3, alD3);
    gat_aggregate<1, 128, 2><<<node_blocks, 256, 0, stream>>>(
        hbuf, alS3, alD3, off, csr, b3, xbf, N);

    // ---- MFMA risk head ----
    head_mfma<<<headTiles, 256, 0, stream>>>(xbf, Ws1t, bs1, Ws2, bs2, (float*)d_out, N);
}